// Round 6
// baseline (714.991 us; speedup 1.0000x reference)
//
#include <hip/hip_runtime.h>
#include <hip/hip_bf16.h>
#include <cstdint>
#include <math.h>

typedef __bf16 bf16_t;
typedef __attribute__((ext_vector_type(2))) __bf16 bf16x2;
typedef __attribute__((ext_vector_type(4))) __bf16 bf16x4;
typedef __attribute__((ext_vector_type(8))) __bf16 bf16x8;
typedef __attribute__((ext_vector_type(4))) float f32x4;
typedef __attribute__((ext_vector_type(16))) float f32x16;
typedef __attribute__((ext_vector_type(2))) int int2v;
typedef __attribute__((ext_vector_type(4))) int int4v;

#define B_SZ 2
#define S_SZ 2048
#define D_MODEL 1024
#define NUM_HEADS 16
#define HEAD_DIM 64
#define FF_DIM 4096
#define M_ROWS (B_SZ * S_SZ)   // 4096

// exp2-domain scale: 0.125 (1/sqrt(64)) * log2(e)
#define CF 0.180336880f
#define THRC 2.0f   // defer-max threshold in exp2 domain -> P bounded by 4

// ---------------------------------------------------------------------------
__device__ __forceinline__ void gload_lds16(const void* g, void* lds) {
    __builtin_amdgcn_global_load_lds(
        (const __attribute__((address_space(1))) void*)(uintptr_t)g,
        (__attribute__((address_space(3))) void*)(uint32_t)(uintptr_t)lds,
        16, 0, 0);
}

__device__ __forceinline__ f32x4 mfma16(bf16x8 a, bf16x8 b, f32x4 c) {
    return __builtin_amdgcn_mfma_f32_16x16x32_bf16(a, b, c, 0, 0, 0);
}
__device__ __forceinline__ f32x16 mfma32(bf16x8 a, bf16x8 b, f32x16 c) {
    return __builtin_amdgcn_mfma_f32_32x32x16_bf16(a, b, c, 0, 0, 0);
}
__device__ __forceinline__ int2v plswap(int a, int b) {
    return __builtin_amdgcn_permlane32_swap(a, b, false, false);
}
__device__ __forceinline__ int packbf(float a, float b) {
    bf16x2 t; t[0] = (bf16_t)a; t[1] = (bf16_t)b;
    return __builtin_bit_cast(int, t);
}

// XCD-aware bijective swizzle helper (nwg must be divisible by 8)
__device__ __forceinline__ int xcd_swz(int lin, int nwg) {
    return (lin & 7) * (nwg >> 3) + (lin >> 3);
}

// ---------------------------------------------------------------------------
__global__ __launch_bounds__(256) void cast_f32_bf16(const float* __restrict__ in,
                                                     bf16_t* __restrict__ out) {
    size_t i = ((size_t)blockIdx.x * 256 + threadIdx.x) * 4;
    float4 v = *(const float4*)(in + i);
    bf16x4 o;
    o[0] = (bf16_t)v.x; o[1] = (bf16_t)v.y; o[2] = (bf16_t)v.z; o[3] = (bf16_t)v.w;
    *(bf16x4*)(out + i) = o;
}

// ---------------------------------------------------------------------------
__global__ __launch_bounds__(256) void transpose_cast_w(const float* __restrict__ W,
                                                        bf16_t* __restrict__ WT,
                                                        int K, int N) {
    __shared__ float t[32][33];
    int tid = threadIdx.x;
    int rr = tid >> 3, cc = (tid & 7) * 4;
    int k0 = blockIdx.x * 32, n0 = blockIdx.y * 32;
    float4 v = *(const float4*)(W + (size_t)(k0 + rr) * N + n0 + cc);
    t[rr][cc + 0] = v.x; t[rr][cc + 1] = v.y; t[rr][cc + 2] = v.z; t[rr][cc + 3] = v.w;
    __syncthreads();
    bf16x4 o;
    o[0] = (bf16_t)t[cc + 0][rr]; o[1] = (bf16_t)t[cc + 1][rr];
    o[2] = (bf16_t)t[cc + 2][rr]; o[3] = (bf16_t)t[cc + 3][rr];
    *(bf16x4*)(WT + (size_t)(n0 + rr) * K + k0 + cc) = o;
}

// ---------------------------------------------------------------------------
__global__ __launch_bounds__(256) void transpose_v(const bf16_t* __restrict__ Vp,
                                                   bf16_t* __restrict__ VT) {
    __shared__ bf16_t t[32][34];
    int tid = threadIdx.x;
    int rr = tid >> 3, cc = (tid & 7) * 4;
    int bh = blockIdx.z;
    int b = bh >> 4, h = bh & 15;
    int s0 = blockIdx.x * 32, d0 = blockIdx.y * 32;
    bf16x4 v = *(const bf16x4*)(Vp + ((size_t)(b * S_SZ + s0 + rr)) * D_MODEL + h * HEAD_DIM + d0 + cc);
    t[rr][cc + 0] = v[0]; t[rr][cc + 1] = v[1]; t[rr][cc + 2] = v[2]; t[rr][cc + 3] = v[3];
    __syncthreads();
    bf16x4 o;
    o[0] = t[cc + 0][rr]; o[1] = t[cc + 1][rr]; o[2] = t[cc + 2][rr]; o[3] = t[cc + 3][rr];
    *(bf16x4*)(VT + ((size_t)(bh * HEAD_DIM + d0 + rr)) * S_SZ + s0 + cc) = o;
}

// ---------------------------------------------------------------------------
// GEMM core: C[128x128 tile at m0,n0] = A[:,0:Klen] @ Bt[:,0:Klen]^T (+bias)
// BK=32, 4 waves (each 64x64 = 4x4 frags of 16x16x32)
// ---------------------------------------------------------------------------
template<bool RELU, bool OUT_BF16, bool OUT_F32>
__device__ __forceinline__ void gemm_core(const bf16_t* __restrict__ A, int lda,
                                          const bf16_t* __restrict__ Bt, int ldb,
                                          const float* __restrict__ bias, bool useBias,
                                          float* __restrict__ Cf,
                                          bf16_t* __restrict__ Cb,
                                          int N, int Klen, int m0, int n0,
                                          bf16_t* sA, bf16_t* sB) {
    const int tid = threadIdx.x;
    const int lane = tid & 63, wave = tid >> 6;
    const int g = lane >> 4, r = lane & 15;
    const int wm = (wave >> 1) * 64, wn = (wave & 1) * 64;

    const bf16_t* Ablk = A + (size_t)m0 * lda;
    const bf16_t* Bblk = Bt + (size_t)n0 * ldb;
    const int c0 = wave * 64 + lane;
    const int c1 = c0 + 256;

    f32x4 acc[4][4];
#pragma unroll
    for (int i = 0; i < 4; i++)
#pragma unroll
        for (int j = 0; j < 4; j++)
#pragma unroll
            for (int e = 0; e < 4; e++) acc[i][j][e] = 0.f;

    for (int k0 = 0; k0 < Klen; k0 += 32) {
        gload_lds16(Ablk + (size_t)(c0 >> 2) * lda + k0 + (c0 & 3) * 8, sA + wave * 512);
        gload_lds16(Ablk + (size_t)(c1 >> 2) * lda + k0 + (c1 & 3) * 8, sA + 2048 + wave * 512);
        gload_lds16(Bblk + (size_t)(c0 >> 2) * ldb + k0 + (c0 & 3) * 8, sB + wave * 512);
        gload_lds16(Bblk + (size_t)(c1 >> 2) * ldb + k0 + (c1 & 3) * 8, sB + 2048 + wave * 512);
        __syncthreads();

        bf16x8 a[4], b[4];
#pragma unroll
        for (int i = 0; i < 4; i++)
            a[i] = *(const bf16x8*)(sA + (wm + i * 16 + r) * 32 + g * 8);
#pragma unroll
        for (int j = 0; j < 4; j++)
            b[j] = *(const bf16x8*)(sB + (wn + j * 16 + r) * 32 + g * 8);
#pragma unroll
        for (int i = 0; i < 4; i++)
#pragma unroll
            for (int j = 0; j < 4; j++)
                acc[i][j] = mfma16(a[i], b[j], acc[i][j]);
        __syncthreads();
    }

#pragma unroll
    for (int j = 0; j < 4; j++) {
        int n = n0 + wn + j * 16 + r;
        float bv = useBias ? bias[n] : 0.f;
#pragma unroll
        for (int i = 0; i < 4; i++) {
#pragma unroll
            for (int rr = 0; rr < 4; rr++) {
                int mrow = m0 + wm + i * 16 + g * 4 + rr;
                float val = acc[i][j][rr] + bv;
                if (RELU) val = fmaxf(val, 0.f);
                if (OUT_F32) Cf[(size_t)mrow * N + n] = val;
                if (OUT_BF16) Cb[(size_t)mrow * N + n] = (bf16_t)val;
            }
        }
    }
}

// split-K wrapper (z = K-chunk); XCD-swizzled grid
template<bool RELU, bool OUT_BF16, bool OUT_F32>
__global__ __launch_bounds__(256) void gemm_bt(const bf16_t* __restrict__ A, int lda,
                                               const bf16_t* __restrict__ Bt, int ldb,
                                               const float* __restrict__ bias,
                                               float* __restrict__ Cf0,
                                               float* __restrict__ Cf1,
                                               bf16_t* __restrict__ Cb,
                                               int N, int Klen) {
    __shared__ bf16_t sA[128 * 32];
    __shared__ bf16_t sB[128 * 32];
    const int lin = blockIdx.x + gridDim.x * (blockIdx.y + gridDim.y * blockIdx.z);
    const int nwg = gridDim.x * gridDim.y * gridDim.z;
    const int swz = xcd_swz(lin, nwg);
    const int bx = swz % gridDim.x;
    const int rest = swz / gridDim.x;
    const int by = rest % gridDim.y;
    const int bz = rest / gridDim.y;
    const int koff = bz * Klen;
    gemm_core<RELU, OUT_BF16, OUT_F32>(A + koff, lda, Bt + koff, ldb, bias, bz == 0,
                                       bz ? Cf1 : Cf0, Cb, N, Klen, bx * 128, by * 128, sA, sB);
}

// grouped QKV: z selects (A, W, bias, C); 3 blocks/CU instead of 1
__global__ __launch_bounds__(256) void gemm_qkv(const bf16_t* __restrict__ A0,
                                                const bf16_t* __restrict__ A1,
                                                const bf16_t* __restrict__ A2,
                                                const bf16_t* __restrict__ B0,
                                                const bf16_t* __restrict__ B1,
                                                const bf16_t* __restrict__ B2,
                                                const float* __restrict__ b0,
                                                const float* __restrict__ b1,
                                                const float* __restrict__ b2,
                                                bf16_t* __restrict__ C0,
                                                bf16_t* __restrict__ C1,
                                                bf16_t* __restrict__ C2) {
    __shared__ bf16_t sA[128 * 32];
    __shared__ bf16_t sB[128 * 32];
    const int lin = blockIdx.x + gridDim.x * (blockIdx.y + gridDim.y * blockIdx.z);
    const int nwg = gridDim.x * gridDim.y * gridDim.z;
    const int swz = xcd_swz(lin, nwg);
    const int bx = swz % gridDim.x;
    const int rest = swz / gridDim.x;
    const int by = rest % gridDim.y;
    const int bz = rest / gridDim.y;
    const bf16_t* A = bz == 0 ? A0 : bz == 1 ? A1 : A2;
    const bf16_t* Bt = bz == 0 ? B0 : bz == 1 ? B1 : B2;
    const float* bias = bz == 0 ? b0 : bz == 1 ? b1 : b2;
    bf16_t* C = bz == 0 ? C0 : bz == 1 ? C1 : C2;
    gemm_core<false, true, false>(A, 1024, Bt, 1024, bias, true,
                                  nullptr, C, 1024, 1024, bx * 128, by * 128, sA, sB);
}

// ---------------------------------------------------------------------------
// Flash attention, 32x32 double-swapped, defer-max, 4-way KV split.
// Block = 4 waves = 1 q-tile (32 rows) x 4 kv-quarters (512 each, 16 tiles).
// V loaded intra-tile (covered by softmax latency); K double-buffered.
// Grid (S/32, H, B) = 2048 blocks, XCD-swizzled; 4-way merge via LDS.
// ---------------------------------------------------------------------------
__device__ __forceinline__ void attn_tile32(
    const bf16_t* __restrict__ Kb, const bf16_t* __restrict__ Vb,
    int l31, int hi, int kv0, int kvn,
    const bf16x8 (&bq)[4],
    bf16x8 (&ak)[4], bf16x8 (&akn)[4],
    f32x16& o0, f32x16& o1, float& mC, float& l_run)
{
    // QK^T (swapped): s reg e -> E[kv = kv0 + (e&3)+8*(e>>2)+4*hi][q = l31]
    f32x16 s;
#pragma unroll
    for (int e = 0; e < 16; e++) s[e] = 0.f;
    __builtin_amdgcn_s_setprio(1);
#pragma unroll
    for (int kb = 0; kb < 4; kb++) s = mfma32(ak[kb], bq[kb], s);
    __builtin_amdgcn_s_setprio(0);

    // V for THIS tile (consumed after softmax ~250 cyc later)
    bf16x8 av[4];
#pragma unroll
    for (int db = 0; db < 2; db++)
#pragma unroll
        for (int kb = 0; kb < 2; kb++)
            av[db * 2 + kb] = *(const bf16x8*)(Vb + (size_t)(db * 32 + l31) * S_SZ + kv0 + kb * 16 + hi * 8);
    // K for NEXT tile
#pragma unroll
    for (int kb = 0; kb < 4; kb++)
        akn[kb] = *(const bf16x8*)(Kb + (size_t)(kvn + l31) * D_MODEL + kb * 16 + hi * 8);

    // in-lane max of 16
    float ma = fmaxf(fmaxf(s[0], s[1]), fmaxf(s[2], s[3]));
    float mb = fmaxf(fmaxf(s[4], s[5]), fmaxf(s[6], s[7]));
    float mc = fmaxf(fmaxf(s[8], s[9]), fmaxf(s[10], s[11]));
    float md = fmaxf(fmaxf(s[12], s[13]), fmaxf(s[14], s[15]));
    float pmaxC = fmaxf(fmaxf(ma, mb), fmaxf(mc, md)) * CF;

    // defer-max: __all spans the wave -> covers both hi halves
    if (!__all(pmaxC <= mC + THRC)) {
        int2v pr = plswap(__float_as_int(pmaxC), __float_as_int(pmaxC));
        float rowmaxC = fmaxf(__int_as_float(pr[0]), __int_as_float(pr[1]));
        float mnewC = fmaxf(mC, rowmaxC);
        float alpha = exp2f(mC - mnewC);
        mC = mnewC;
        l_run *= alpha;
#pragma unroll
        for (int e = 0; e < 16; e++) { o0[e] *= alpha; o1[e] *= alpha; }
    }

    // P = 2^(s*CF - mC); in-lane partial sum
#pragma unroll
    for (int e = 0; e < 16; e++) s[e] = exp2f(__builtin_fmaf(s[e], CF, -mC));
    float t0 = (s[0] + s[1]) + (s[2] + s[3]);
    float t1 = (s[4] + s[5]) + (s[6] + s[7]);
    float t2 = (s[8] + s[9]) + (s[10] + s[11]);
    float t3 = (s[12] + s[13]) + (s[14] + s[15]);
    l_run += (t0 + t1) + (t2 + t3);

    // pack P -> bf16 B-frags via permlane32_swap; PV
    __builtin_amdgcn_s_setprio(1);
#pragma unroll
    for (int kb2 = 0; kb2 < 2; kb2++) {
        const int bse = kb2 * 8;
        int W0 = packbf(s[bse + 0], s[bse + 1]);
        int W1 = packbf(s[bse + 2], s[bse + 3]);
        int W2 = packbf(s[bse + 4], s[bse + 5]);
        int W3 = packbf(s[bse + 6], s[bse + 7]);
        int2v r02 = plswap(W0, W2);
        int2v r13 = plswap(W1, W3);
        int4v fw; fw[0] = r02[0]; fw[1] = r13[0]; fw[2] = r02[1]; fw[3] = r13[1];
        bf16x8 pf = __builtin_bit_cast(bf16x8, fw);
        o0 = mfma32(av[kb2], pf, o0);
        o1 = mfma32(av[2 + kb2], pf, o1);
    }
    __builtin_amdgcn_s_setprio(0);
}

__global__ __launch_bounds__(256, 6) void flash_attn(const bf16_t* __restrict__ Qp,
                                                     const bf16_t* __restrict__ Kp,
                                                     const bf16_t* __restrict__ VT,
                                                     bf16_t* __restrict__ Oa) {
    __shared__ float obuf[3][32][64];   // publishers' O words
    __shared__ float mrg[3][64][2];     // publishers' (m,l)
    const int tid = threadIdx.x;
    const int lane = tid & 63;
    const int wave = tid >> 6;          // kv quarter
    const int l31 = lane & 31, hi = lane >> 5;

    // XCD-aware bijective swizzle (2048 blocks = 8 XCDs x 256 = 4 heads each)
    const int lin = blockIdx.x + (blockIdx.y << 6) + (blockIdx.z << 10);
    const int swz = (lin & 7) * 256 + (lin >> 3);
    const int qtile = swz & 63;
    const int h = (swz >> 6) & 15;
    const int b = swz >> 10;

    const int q0 = qtile * 32;
    const int kvbase = wave * (S_SZ / 4);

    const bf16_t* Qb = Qp + (size_t)b * S_SZ * D_MODEL + h * HEAD_DIM;
    const bf16_t* Kb = Kp + (size_t)b * S_SZ * D_MODEL + h * HEAD_DIM;
    const bf16_t* Vb = VT + ((size_t)(b * NUM_HEADS + h) * HEAD_DIM) * S_SZ;

    bf16x8 bq[4];
#pragma unroll
    for (int kb = 0; kb < 4; kb++)
        bq[kb] = *(const bf16x8*)(Qb + (size_t)(q0 + l31) * D_MODEL + kb * 16 + hi * 8);

    f32x16 o0, o1;
#pragma unroll
    for (int e = 0; e < 16; e++) { o0[e] = 0.f; o1[e] = 0.f; }
    float mC = -1e30f, l_run = 0.f;

    bf16x8 akA[4], akB[4];
#pragma unroll
    for (int kb = 0; kb < 4; kb++)
        akA[kb] = *(const bf16x8*)(Kb + (size_t)(kvbase + l31) * D_MODEL + kb * 16 + hi * 8);

    for (int t = 0; t < 16; t += 2) {
        const int kv0 = kvbase + t * 32;
        attn_tile32(Kb, Vb, l31, hi, kv0, kv0 + 32, bq, akA, akB, o0, o1, mC, l_run);
        const int kvn2 = (t + 2 < 16) ? kv0 + 64 : kvbase;
        attn_tile32(Kb, Vb, l31, hi, kv0 + 32, kvn2, bq, akB, akA, o0, o1, mC, l_run);
    }

    // cross-half l combine (both hi lanes -> full quarter-l for q=l31)
    int2v lp = plswap(__float_as_int(l_run), __float_as_int(l_run));
    l_run = __int_as_float(lp[0]) + __int_as_float(lp[1]);

    // 4-way merge: waves 1..3 publish; wave 0 combines + stores
    if (wave != 0) {
        mrg[wave - 1][lane][0] = mC;
        mrg[wave - 1][lane][1] = l_run;
#pragma unroll
        for (int e = 0; e < 16; e++) {
            obuf[wave - 1][e][lane] = o0[e];
            obuf[wave - 1][16 + e][lane] = o1[e];
        }
    }
    __syncthreads();
    if (wave == 0) {
        float mw0 = mrg[0][lane][0], mw1 = mrg[1][lane][0], mw2 = mrg[2][lane][0];
        float mm = fmaxf(fmaxf(mC, mw0), fmaxf(mw1, mw2));
        float e0 = exp2f(mC - mm);
        float e1 = exp2f(mw0 - mm);
        float e2 = exp2f(mw1 - mm);
        float e3 = exp2f(mw2 - mm);
        float ltot = l_run * e0 + mrg[0][lane][1] * e1 + mrg[1][lane][1] * e2 + mrg[2][lane][1] * e3;
        float linv = 1.f / ltot;
        bf16_t* Orow = Oa + ((size_t)b * S_SZ + q0 + l31) * D_MODEL + h * HEAD_DIM;
#pragma unroll
        for (int db = 0; db < 2; db++) {
#pragma unroll
            for (int rq = 0; rq < 4; rq++) {
                bf16x4 st;
#pragma unroll
                for (int i = 0; i < 4; i++) {
                    const int e = rq * 4 + i;
                    float val = (db ? o1[e] : o0[e]) * e0;
                    val += obuf[0][db * 16 + e][lane] * e1;
                    val += obuf[1][db * 16 + e][lane] * e2;
                    val += obuf[2][db * 16 + e][lane] * e3;
                    st[i] = (bf16_t)(val * linv);
                }
                *(bf16x4*)(Orow + db * 32 + rq * 8 + hi * 4) = st;
            }
        }
    }
}

// ---------------------------------------------------------------------------
// LayerNorm over 1024 with fused residual + optional second addend
// ---------------------------------------------------------------------------
__global__ __launch_bounds__(256) void ln_fused(const float* __restrict__ A,
                                                const float* __restrict__ A2,
                                                const float* __restrict__ R,
                                                const float* __restrict__ gamma,
                                                const float* __restrict__ beta,
                                                float* __restrict__ Xf,
                                                bf16_t* __restrict__ Xb) {
    __shared__ float red[8];
    int row = blockIdx.x, tid = threadIdx.x;
    size_t base = (size_t)row * D_MODEL + tid * 4;
    float4 a = *(const float4*)(A + base);
    float4 rv = *(const float4*)(R + base);
    float v0 = a.x + rv.x, v1 = a.y + rv.y, v2 = a.z + rv.z, v3 = a.w + rv.w;
    if (A2) {
        float4 a2 = *(const float4*)(A2 + base);
        v0 += a2.x; v1 += a2.y; v2 += a2.z; v3 += a2.w;
    }
    float s = v0 + v1 + v2 + v3;
    float q = v0 * v0 + v1 * v1 + v2 * v2 + v3 * v3;
#pragma unroll
    for (int off = 32; off; off >>= 1) { s += __shfl_down(s, off); q += __shfl_down(q, off); }
    if ((tid & 63) == 0) { red[tid >> 6] = s; red[4 + (tid >> 6)] = q; }
    __syncthreads();
    s = red[0] + red[1] + red[2] + red[3];
    q = red[4] + red[5] + red[6] + red[7];
    float mean = s * (1.f / D_MODEL);
    float var = q * (1.f / D_MODEL) - mean * mean;
    float rstd = rsqrtf(var + 1e-5f);
    float4 gm = *(const float4*)(gamma + tid * 4);
    float4 bt = *(const float4*)(beta + tid * 4);
    float y0 = (v0 - mean) * rstd * gm.x + bt.x;
    float y1 = (v1 - mean) * rstd * gm.y + bt.y;
    float y2 = (v2 - mean) * rstd * gm.z + bt.z;
    float y3 = (v3 - mean) * rstd * gm.w + bt.w;
    float4 yo; yo.x = y0; yo.y = y1; yo.z = y2; yo.w = y3;
    *(float4*)(Xf + base) = yo;
    if (Xb) {
        bf16x4 ob; ob[0] = (bf16_t)y0; ob[1] = (bf16_t)y1; ob[2] = (bf16_t)y2; ob[3] = (bf16_t)y3;
        *(bf16x4*)(Xb + base) = ob;
    }
}

// ---------------------------------------------------------------------------
extern "C" void kernel_launch(void* const* d_in, const int* in_sizes, int n_in,
                              void* d_out, int out_size, void* d_ws, size_t ws_size,
                              hipStream_t stream) {
    const float* value = (const float*)d_in[0];
    const float* key   = (const float*)d_in[1];
    const float* query = (const float*)d_in[2];
    const float* wq = (const float*)d_in[3];
    const float* bq = (const float*)d_in[4];
    const float* wk = (const float*)d_in[5];
    const float* bk = (const float*)d_in[6];
    const float* wv = (const float*)d_in[7];
    const float* bv = (const float*)d_in[8];
    const float* wo = (const float*)d_in[9];
    const float* bo = (const float*)d_in[10];
    const float* g1 = (const float*)d_in[11];
    const float* beta1 = (const float*)d_in[12];
    const float* w1 = (const float*)d_in[13];
    const float* b1 = (const float*)d_in[14];
    const float* w2 = (const float*)d_in[15];
    const float* b2 = (const float*)d_in[16];
    const float* g2 = (const float*)d_in[17];
    const float* beta2 = (const float*)d_in[18];
    (void)in_sizes; (void)n_in; (void)out_size; (void)ws_size;

    const size_t MB = 1ull << 20;
    char* ws = (char*)d_ws;
    bf16_t* wqT = (bf16_t*)(ws + 0 * MB);
    bf16_t* wkT = (bf16_t*)(ws + 2 * MB);
    bf16_t* wvT = (bf16_t*)(ws + 4 * MB);
    bf16_t* woT = (bf16_t*)(ws + 6 * MB);
    bf16_t* w1T = (bf16_t*)(ws + 8 * MB);
    bf16_t* w2T = (bf16_t*)(ws + 16 * MB);
    bf16_t* q_bf = (bf16_t*)(ws + 24 * MB);
    bf16_t* k_bf = (bf16_t*)(ws + 32 * MB);
    bf16_t* v_bf = (bf16_t*)(ws + 40 * MB);
    bf16_t* Qp  = (bf16_t*)(ws + 48 * MB);
    bf16_t* Kp  = (bf16_t*)(ws + 56 * MB);
    bf16_t* Vp  = (bf16_t*)(ws + 64 * MB);
    bf16_t* VT  = (bf16_t*)(ws + 72 * MB);
    bf16_t* attn = (bf16_t*)(ws + 24 * MB);   // reuse q_bf (dead after QKV gemm)
    float*  woP0 = (float*)(ws + 32 * MB);    // reuse k_bf..Qp (dead after flash)
    float*  woP1 = (float*)(ws + 48 * MB);
    float*  x_f = (float*)(ws + 64 * MB);     // reuse Vp/VT (dead after flash)
    bf16_t* x_b = (bf16_t*)(ws + 24 * MB);    // reuse attn (dead after WO gemm)
    bf16_t* h_b = (bf16_t*)(ws + 32 * MB);    // reuse woP (dead after LN1), 32MB
    float*  ffP0 = (float*)(ws + 80 * MB);
    float*  ffP1 = (float*)(ws + 96 * MB);

    dim3 blk(256);

    // 1) casts + weight transposes
    cast_f32_bf16<<<4096, blk, 0, stream>>>(query, q_bf);
    cast_f32_bf16<<<4096, blk, 0, stream>>>(key, k_bf);
    cast_f32_bf16<<<4096, blk, 0, stream>>>(value, v_bf);
    transpose_cast_w<<<dim3(32, 32), blk, 0, stream>>>(wq, wqT, 1024, 1024);
    transpose_cast_w<<<dim3(32, 32), blk, 0, stream>>>(wk, wkT, 1024, 1024);
    transpose_cast_w<<<dim3(32, 32), blk, 0, stream>>>(wv, wvT, 1024, 1024);
    transpose_cast_w<<<dim3(32, 32), blk, 0, stream>>>(wo, woT, 1024, 1024);
    transpose_cast_w<<<dim3(32, 128), blk, 0, stream>>>(w1, w1T, 1024, 4096);
    transpose_cast_w<<<dim3(128, 32), blk, 0, stream>>>(w2, w2T, 4096, 1024);

    // 2) grouped QKV projection (one launch, 3 blocks/CU)
    gemm_qkv<<<dim3(32, 8, 3), blk, 0, stream>>>(q_bf, k_bf, v_bf, wqT, wkT, wvT,
                                                 bq, bk, bv, Qp, Kp, Vp);

    // 3) V transpose for PV A-operand
    transpose_v<<<dim3(64, 2, 32), blk, 0, stream>>>(Vp, VT);

    // 4) flash attention (4-way KV split, XCD-swizzled)
    flash_attn<<<dim3(64, 16, 2), blk, 0, stream>>>(Qp, Kp, VT, attn);

    // 5) WO projection, split-K=2 (f32 partials)
    gemm_bt<false, false, true><<<dim3(32, 8, 2), blk, 0, stream>>>(attn, 1024, woT, 1024, bo, woP0, woP1, nullptr, D_MODEL, 512);

    // 6) LN1: x = LN(woP0 + woP1 + query)
    ln_fused<<<4096, blk, 0, stream>>>(woP0, woP1, query, g1, beta1, x_f, x_b);

    // 7) FF1 + ReLU (bf16 out)
    gemm_bt<true, true, false><<<dim3(32, 32, 1), blk, 0, stream>>>(x_b, 1024, w1T, 1024, b1, nullptr, nullptr, h_b, FF_DIM, 1024);

    // 8) FF2, split-K=2 (f32 partials)
    gemm_bt<false, false, true><<<dim3(32, 8, 2), blk, 0, stream>>>(h_b, 4096, w2T, 4096, b2, ffP0, ffP1, nullptr, D_MODEL, 2048);

    // 9) LN2 -> d_out
    ln_fused<<<4096, blk, 0, stream>>>(ffP0, ffP1, x_f, g2, beta2, (float*)d_out, nullptr);
}

// Round 7
// 358.438 us; speedup vs baseline: 1.9947x; 1.9947x over previous
//
#include <hip/hip_runtime.h>
#include <hip/hip_bf16.h>
#include <cstdint>
#include <math.h>

typedef __bf16 bf16_t;
typedef __attribute__((ext_vector_type(2))) __bf16 bf16x2;
typedef __attribute__((ext_vector_type(4))) __bf16 bf16x4;
typedef __attribute__((ext_vector_type(8))) __bf16 bf16x8;
typedef __attribute__((ext_vector_type(4))) float f32x4;
typedef __attribute__((ext_vector_type(16))) float f32x16;
typedef __attribute__((ext_vector_type(2))) int int2v;
typedef __attribute__((ext_vector_type(4))) int int4v;

#define B_SZ 2
#define S_SZ 2048
#define D_MODEL 1024
#define NUM_HEADS 16
#define HEAD_DIM 64
#define FF_DIM 4096
#define M_ROWS (B_SZ * S_SZ)   // 4096

// exp2-domain scale: 0.125 (1/sqrt(64)) * log2(e)
#define CF 0.180336880f
#define THRC 2.0f   // defer-max threshold in exp2 domain -> P bounded by 4

// ---------------------------------------------------------------------------
__device__ __forceinline__ void gload_lds16(const void* g, void* lds) {
    __builtin_amdgcn_global_load_lds(
        (const __attribute__((address_space(1))) void*)(uintptr_t)g,
        (__attribute__((address_space(3))) void*)(uint32_t)(uintptr_t)lds,
        16, 0, 0);
}

__device__ __forceinline__ f32x4 mfma16(bf16x8 a, bf16x8 b, f32x4 c) {
    return __builtin_amdgcn_mfma_f32_16x16x32_bf16(a, b, c, 0, 0, 0);
}
__device__ __forceinline__ f32x16 mfma32(bf16x8 a, bf16x8 b, f32x16 c) {
    return __builtin_amdgcn_mfma_f32_32x32x16_bf16(a, b, c, 0, 0, 0);
}
__device__ __forceinline__ int2v plswap(int a, int b) {
    return __builtin_amdgcn_permlane32_swap(a, b, false, false);
}
__device__ __forceinline__ int packbf(float a, float b) {
    bf16x2 t; t[0] = (bf16_t)a; t[1] = (bf16_t)b;
    return __builtin_bit_cast(int, t);
}

// XCD-aware bijective swizzle helper (nwg must be divisible by 8)
__device__ __forceinline__ int xcd_swz(int lin, int nwg) {
    return (lin & 7) * (nwg >> 3) + (lin >> 3);
}

// ---------------------------------------------------------------------------
__global__ __launch_bounds__(256) void cast_f32_bf16(const float* __restrict__ in,
                                                     bf16_t* __restrict__ out) {
    size_t i = ((size_t)blockIdx.x * 256 + threadIdx.x) * 4;
    float4 v = *(const float4*)(in + i);
    bf16x4 o;
    o[0] = (bf16_t)v.x; o[1] = (bf16_t)v.y; o[2] = (bf16_t)v.z; o[3] = (bf16_t)v.w;
    *(bf16x4*)(out + i) = o;
}

// ---------------------------------------------------------------------------
__global__ __launch_bounds__(256) void transpose_cast_w(const float* __restrict__ W,
                                                        bf16_t* __restrict__ WT,
                                                        int K, int N) {
    __shared__ float t[32][33];
    int tid = threadIdx.x;
    int rr = tid >> 3, cc = (tid & 7) * 4;
    int k0 = blockIdx.x * 32, n0 = blockIdx.y * 32;
    float4 v = *(const float4*)(W + (size_t)(k0 + rr) * N + n0 + cc);
    t[rr][cc + 0] = v.x; t[rr][cc + 1] = v.y; t[rr][cc + 2] = v.z; t[rr][cc + 3] = v.w;
    __syncthreads();
    bf16x4 o;
    o[0] = (bf16_t)t[cc + 0][rr]; o[1] = (bf16_t)t[cc + 1][rr];
    o[2] = (bf16_t)t[cc + 2][rr]; o[3] = (bf16_t)t[cc + 3][rr];
    *(bf16x4*)(WT + (size_t)(n0 + rr) * K + k0 + cc) = o;
}

// ---------------------------------------------------------------------------
__global__ __launch_bounds__(256) void transpose_v(const bf16_t* __restrict__ Vp,
                                                   bf16_t* __restrict__ VT) {
    __shared__ bf16_t t[32][34];
    int tid = threadIdx.x;
    int rr = tid >> 3, cc = (tid & 7) * 4;
    int bh = blockIdx.z;
    int b = bh >> 4, h = bh & 15;
    int s0 = blockIdx.x * 32, d0 = blockIdx.y * 32;
    bf16x4 v = *(const bf16x4*)(Vp + ((size_t)(b * S_SZ + s0 + rr)) * D_MODEL + h * HEAD_DIM + d0 + cc);
    t[rr][cc + 0] = v[0]; t[rr][cc + 1] = v[1]; t[rr][cc + 2] = v[2]; t[rr][cc + 3] = v[3];
    __syncthreads();
    bf16x4 o;
    o[0] = t[cc + 0][rr]; o[1] = t[cc + 1][rr]; o[2] = t[cc + 2][rr]; o[3] = t[cc + 3][rr];
    *(bf16x4*)(VT + ((size_t)(bh * HEAD_DIM + d0 + rr)) * S_SZ + s0 + cc) = o;
}

// ---------------------------------------------------------------------------
// GEMM core: C[128x128 tile at m0,n0] = A[:,0:Klen] @ Bt[:,0:Klen]^T (+bias)
// BK=32, 4 waves (each 64x64 = 4x4 frags of 16x16x32)
// ---------------------------------------------------------------------------
template<bool RELU, bool OUT_BF16, bool OUT_F32>
__device__ __forceinline__ void gemm_core(const bf16_t* __restrict__ A, int lda,
                                          const bf16_t* __restrict__ Bt, int ldb,
                                          const float* __restrict__ bias, bool useBias,
                                          float* __restrict__ Cf,
                                          bf16_t* __restrict__ Cb,
                                          int N, int Klen, int m0, int n0,
                                          bf16_t* sA, bf16_t* sB) {
    const int tid = threadIdx.x;
    const int lane = tid & 63, wave = tid >> 6;
    const int g = lane >> 4, r = lane & 15;
    const int wm = (wave >> 1) * 64, wn = (wave & 1) * 64;

    const bf16_t* Ablk = A + (size_t)m0 * lda;
    const bf16_t* Bblk = Bt + (size_t)n0 * ldb;
    const int c0 = wave * 64 + lane;
    const int c1 = c0 + 256;

    f32x4 acc[4][4];
#pragma unroll
    for (int i = 0; i < 4; i++)
#pragma unroll
        for (int j = 0; j < 4; j++)
#pragma unroll
            for (int e = 0; e < 4; e++) acc[i][j][e] = 0.f;

    for (int k0 = 0; k0 < Klen; k0 += 32) {
        gload_lds16(Ablk + (size_t)(c0 >> 2) * lda + k0 + (c0 & 3) * 8, sA + wave * 512);
        gload_lds16(Ablk + (size_t)(c1 >> 2) * lda + k0 + (c1 & 3) * 8, sA + 2048 + wave * 512);
        gload_lds16(Bblk + (size_t)(c0 >> 2) * ldb + k0 + (c0 & 3) * 8, sB + wave * 512);
        gload_lds16(Bblk + (size_t)(c1 >> 2) * ldb + k0 + (c1 & 3) * 8, sB + 2048 + wave * 512);
        __syncthreads();

        bf16x8 a[4], b[4];
#pragma unroll
        for (int i = 0; i < 4; i++)
            a[i] = *(const bf16x8*)(sA + (wm + i * 16 + r) * 32 + g * 8);
#pragma unroll
        for (int j = 0; j < 4; j++)
            b[j] = *(const bf16x8*)(sB + (wn + j * 16 + r) * 32 + g * 8);
#pragma unroll
        for (int i = 0; i < 4; i++)
#pragma unroll
            for (int j = 0; j < 4; j++)
                acc[i][j] = mfma16(a[i], b[j], acc[i][j]);
        __syncthreads();
    }

#pragma unroll
    for (int j = 0; j < 4; j++) {
        int n = n0 + wn + j * 16 + r;
        float bv = useBias ? bias[n] : 0.f;
#pragma unroll
        for (int i = 0; i < 4; i++) {
#pragma unroll
            for (int rr = 0; rr < 4; rr++) {
                int mrow = m0 + wm + i * 16 + g * 4 + rr;
                float val = acc[i][j][rr] + bv;
                if (RELU) val = fmaxf(val, 0.f);
                if (OUT_F32) Cf[(size_t)mrow * N + n] = val;
                if (OUT_BF16) Cb[(size_t)mrow * N + n] = (bf16_t)val;
            }
        }
    }
}

// split-K wrapper (z = K-chunk); XCD-swizzled grid
template<bool RELU, bool OUT_BF16, bool OUT_F32>
__global__ __launch_bounds__(256) void gemm_bt(const bf16_t* __restrict__ A, int lda,
                                               const bf16_t* __restrict__ Bt, int ldb,
                                               const float* __restrict__ bias,
                                               float* __restrict__ Cf0,
                                               float* __restrict__ Cf1,
                                               bf16_t* __restrict__ Cb,
                                               int N, int Klen) {
    __shared__ bf16_t sA[128 * 32];
    __shared__ bf16_t sB[128 * 32];
    const int lin = blockIdx.x + gridDim.x * (blockIdx.y + gridDim.y * blockIdx.z);
    const int nwg = gridDim.x * gridDim.y * gridDim.z;
    const int swz = xcd_swz(lin, nwg);
    const int bx = swz % gridDim.x;
    const int rest = swz / gridDim.x;
    const int by = rest % gridDim.y;
    const int bz = rest / gridDim.y;
    const int koff = bz * Klen;
    gemm_core<RELU, OUT_BF16, OUT_F32>(A + koff, lda, Bt + koff, ldb, bias, bz == 0,
                                       bz ? Cf1 : Cf0, Cb, N, Klen, bx * 128, by * 128, sA, sB);
}

// grouped QKV: z selects (A, W, bias, C); 3 blocks/CU instead of 1
__global__ __launch_bounds__(256) void gemm_qkv(const bf16_t* __restrict__ A0,
                                                const bf16_t* __restrict__ A1,
                                                const bf16_t* __restrict__ A2,
                                                const bf16_t* __restrict__ B0,
                                                const bf16_t* __restrict__ B1,
                                                const bf16_t* __restrict__ B2,
                                                const float* __restrict__ b0,
                                                const float* __restrict__ b1,
                                                const float* __restrict__ b2,
                                                bf16_t* __restrict__ C0,
                                                bf16_t* __restrict__ C1,
                                                bf16_t* __restrict__ C2) {
    __shared__ bf16_t sA[128 * 32];
    __shared__ bf16_t sB[128 * 32];
    const int lin = blockIdx.x + gridDim.x * (blockIdx.y + gridDim.y * blockIdx.z);
    const int nwg = gridDim.x * gridDim.y * gridDim.z;
    const int swz = xcd_swz(lin, nwg);
    const int bx = swz % gridDim.x;
    const int rest = swz / gridDim.x;
    const int by = rest % gridDim.y;
    const int bz = rest / gridDim.y;
    const bf16_t* A = bz == 0 ? A0 : bz == 1 ? A1 : A2;
    const bf16_t* Bt = bz == 0 ? B0 : bz == 1 ? B1 : B2;
    const float* bias = bz == 0 ? b0 : bz == 1 ? b1 : b2;
    bf16_t* C = bz == 0 ? C0 : bz == 1 ? C1 : C2;
    gemm_core<false, true, false>(A, 1024, Bt, 1024, bias, true,
                                  nullptr, C, 1024, 1024, bx * 128, by * 128, sA, sB);
}

// ---------------------------------------------------------------------------
// Flash attention, 32x32 double-swapped, defer-max, 4-way KV split.
// Block = 4 waves = 1 q-tile (32 rows) x 4 kv-quarters (512 each, 16 tiles).
// V loaded intra-tile (covered by softmax latency); K double-buffered.
// Grid (S/32, H, B) = 2048 blocks, XCD-swizzled; 4-way merge via LDS.
// __launch_bounds__(256,4): VGPR cap 128 >= ~120 live state -> NO SPILL
// (R5 lesson: (256,6) forced VGPR=40 -> 2 GB scratch traffic, 3.4x slower).
// ---------------------------------------------------------------------------
__device__ __forceinline__ void attn_tile32(
    const bf16_t* __restrict__ Kb, const bf16_t* __restrict__ Vb,
    int l31, int hi, int kv0, int kvn,
    const bf16x8 (&bq)[4],
    bf16x8 (&ak)[4], bf16x8 (&akn)[4],
    f32x16& o0, f32x16& o1, float& mC, float& l_run)
{
    // QK^T (swapped): s reg e -> E[kv = kv0 + (e&3)+8*(e>>2)+4*hi][q = l31]
    f32x16 s;
#pragma unroll
    for (int e = 0; e < 16; e++) s[e] = 0.f;
    __builtin_amdgcn_s_setprio(1);
#pragma unroll
    for (int kb = 0; kb < 4; kb++) s = mfma32(ak[kb], bq[kb], s);
    __builtin_amdgcn_s_setprio(0);

    // V for THIS tile (consumed after softmax ~250 cyc later)
    bf16x8 av[4];
#pragma unroll
    for (int db = 0; db < 2; db++)
#pragma unroll
        for (int kb = 0; kb < 2; kb++)
            av[db * 2 + kb] = *(const bf16x8*)(Vb + (size_t)(db * 32 + l31) * S_SZ + kv0 + kb * 16 + hi * 8);
    // K for NEXT tile
#pragma unroll
    for (int kb = 0; kb < 4; kb++)
        akn[kb] = *(const bf16x8*)(Kb + (size_t)(kvn + l31) * D_MODEL + kb * 16 + hi * 8);

    // in-lane max of 16
    float ma = fmaxf(fmaxf(s[0], s[1]), fmaxf(s[2], s[3]));
    float mb = fmaxf(fmaxf(s[4], s[5]), fmaxf(s[6], s[7]));
    float mc = fmaxf(fmaxf(s[8], s[9]), fmaxf(s[10], s[11]));
    float md = fmaxf(fmaxf(s[12], s[13]), fmaxf(s[14], s[15]));
    float pmaxC = fmaxf(fmaxf(ma, mb), fmaxf(mc, md)) * CF;

    // defer-max: __all spans the wave -> covers both hi halves
    if (!__all(pmaxC <= mC + THRC)) {
        int2v pr = plswap(__float_as_int(pmaxC), __float_as_int(pmaxC));
        float rowmaxC = fmaxf(__int_as_float(pr[0]), __int_as_float(pr[1]));
        float mnewC = fmaxf(mC, rowmaxC);
        float alpha = exp2f(mC - mnewC);
        mC = mnewC;
        l_run *= alpha;
#pragma unroll
        for (int e = 0; e < 16; e++) { o0[e] *= alpha; o1[e] *= alpha; }
    }

    // P = 2^(s*CF - mC); in-lane partial sum
#pragma unroll
    for (int e = 0; e < 16; e++) s[e] = exp2f(__builtin_fmaf(s[e], CF, -mC));
    float t0 = (s[0] + s[1]) + (s[2] + s[3]);
    float t1 = (s[4] + s[5]) + (s[6] + s[7]);
    float t2 = (s[8] + s[9]) + (s[10] + s[11]);
    float t3 = (s[12] + s[13]) + (s[14] + s[15]);
    l_run += (t0 + t1) + (t2 + t3);

    // pack P -> bf16 B-frags via permlane32_swap; PV
    __builtin_amdgcn_s_setprio(1);
#pragma unroll
    for (int kb2 = 0; kb2 < 2; kb2++) {
        const int bse = kb2 * 8;
        int W0 = packbf(s[bse + 0], s[bse + 1]);
        int W1 = packbf(s[bse + 2], s[bse + 3]);
        int W2 = packbf(s[bse + 4], s[bse + 5]);
        int W3 = packbf(s[bse + 6], s[bse + 7]);
        int2v r02 = plswap(W0, W2);
        int2v r13 = plswap(W1, W3);
        int4v fw; fw[0] = r02[0]; fw[1] = r13[0]; fw[2] = r02[1]; fw[3] = r13[1];
        bf16x8 pf = __builtin_bit_cast(bf16x8, fw);
        o0 = mfma32(av[kb2], pf, o0);
        o1 = mfma32(av[2 + kb2], pf, o1);
    }
    __builtin_amdgcn_s_setprio(0);
}

__global__ __launch_bounds__(256, 4) void flash_attn(const bf16_t* __restrict__ Qp,
                                                     const bf16_t* __restrict__ Kp,
                                                     const bf16_t* __restrict__ VT,
                                                     bf16_t* __restrict__ Oa) {
    __shared__ float obuf[3][32][64];   // publishers' O words
    __shared__ float mrg[3][64][2];     // publishers' (m,l)
    const int tid = threadIdx.x;
    const int lane = tid & 63;
    const int wave = tid >> 6;          // kv quarter
    const int l31 = lane & 31, hi = lane >> 5;

    // XCD-aware bijective swizzle (2048 blocks = 8 XCDs x 256 = 4 heads each)
    const int lin = blockIdx.x + (blockIdx.y << 6) + (blockIdx.z << 10);
    const int swz = (lin & 7) * 256 + (lin >> 3);
    const int qtile = swz & 63;
    const int h = (swz >> 6) & 15;
    const int b = swz >> 10;

    const int q0 = qtile * 32;
    const int kvbase = wave * (S_SZ / 4);

    const bf16_t* Qb = Qp + (size_t)b * S_SZ * D_MODEL + h * HEAD_DIM;
    const bf16_t* Kb = Kp + (size_t)b * S_SZ * D_MODEL + h * HEAD_DIM;
    const bf16_t* Vb = VT + ((size_t)(b * NUM_HEADS + h) * HEAD_DIM) * S_SZ;

    bf16x8 bq[4];
#pragma unroll
    for (int kb = 0; kb < 4; kb++)
        bq[kb] = *(const bf16x8*)(Qb + (size_t)(q0 + l31) * D_MODEL + kb * 16 + hi * 8);

    f32x16 o0, o1;
#pragma unroll
    for (int e = 0; e < 16; e++) { o0[e] = 0.f; o1[e] = 0.f; }
    float mC = -1e30f, l_run = 0.f;

    bf16x8 akA[4], akB[4];
#pragma unroll
    for (int kb = 0; kb < 4; kb++)
        akA[kb] = *(const bf16x8*)(Kb + (size_t)(kvbase + l31) * D_MODEL + kb * 16 + hi * 8);

    for (int t = 0; t < 16; t += 2) {
        const int kv0 = kvbase + t * 32;
        attn_tile32(Kb, Vb, l31, hi, kv0, kv0 + 32, bq, akA, akB, o0, o1, mC, l_run);
        const int kvn2 = (t + 2 < 16) ? kv0 + 64 : kvbase;
        attn_tile32(Kb, Vb, l31, hi, kv0 + 32, kvn2, bq, akB, akA, o0, o1, mC, l_run);
    }

    // cross-half l combine (both hi lanes -> full quarter-l for q=l31)
    int2v lp = plswap(__float_as_int(l_run), __float_as_int(l_run));
    l_run = __int_as_float(lp[0]) + __int_as_float(lp[1]);

    // 4-way merge: waves 1..3 publish; wave 0 combines + stores
    if (wave != 0) {
        mrg[wave - 1][lane][0] = mC;
        mrg[wave - 1][lane][1] = l_run;
#pragma unroll
        for (int e = 0; e < 16; e++) {
            obuf[wave - 1][e][lane] = o0[e];
            obuf[wave - 1][16 + e][lane] = o1[e];
        }
    }
    __syncthreads();
    if (wave == 0) {
        float mw0 = mrg[0][lane][0], mw1 = mrg[1][lane][0], mw2 = mrg[2][lane][0];
        float mm = fmaxf(fmaxf(mC, mw0), fmaxf(mw1, mw2));
        float e0 = exp2f(mC - mm);
        float e1 = exp2f(mw0 - mm);
        float e2 = exp2f(mw1 - mm);
        float e3 = exp2f(mw2 - mm);
        float ltot = l_run * e0 + mrg[0][lane][1] * e1 + mrg[1][lane][1] * e2 + mrg[2][lane][1] * e3;
        float linv = 1.f / ltot;
        bf16_t* Orow = Oa + ((size_t)b * S_SZ + q0 + l31) * D_MODEL + h * HEAD_DIM;
#pragma unroll
        for (int db = 0; db < 2; db++) {
#pragma unroll
            for (int rq = 0; rq < 4; rq++) {
                bf16x4 st;
#pragma unroll
                for (int i = 0; i < 4; i++) {
                    const int e = rq * 4 + i;
                    float val = (db ? o1[e] : o0[e]) * e0;
                    val += obuf[0][db * 16 + e][lane] * e1;
                    val += obuf[1][db * 16 + e][lane] * e2;
                    val += obuf[2][db * 16 + e][lane] * e3;
                    st[i] = (bf16_t)(val * linv);
                }
                *(bf16x4*)(Orow + db * 32 + rq * 8 + hi * 4) = st;
            }
        }
    }
}

// ---------------------------------------------------------------------------
// LayerNorm over 1024 with fused residual + optional second addend
// ---------------------------------------------------------------------------
__global__ __launch_bounds__(256) void ln_fused(const float* __restrict__ A,
                                                const float* __restrict__ A2,
                                                const float* __restrict__ R,
                                                const float* __restrict__ gamma,
                                                const float* __restrict__ beta,
                                                float* __restrict__ Xf,
                                                bf16_t* __restrict__ Xb) {
    __shared__ float red[8];
    int row = blockIdx.x, tid = threadIdx.x;
    size_t base = (size_t)row * D_MODEL + tid * 4;
    float4 a = *(const float4*)(A + base);
    float4 rv = *(const float4*)(R + base);
    float v0 = a.x + rv.x, v1 = a.y + rv.y, v2 = a.z + rv.z, v3 = a.w + rv.w;
    if (A2) {
        float4 a2 = *(const float4*)(A2 + base);
        v0 += a2.x; v1 += a2.y; v2 += a2.z; v3 += a2.w;
    }
    float s = v0 + v1 + v2 + v3;
    float q = v0 * v0 + v1 * v1 + v2 * v2 + v3 * v3;
#pragma unroll
    for (int off = 32; off; off >>= 1) { s += __shfl_down(s, off); q += __shfl_down(q, off); }
    if ((tid & 63) == 0) { red[tid >> 6] = s; red[4 + (tid >> 6)] = q; }
    __syncthreads();
    s = red[0] + red[1] + red[2] + red[3];
    q = red[4] + red[5] + red[6] + red[7];
    float mean = s * (1.f / D_MODEL);
    float var = q * (1.f / D_MODEL) - mean * mean;
    float rstd = rsqrtf(var + 1e-5f);
    float4 gm = *(const float4*)(gamma + tid * 4);
    float4 bt = *(const float4*)(beta + tid * 4);
    float y0 = (v0 - mean) * rstd * gm.x + bt.x;
    float y1 = (v1 - mean) * rstd * gm.y + bt.y;
    float y2 = (v2 - mean) * rstd * gm.z + bt.z;
    float y3 = (v3 - mean) * rstd * gm.w + bt.w;
    float4 yo; yo.x = y0; yo.y = y1; yo.z = y2; yo.w = y3;
    *(float4*)(Xf + base) = yo;
    if (Xb) {
        bf16x4 ob; ob[0] = (bf16_t)y0; ob[1] = (bf16_t)y1; ob[2] = (bf16_t)y2; ob[3] = (bf16_t)y3;
        *(bf16x4*)(Xb + base) = ob;
    }
}

// ---------------------------------------------------------------------------
extern "C" void kernel_launch(void* const* d_in, const int* in_sizes, int n_in,
                              void* d_out, int out_size, void* d_ws, size_t ws_size,
                              hipStream_t stream) {
    const float* value = (const float*)d_in[0];
    const float* key   = (const float*)d_in[1];
    const float* query = (const float*)d_in[2];
    const float* wq = (const float*)d_in[3];
    const float* bq = (const float*)d_in[4];
    const float* wk = (const float*)d_in[5];
    const float* bk = (const float*)d_in[6];
    const float* wv = (const float*)d_in[7];
    const float* bv = (const float*)d_in[8];
    const float* wo = (const float*)d_in[9];
    const float* bo = (const float*)d_in[10];
    const float* g1 = (const float*)d_in[11];
    const float* beta1 = (const float*)d_in[12];
    const float* w1 = (const float*)d_in[13];
    const float* b1 = (const float*)d_in[14];
    const float* w2 = (const float*)d_in[15];
    const float* b2 = (const float*)d_in[16];
    const float* g2 = (const float*)d_in[17];
    const float* beta2 = (const float*)d_in[18];
    (void)in_sizes; (void)n_in; (void)out_size; (void)ws_size;

    const size_t MB = 1ull << 20;
    char* ws = (char*)d_ws;
    bf16_t* wqT = (bf16_t*)(ws + 0 * MB);
    bf16_t* wkT = (bf16_t*)(ws + 2 * MB);
    bf16_t* wvT = (bf16_t*)(ws + 4 * MB);
    bf16_t* woT = (bf16_t*)(ws + 6 * MB);
    bf16_t* w1T = (bf16_t*)(ws + 8 * MB);
    bf16_t* w2T = (bf16_t*)(ws + 16 * MB);
    bf16_t* q_bf = (bf16_t*)(ws + 24 * MB);
    bf16_t* k_bf = (bf16_t*)(ws + 32 * MB);
    bf16_t* v_bf = (bf16_t*)(ws + 40 * MB);
    bf16_t* Qp  = (bf16_t*)(ws + 48 * MB);
    bf16_t* Kp  = (bf16_t*)(ws + 56 * MB);
    bf16_t* Vp  = (bf16_t*)(ws + 64 * MB);
    bf16_t* VT  = (bf16_t*)(ws + 72 * MB);
    bf16_t* attn = (bf16_t*)(ws + 24 * MB);   // reuse q_bf (dead after QKV gemm)
    float*  woP0 = (float*)(ws + 32 * MB);    // reuse k_bf..Qp (dead after flash)
    float*  woP1 = (float*)(ws + 48 * MB);
    float*  x_f = (float*)(ws + 64 * MB);     // reuse Vp/VT (dead after flash)
    bf16_t* x_b = (bf16_t*)(ws + 24 * MB);    // reuse attn (dead after WO gemm)
    bf16_t* h_b = (bf16_t*)(ws + 32 * MB);    // reuse woP (dead after LN1), 32MB
    float*  ffP0 = (float*)(ws + 80 * MB);
    float*  ffP1 = (float*)(ws + 96 * MB);

    dim3 blk(256);

    // 1) casts + weight transposes
    cast_f32_bf16<<<4096, blk, 0, stream>>>(query, q_bf);
    cast_f32_bf16<<<4096, blk, 0, stream>>>(key, k_bf);
    cast_f32_bf16<<<4096, blk, 0, stream>>>(value, v_bf);
    transpose_cast_w<<<dim3(32, 32), blk, 0, stream>>>(wq, wqT, 1024, 1024);
    transpose_cast_w<<<dim3(32, 32), blk, 0, stream>>>(wk, wkT, 1024, 1024);
    transpose_cast_w<<<dim3(32, 32), blk, 0, stream>>>(wv, wvT, 1024, 1024);
    transpose_cast_w<<<dim3(32, 32), blk, 0, stream>>>(wo, woT, 1024, 1024);
    transpose_cast_w<<<dim3(32, 128), blk, 0, stream>>>(w1, w1T, 1024, 4096);
    transpose_cast_w<<<dim3(128, 32), blk, 0, stream>>>(w2, w2T, 4096, 1024);

    // 2) grouped QKV projection (one launch, 3 blocks/CU)
    gemm_qkv<<<dim3(32, 8, 3), blk, 0, stream>>>(q_bf, k_bf, v_bf, wqT, wkT, wvT,
                                                 bq, bk, bv, Qp, Kp, Vp);

    // 3) V transpose for PV A-operand
    transpose_v<<<dim3(64, 2, 32), blk, 0, stream>>>(Vp, VT);

    // 4) flash attention (4-way KV split, XCD-swizzled, no spill)
    flash_attn<<<dim3(64, 16, 2), blk, 0, stream>>>(Qp, Kp, VT, attn);

    // 5) WO projection, split-K=2 (f32 partials)
    gemm_bt<false, false, true><<<dim3(32, 8, 2), blk, 0, stream>>>(attn, 1024, woT, 1024, bo, woP0, woP1, nullptr, D_MODEL, 512);

    // 6) LN1: x = LN(woP0 + woP1 + query)
    ln_fused<<<4096, blk, 0, stream>>>(woP0, woP1, query, g1, beta1, x_f, x_b);

    // 7) FF1 + ReLU (bf16 out)
    gemm_bt<true, true, false><<<dim3(32, 32, 1), blk, 0, stream>>>(x_b, 1024, w1T, 1024, b1, nullptr, nullptr, h_b, FF_DIM, 1024);

    // 8) FF2, split-K=2 (f32 partials)
    gemm_bt<false, false, true><<<dim3(32, 8, 2), blk, 0, stream>>>(h_b, 4096, w2T, 4096, b2, ffP0, ffP1, nullptr, D_MODEL, 2048);

    // 9) LN2 -> d_out
    ln_fused<<<4096, blk, 0, stream>>>(ffP0, ffP1, x_f, g2, beta2, (float*)d_out, nullptr);
}

// Round 8
// 310.299 us; speedup vs baseline: 2.3042x; 1.1551x over previous
//
#include <hip/hip_runtime.h>
#include <hip/hip_bf16.h>
#include <cstdint>
#include <math.h>

typedef __bf16 bf16_t;
typedef __attribute__((ext_vector_type(2))) __bf16 bf16x2;
typedef __attribute__((ext_vector_type(4))) __bf16 bf16x4;
typedef __attribute__((ext_vector_type(8))) __bf16 bf16x8;
typedef __attribute__((ext_vector_type(4))) float f32x4;
typedef __attribute__((ext_vector_type(16))) float f32x16;
typedef __attribute__((ext_vector_type(2))) int int2v;
typedef __attribute__((ext_vector_type(4))) int int4v;

#define B_SZ 2
#define S_SZ 2048
#define D_MODEL 1024
#define NUM_HEADS 16
#define HEAD_DIM 64
#define FF_DIM 4096
#define M_ROWS (B_SZ * S_SZ)   // 4096

// exp2-domain scale: 0.125 (1/sqrt(64)) * log2(e)
#define CF 0.180336880f
#define THRC 2.0f   // defer-max threshold in exp2 domain -> P bounded by 4

// ---------------------------------------------------------------------------
__device__ __forceinline__ void gload_lds16(const void* g, void* lds) {
    __builtin_amdgcn_global_load_lds(
        (const __attribute__((address_space(1))) void*)(uintptr_t)g,
        (__attribute__((address_space(3))) void*)(uint32_t)(uintptr_t)lds,
        16, 0, 0);
}

__device__ __forceinline__ f32x4 mfma16(bf16x8 a, bf16x8 b, f32x4 c) {
    return __builtin_amdgcn_mfma_f32_16x16x32_bf16(a, b, c, 0, 0, 0);
}
__device__ __forceinline__ f32x16 mfma32(bf16x8 a, bf16x8 b, f32x16 c) {
    return __builtin_amdgcn_mfma_f32_32x32x16_bf16(a, b, c, 0, 0, 0);
}
__device__ __forceinline__ int2v plswap(int a, int b) {
    return __builtin_amdgcn_permlane32_swap(a, b, false, false);
}
__device__ __forceinline__ int packbf(float a, float b) {
    bf16x2 t; t[0] = (bf16_t)a; t[1] = (bf16_t)b;
    return __builtin_bit_cast(int, t);
}

// XCD-aware bijective swizzle helper (nwg must be divisible by 8)
__device__ __forceinline__ int xcd_swz(int lin, int nwg) {
    return (lin & 7) * (nwg >> 3) + (lin >> 3);
}

// ---------------------------------------------------------------------------
__global__ __launch_bounds__(256) void cast_f32_bf16(const float* __restrict__ in,
                                                     bf16_t* __restrict__ out) {
    size_t i = ((size_t)blockIdx.x * 256 + threadIdx.x) * 4;
    float4 v = *(const float4*)(in + i);
    bf16x4 o;
    o[0] = (bf16_t)v.x; o[1] = (bf16_t)v.y; o[2] = (bf16_t)v.z; o[3] = (bf16_t)v.w;
    *(bf16x4*)(out + i) = o;
}

// ---------------------------------------------------------------------------
__global__ __launch_bounds__(256) void transpose_cast_w(const float* __restrict__ W,
                                                        bf16_t* __restrict__ WT,
                                                        int K, int N) {
    __shared__ float t[32][33];
    int tid = threadIdx.x;
    int rr = tid >> 3, cc = (tid & 7) * 4;
    int k0 = blockIdx.x * 32, n0 = blockIdx.y * 32;
    float4 v = *(const float4*)(W + (size_t)(k0 + rr) * N + n0 + cc);
    t[rr][cc + 0] = v.x; t[rr][cc + 1] = v.y; t[rr][cc + 2] = v.z; t[rr][cc + 3] = v.w;
    __syncthreads();
    bf16x4 o;
    o[0] = (bf16_t)t[cc + 0][rr]; o[1] = (bf16_t)t[cc + 1][rr];
    o[2] = (bf16_t)t[cc + 2][rr]; o[3] = (bf16_t)t[cc + 3][rr];
    *(bf16x4*)(WT + (size_t)(n0 + rr) * K + k0 + cc) = o;
}

// ---------------------------------------------------------------------------
__global__ __launch_bounds__(256) void transpose_v(const bf16_t* __restrict__ Vp,
                                                   bf16_t* __restrict__ VT) {
    __shared__ bf16_t t[32][34];
    int tid = threadIdx.x;
    int rr = tid >> 3, cc = (tid & 7) * 4;
    int bh = blockIdx.z;
    int b = bh >> 4, h = bh & 15;
    int s0 = blockIdx.x * 32, d0 = blockIdx.y * 32;
    bf16x4 v = *(const bf16x4*)(Vp + ((size_t)(b * S_SZ + s0 + rr)) * D_MODEL + h * HEAD_DIM + d0 + cc);
    t[rr][cc + 0] = v[0]; t[rr][cc + 1] = v[1]; t[rr][cc + 2] = v[2]; t[rr][cc + 3] = v[3];
    __syncthreads();
    bf16x4 o;
    o[0] = t[cc + 0][rr]; o[1] = t[cc + 1][rr]; o[2] = t[cc + 2][rr]; o[3] = t[cc + 3][rr];
    *(bf16x4*)(VT + ((size_t)(bh * HEAD_DIM + d0 + rr)) * S_SZ + s0 + cc) = o;
}

// ---------------------------------------------------------------------------
// GEMM core: C[128x128 tile at m0,n0] = A[:,0:Klen] @ Bt[:,0:Klen]^T (+bias)
// ---------------------------------------------------------------------------
template<bool RELU, bool OUT_BF16, bool OUT_F32>
__device__ __forceinline__ void gemm_core(const bf16_t* __restrict__ A, int lda,
                                          const bf16_t* __restrict__ Bt, int ldb,
                                          const float* __restrict__ bias, bool useBias,
                                          float* __restrict__ Cf,
                                          bf16_t* __restrict__ Cb,
                                          int N, int Klen, int m0, int n0,
                                          bf16_t* sA, bf16_t* sB) {
    const int tid = threadIdx.x;
    const int lane = tid & 63, wave = tid >> 6;
    const int g = lane >> 4, r = lane & 15;
    const int wm = (wave >> 1) * 64, wn = (wave & 1) * 64;

    const bf16_t* Ablk = A + (size_t)m0 * lda;
    const bf16_t* Bblk = Bt + (size_t)n0 * ldb;
    const int c0 = wave * 64 + lane;
    const int c1 = c0 + 256;

    f32x4 acc[4][4];
#pragma unroll
    for (int i = 0; i < 4; i++)
#pragma unroll
        for (int j = 0; j < 4; j++)
#pragma unroll
            for (int e = 0; e < 4; e++) acc[i][j][e] = 0.f;

    for (int k0 = 0; k0 < Klen; k0 += 32) {
        gload_lds16(Ablk + (size_t)(c0 >> 2) * lda + k0 + (c0 & 3) * 8, sA + wave * 512);
        gload_lds16(Ablk + (size_t)(c1 >> 2) * lda + k0 + (c1 & 3) * 8, sA + 2048 + wave * 512);
        gload_lds16(Bblk + (size_t)(c0 >> 2) * ldb + k0 + (c0 & 3) * 8, sB + wave * 512);
        gload_lds16(Bblk + (size_t)(c1 >> 2) * ldb + k0 + (c1 & 3) * 8, sB + 2048 + wave * 512);
        __syncthreads();

        bf16x8 a[4], b[4];
#pragma unroll
        for (int i = 0; i < 4; i++)
            a[i] = *(const bf16x8*)(sA + (wm + i * 16 + r) * 32 + g * 8);
#pragma unroll
        for (int j = 0; j < 4; j++)
            b[j] = *(const bf16x8*)(sB + (wn + j * 16 + r) * 32 + g * 8);
#pragma unroll
        for (int i = 0; i < 4; i++)
#pragma unroll
            for (int j = 0; j < 4; j++)
                acc[i][j] = mfma16(a[i], b[j], acc[i][j]);
        __syncthreads();
    }

#pragma unroll
    for (int j = 0; j < 4; j++) {
        int n = n0 + wn + j * 16 + r;
        float bv = useBias ? bias[n] : 0.f;
#pragma unroll
        for (int i = 0; i < 4; i++) {
#pragma unroll
            for (int rr = 0; rr < 4; rr++) {
                int mrow = m0 + wm + i * 16 + g * 4 + rr;
                float val = acc[i][j][rr] + bv;
                if (RELU) val = fmaxf(val, 0.f);
                if (OUT_F32) Cf[(size_t)mrow * N + n] = val;
                if (OUT_BF16) Cb[(size_t)mrow * N + n] = (bf16_t)val;
            }
        }
    }
}

// split-K wrapper (z = K-chunk); XCD-swizzled grid
template<bool RELU, bool OUT_BF16, bool OUT_F32>
__global__ __launch_bounds__(256) void gemm_bt(const bf16_t* __restrict__ A, int lda,
                                               const bf16_t* __restrict__ Bt, int ldb,
                                               const float* __restrict__ bias,
                                               float* __restrict__ Cf0,
                                               float* __restrict__ Cf1,
                                               bf16_t* __restrict__ Cb,
                                               int N, int Klen) {
    __shared__ bf16_t sA[128 * 32];
    __shared__ bf16_t sB[128 * 32];
    const int lin = blockIdx.x + gridDim.x * (blockIdx.y + gridDim.y * blockIdx.z);
    const int nwg = gridDim.x * gridDim.y * gridDim.z;
    const int swz = xcd_swz(lin, nwg);
    const int bx = swz % gridDim.x;
    const int rest = swz / gridDim.x;
    const int by = rest % gridDim.y;
    const int bz = rest / gridDim.y;
    const int koff = bz * Klen;
    gemm_core<RELU, OUT_BF16, OUT_F32>(A + koff, lda, Bt + koff, ldb, bias, bz == 0,
                                       bz ? Cf1 : Cf0, Cb, N, Klen, bx * 128, by * 128, sA, sB);
}

// grouped QKV: z selects (A, W, bias, C)
__global__ __launch_bounds__(256) void gemm_qkv(const bf16_t* __restrict__ A0,
                                                const bf16_t* __restrict__ A1,
                                                const bf16_t* __restrict__ A2,
                                                const bf16_t* __restrict__ B0,
                                                const bf16_t* __restrict__ B1,
                                                const bf16_t* __restrict__ B2,
                                                const float* __restrict__ b0,
                                                const float* __restrict__ b1,
                                                const float* __restrict__ b2,
                                                bf16_t* __restrict__ C0,
                                                bf16_t* __restrict__ C1,
                                                bf16_t* __restrict__ C2) {
    __shared__ bf16_t sA[128 * 32];
    __shared__ bf16_t sB[128 * 32];
    const int lin = blockIdx.x + gridDim.x * (blockIdx.y + gridDim.y * blockIdx.z);
    const int nwg = gridDim.x * gridDim.y * gridDim.z;
    const int swz = xcd_swz(lin, nwg);
    const int bx = swz % gridDim.x;
    const int rest = swz / gridDim.x;
    const int by = rest % gridDim.y;
    const int bz = rest / gridDim.y;
    const bf16_t* A = bz == 0 ? A0 : bz == 1 ? A1 : A2;
    const bf16_t* Bt = bz == 0 ? B0 : bz == 1 ? B1 : B2;
    const float* bias = bz == 0 ? b0 : bz == 1 ? b1 : b2;
    bf16_t* C = bz == 0 ? C0 : bz == 1 ? C1 : C2;
    gemm_core<false, true, false>(A, 1024, Bt, 1024, bias, true,
                                  nullptr, C, 1024, 1024, bx * 128, by * 128, sA, sB);
}

// ---------------------------------------------------------------------------
// Flash attention v3: LDS-staged K/V (kills VMEM address divergence).
// Block = 256 thr = 4 waves = 2 q-subtiles (32 rows) x 2 kv-halves (1024 kv).
// Per 32-kv tile: 8 global_load_lds (16B) stage K[32][64] + V^T[64][32] into
// double-buffered LDS; all waves read MFMA fragments via ds_read_b128.
// K tile XOR-swizzled (linear LDS dest + inverse-swizzled GLOBAL source,
// m173 pattern): slot (row r, chunk c) holds global chunk c^(r&7); reader
// reads chunk g at slot g^(r&7). V tile linear (4-way conflict, negligible).
// One barrier per tile (vmcnt drain = pipeline sync). 2-way KV merge via
// LDS aliased over the (dead) staging buffers. No setprio (lockstep).
// Grid (S/64, H, B) = 1024 blocks, XCD-swizzled -> 4 blocks/CU.
// ---------------------------------------------------------------------------
__global__ __launch_bounds__(256) void flash_attn(const bf16_t* __restrict__ Qp,
                                                  const bf16_t* __restrict__ Kp,
                                                  const bf16_t* __restrict__ VT,
                                                  bf16_t* __restrict__ Oa) {
    __shared__ alignas(16) char lds[2][2][8192];  // [buf][half][K 4KB | V 4KB]
    const int tid = threadIdx.x;
    const int lane = tid & 63;
    const int wave = tid >> 6;
    const int half = wave >> 1;     // kv half this wave computes
    const int qt = wave & 1;        // q sub-tile
    const int l31 = lane & 31, hi = lane >> 5;

    // XCD swizzle: 1024 blocks = 8 XCDs x 128 (=4 heads' worth each)
    const int lin = blockIdx.x + (blockIdx.y << 5) + (blockIdx.z << 9);
    const int swz = (lin & 7) * 128 + (lin >> 3);
    const int qb = swz & 31;
    const int h = (swz >> 5) & 15;
    const int b = swz >> 9;

    const int q0 = qb * 64 + qt * 32;

    const bf16_t* Qb = Qp + (size_t)b * S_SZ * D_MODEL + h * HEAD_DIM;
    const bf16_t* Kb = Kp + (size_t)b * S_SZ * D_MODEL + h * HEAD_DIM;
    const bf16_t* Vb = VT + ((size_t)(b * NUM_HEADS + h) * HEAD_DIM) * S_SZ;

    // stage roles: wave0->K half0, wave1->K half1, wave2->V half0, wave3->V half1
    const int sh = wave & 1;
    const int skvbase = sh * (S_SZ / 2);
    // per-lane constant source offsets (elements)
    const bf16_t* Ksrc = Kb + (size_t)(lane >> 3) * D_MODEL + ((lane & 7) ^ (lane >> 3)) * 8;
    const bf16_t* Vsrc = Vb + (size_t)(lane >> 2) * S_SZ + (lane & 3) * 8;

    auto stage = [&](int buf, int t) {
        if (wave < 2) {
            char* kb = &lds[buf][sh][0];
            const bf16_t* src = Ksrc + (size_t)(skvbase + t * 32) * D_MODEL;
#pragma unroll
            for (int ii = 0; ii < 4; ii++)
                gload_lds16(src + (size_t)(ii * 8) * D_MODEL, kb + ii * 1024 + lane * 16);
        } else {
            char* vb = &lds[buf][sh][4096];
            const bf16_t* src = Vsrc + skvbase + t * 32;
#pragma unroll
            for (int ii = 0; ii < 4; ii++)
                gload_lds16(src + (size_t)(ii * 16) * S_SZ, vb + ii * 1024 + lane * 16);
        }
    };

    // Q B-frags: lane holds Q[q0+l31][d = kb*16 + hi*8 + e]
    bf16x8 bq[4];
#pragma unroll
    for (int kb = 0; kb < 4; kb++)
        bq[kb] = *(const bf16x8*)(Qb + (size_t)(q0 + l31) * D_MODEL + kb * 16 + hi * 8);

    f32x16 o0, o1;
#pragma unroll
    for (int e = 0; e < 16; e++) { o0[e] = 0.f; o1[e] = 0.f; }
    float mC = -1e30f, l_run = 0.f;

    // prologue: stage tile 0
    stage(0, 0);
    __syncthreads();

    for (int t = 0; t < 32; t++) {
        const int buf = t & 1;
        if (t + 1 < 32) stage(buf ^ 1, t + 1);

        const char* kt = &lds[buf][half][0];
        const char* vt = &lds[buf][half][4096];

        // QK^T (swapped): s reg e -> E[kv = (e&3)+8*(e>>2)+4*hi][q = l31]
        bf16x8 ak[4];
#pragma unroll
        for (int kb = 0; kb < 4; kb++)
            ak[kb] = *(const bf16x8*)(kt + l31 * 128 + (((kb << 1) | hi) ^ (l31 & 7)) * 16);
        f32x16 s;
#pragma unroll
        for (int e = 0; e < 16; e++) s[e] = 0.f;
#pragma unroll
        for (int kb = 0; kb < 4; kb++) s = mfma32(ak[kb], bq[kb], s);

        // in-lane max of 16
        float ma = fmaxf(fmaxf(s[0], s[1]), fmaxf(s[2], s[3]));
        float mb = fmaxf(fmaxf(s[4], s[5]), fmaxf(s[6], s[7]));
        float mc = fmaxf(fmaxf(s[8], s[9]), fmaxf(s[10], s[11]));
        float md = fmaxf(fmaxf(s[12], s[13]), fmaxf(s[14], s[15]));
        float pmaxC = fmaxf(fmaxf(ma, mb), fmaxf(mc, md)) * CF;

        // defer-max (wave-wide __all covers both hi halves of this wave's kv)
        if (!__all(pmaxC <= mC + THRC)) {
            int2v pr = plswap(__float_as_int(pmaxC), __float_as_int(pmaxC));
            float rowmaxC = fmaxf(__int_as_float(pr[0]), __int_as_float(pr[1]));
            float mnewC = fmaxf(mC, rowmaxC);
            float alpha = exp2f(mC - mnewC);
            mC = mnewC;
            l_run *= alpha;
#pragma unroll
            for (int e = 0; e < 16; e++) { o0[e] *= alpha; o1[e] *= alpha; }
        }

        // P = 2^(s*CF - mC); in-lane partial sum
#pragma unroll
        for (int e = 0; e < 16; e++) s[e] = exp2f(__builtin_fmaf(s[e], CF, -mC));
        float t0 = (s[0] + s[1]) + (s[2] + s[3]);
        float t1 = (s[4] + s[5]) + (s[6] + s[7]);
        float t2 = (s[8] + s[9]) + (s[10] + s[11]);
        float t3 = (s[12] + s[13]) + (s[14] + s[15]);
        l_run += (t0 + t1) + (t2 + t3);

        // V frags + pack P -> PV
        bf16x8 av[4];
#pragma unroll
        for (int db = 0; db < 2; db++)
#pragma unroll
            for (int kb = 0; kb < 2; kb++)
                av[db * 2 + kb] = *(const bf16x8*)(vt + (db * 32 + l31) * 64 + ((kb << 1) | hi) * 16);
#pragma unroll
        for (int kb2 = 0; kb2 < 2; kb2++) {
            const int bse = kb2 * 8;
            int W0 = packbf(s[bse + 0], s[bse + 1]);
            int W1 = packbf(s[bse + 2], s[bse + 3]);
            int W2 = packbf(s[bse + 4], s[bse + 5]);
            int W3 = packbf(s[bse + 6], s[bse + 7]);
            int2v r02 = plswap(W0, W2);
            int2v r13 = plswap(W1, W3);
            int4v fw; fw[0] = r02[0]; fw[1] = r13[0]; fw[2] = r02[1]; fw[3] = r13[1];
            bf16x8 pf = __builtin_bit_cast(bf16x8, fw);
            o0 = mfma32(av[kb2], pf, o0);
            o1 = mfma32(av[2 + kb2], pf, o1);
        }
        __syncthreads();   // staged tile t+1 visible; buf free for t+2's stage
    }

    // cross-half(hi) l combine: full half-l for q = l31
    int2v lp = plswap(__float_as_int(l_run), __float_as_int(l_run));
    l_run = __int_as_float(lp[0]) + __int_as_float(lp[1]);

    // 2-way KV-half merge via LDS aliased over staging buffers (dead now;
    // last loop iteration ended with __syncthreads()).
    float (*obuf)[2][64] = (float (*)[2][64])(&lds[0][0][0]);          // 16 KB
    float (*mrg)[64][2] = (float (*)[64][2])(&lds[0][0][0] + 16384);   // 1 KB
    if (half == 1) {
        mrg[qt][lane][0] = mC;
        mrg[qt][lane][1] = l_run;
#pragma unroll
        for (int e = 0; e < 16; e++) {
            obuf[e][qt][lane] = o0[e];
            obuf[16 + e][qt][lane] = o1[e];
        }
    }
    __syncthreads();
    if (half == 0) {
        const float m2C = mrg[qt][lane][0], l2 = mrg[qt][lane][1];
        const float mm = fmaxf(mC, m2C);
        const float e1 = exp2f(mC - mm);
        const float e2 = exp2f(m2C - mm);
        const float linv = 1.f / (l_run * e1 + l2 * e2);
        bf16_t* Orow = Oa + ((size_t)b * S_SZ + q0 + l31) * D_MODEL + h * HEAD_DIM;
#pragma unroll
        for (int db = 0; db < 2; db++) {
#pragma unroll
            for (int rq = 0; rq < 4; rq++) {
                bf16x4 st;
#pragma unroll
                for (int i = 0; i < 4; i++) {
                    const int e = rq * 4 + i;
                    const float own = db ? o1[e] : o0[e];
                    const float oth = obuf[db * 16 + e][qt][lane];
                    st[i] = (bf16_t)((own * e1 + oth * e2) * linv);
                }
                *(bf16x4*)(Orow + db * 32 + rq * 8 + hi * 4) = st;
            }
        }
    }
}

// ---------------------------------------------------------------------------
// LayerNorm over 1024 with fused residual + optional second addend
// ---------------------------------------------------------------------------
__global__ __launch_bounds__(256) void ln_fused(const float* __restrict__ A,
                                                const float* __restrict__ A2,
                                                const float* __restrict__ R,
                                                const float* __restrict__ gamma,
                                                const float* __restrict__ beta,
                                                float* __restrict__ Xf,
                                                bf16_t* __restrict__ Xb) {
    __shared__ float red[8];
    int row = blockIdx.x, tid = threadIdx.x;
    size_t base = (size_t)row * D_MODEL + tid * 4;
    float4 a = *(const float4*)(A + base);
    float4 rv = *(const float4*)(R + base);
    float v0 = a.x + rv.x, v1 = a.y + rv.y, v2 = a.z + rv.z, v3 = a.w + rv.w;
    if (A2) {
        float4 a2 = *(const float4*)(A2 + base);
        v0 += a2.x; v1 += a2.y; v2 += a2.z; v3 += a2.w;
    }
    float s = v0 + v1 + v2 + v3;
    float q = v0 * v0 + v1 * v1 + v2 * v2 + v3 * v3;
#pragma unroll
    for (int off = 32; off; off >>= 1) { s += __shfl_down(s, off); q += __shfl_down(q, off); }
    if ((tid & 63) == 0) { red[tid >> 6] = s; red[4 + (tid >> 6)] = q; }
    __syncthreads();
    s = red[0] + red[1] + red[2] + red[3];
    q = red[4] + red[5] + red[6] + red[7];
    float mean = s * (1.f / D_MODEL);
    float var = q * (1.f / D_MODEL) - mean * mean;
    float rstd = rsqrtf(var + 1e-5f);
    float4 gm = *(const float4*)(gamma + tid * 4);
    float4 bt = *(const float4*)(beta + tid * 4);
    float y0 = (v0 - mean) * rstd * gm.x + bt.x;
    float y1 = (v1 - mean) * rstd * gm.y + bt.y;
    float y2 = (v2 - mean) * rstd * gm.z + bt.z;
    float y3 = (v3 - mean) * rstd * gm.w + bt.w;
    float4 yo; yo.x = y0; yo.y = y1; yo.z = y2; yo.w = y3;
    *(float4*)(Xf + base) = yo;
    if (Xb) {
        bf16x4 ob; ob[0] = (bf16_t)y0; ob[1] = (bf16_t)y1; ob[2] = (bf16_t)y2; ob[3] = (bf16_t)y3;
        *(bf16x4*)(Xb + base) = ob;
    }
}

// ---------------------------------------------------------------------------
extern "C" void kernel_launch(void* const* d_in, const int* in_sizes, int n_in,
                              void* d_out, int out_size, void* d_ws, size_t ws_size,
                              hipStream_t stream) {
    const float* value = (const float*)d_in[0];
    const float* key   = (const float*)d_in[1];
    const float* query = (const float*)d_in[2];
    const float* wq = (const float*)d_in[3];
    const float* bq = (const float*)d_in[4];
    const float* wk = (const float*)d_in[5];
    const float* bk = (const float*)d_in[6];
    const float* wv = (const float*)d_in[7];
    const float* bv = (const float*)d_in[8];
    const float* wo = (const float*)d_in[9];
    const float* bo = (const float*)d_in[10];
    const float* g1 = (const float*)d_in[11];
    const float* beta1 = (const float*)d_in[12];
    const float* w1 = (const float*)d_in[13];
    const float* b1 = (const float*)d_in[14];
    const float* w2 = (const float*)d_in[15];
    const float* b2 = (const float*)d_in[16];
    const float* g2 = (const float*)d_in[17];
    const float* beta2 = (const float*)d_in[18];
    (void)in_sizes; (void)n_in; (void)out_size; (void)ws_size;

    const size_t MB = 1ull << 20;
    char* ws = (char*)d_ws;
    bf16_t* wqT = (bf16_t*)(ws + 0 * MB);
    bf16_t* wkT = (bf16_t*)(ws + 2 * MB);
    bf16_t* wvT = (bf16_t*)(ws + 4 * MB);
    bf16_t* woT = (bf16_t*)(ws + 6 * MB);
    bf16_t* w1T = (bf16_t*)(ws + 8 * MB);
    bf16_t* w2T = (bf16_t*)(ws + 16 * MB);
    bf16_t* q_bf = (bf16_t*)(ws + 24 * MB);
    bf16_t* k_bf = (bf16_t*)(ws + 32 * MB);
    bf16_t* v_bf = (bf16_t*)(ws + 40 * MB);
    bf16_t* Qp  = (bf16_t*)(ws + 48 * MB);
    bf16_t* Kp  = (bf16_t*)(ws + 56 * MB);
    bf16_t* Vp  = (bf16_t*)(ws + 64 * MB);
    bf16_t* VT  = (bf16_t*)(ws + 72 * MB);
    bf16_t* attn = (bf16_t*)(ws + 24 * MB);   // reuse q_bf (dead after QKV gemm)
    float*  woP0 = (float*)(ws + 32 * MB);    // reuse k_bf..Qp (dead after flash)
    float*  woP1 = (float*)(ws + 48 * MB);
    float*  x_f = (float*)(ws + 64 * MB);     // reuse Vp/VT (dead after flash)
    bf16_t* x_b = (bf16_t*)(ws + 24 * MB);    // reuse attn (dead after WO gemm)
    bf16_t* h_b = (bf16_t*)(ws + 32 * MB);    // reuse woP (dead after LN1), 32MB
    float*  ffP0 = (float*)(ws + 80 * MB);
    float*  ffP1 = (float*)(ws + 96 * MB);

    dim3 blk(256);

    // 1) casts + weight transposes
    cast_f32_bf16<<<4096, blk, 0, stream>>>(query, q_bf);
    cast_f32_bf16<<<4096, blk, 0, stream>>>(key, k_bf);
    cast_f32_bf16<<<4096, blk, 0, stream>>>(value, v_bf);
    transpose_cast_w<<<dim3(32, 32), blk, 0, stream>>>(wq, wqT, 1024, 1024);
    transpose_cast_w<<<dim3(32, 32), blk, 0, stream>>>(wk, wkT, 1024, 1024);
    transpose_cast_w<<<dim3(32, 32), blk, 0, stream>>>(wv, wvT, 1024, 1024);
    transpose_cast_w<<<dim3(32, 32), blk, 0, stream>>>(wo, woT, 1024, 1024);
    transpose_cast_w<<<dim3(32, 128), blk, 0, stream>>>(w1, w1T, 1024, 4096);
    transpose_cast_w<<<dim3(128, 32), blk, 0, stream>>>(w2, w2T, 4096, 1024);

    // 2) grouped QKV projection
    gemm_qkv<<<dim3(32, 8, 3), blk, 0, stream>>>(q_bf, k_bf, v_bf, wqT, wkT, wvT,
                                                 bq, bk, bv, Qp, Kp, Vp);

    // 3) V transpose for PV A-operand
    transpose_v<<<dim3(64, 2, 32), blk, 0, stream>>>(Vp, VT);

    // 4) flash attention v3 (LDS-staged K/V)
    flash_attn<<<dim3(32, 16, 2), blk, 0, stream>>>(Qp, Kp, VT, attn);

    // 5) WO projection, split-K=2 (f32 partials)
    gemm_bt<false, false, true><<<dim3(32, 8, 2), blk, 0, stream>>>(attn, 1024, woT, 1024, bo, woP0, woP1, nullptr, D_MODEL, 512);

    // 6) LN1: x = LN(woP0 + woP1 + query)
    ln_fused<<<4096, blk, 0, stream>>>(woP0, woP1, query, g1, beta1, x_f, x_b);

    // 7) FF1 + ReLU (bf16 out)
    gemm_bt<true, true, false><<<dim3(32, 32, 1), blk, 0, stream>>>(x_b, 1024, w1T, 1024, b1, nullptr, nullptr, h_b, FF_DIM, 1024);

    // 8) FF2, split-K=2 (f32 partials)
    gemm_bt<false, false, true><<<dim3(32, 8, 2), blk, 0, stream>>>(h_b, 4096, w2T, 4096, b2, ffP0, ffP1, nullptr, D_MODEL, 2048);

    // 9) LN2 -> d_out
    ln_fused<<<4096, blk, 0, stream>>>(ffP0, ffP1, x_f, g2, beta2, (float*)d_out, nullptr);
}

// Round 9
// 301.237 us; speedup vs baseline: 2.3735x; 1.0301x over previous
//
#include <hip/hip_runtime.h>
#include <hip/hip_bf16.h>
#include <cstdint>
#include <math.h>

typedef __bf16 bf16_t;
typedef __attribute__((ext_vector_type(2))) __bf16 bf16x2;
typedef __attribute__((ext_vector_type(4))) __bf16 bf16x4;
typedef __attribute__((ext_vector_type(8))) __bf16 bf16x8;
typedef __attribute__((ext_vector_type(4))) float f32x4;
typedef __attribute__((ext_vector_type(16))) float f32x16;
typedef __attribute__((ext_vector_type(2))) int int2v;
typedef __attribute__((ext_vector_type(4))) int int4v;

#define B_SZ 2
#define S_SZ 2048
#define D_MODEL 1024
#define NUM_HEADS 16
#define HEAD_DIM 64
#define FF_DIM 4096
#define M_ROWS (B_SZ * S_SZ)   // 4096

// exp2-domain scale: 0.125 (1/sqrt(64)) * log2(e)
#define CF 0.180336880f
#define THRC 2.0f   // defer-max threshold in exp2 domain -> P bounded by 4

// ---------------------------------------------------------------------------
__device__ __forceinline__ void gload_lds16(const void* g, void* lds) {
    __builtin_amdgcn_global_load_lds(
        (const __attribute__((address_space(1))) void*)(uintptr_t)g,
        (__attribute__((address_space(3))) void*)(uint32_t)(uintptr_t)lds,
        16, 0, 0);
}

__device__ __forceinline__ f32x4 mfma16(bf16x8 a, bf16x8 b, f32x4 c) {
    return __builtin_amdgcn_mfma_f32_16x16x32_bf16(a, b, c, 0, 0, 0);
}
__device__ __forceinline__ f32x16 mfma32(bf16x8 a, bf16x8 b, f32x16 c) {
    return __builtin_amdgcn_mfma_f32_32x32x16_bf16(a, b, c, 0, 0, 0);
}
__device__ __forceinline__ int2v plswap(int a, int b) {
    return __builtin_amdgcn_permlane32_swap(a, b, false, false);
}
__device__ __forceinline__ int packbf(float a, float b) {
    bf16x2 t; t[0] = (bf16_t)a; t[1] = (bf16_t)b;
    return __builtin_bit_cast(int, t);
}

// XCD-aware bijective swizzle helper (nwg must be divisible by 8)
__device__ __forceinline__ int xcd_swz(int lin, int nwg) {
    return (lin & 7) * (nwg >> 3) + (lin >> 3);
}

// ---------------------------------------------------------------------------
__global__ __launch_bounds__(256) void cast_f32_bf16(const float* __restrict__ in,
                                                     bf16_t* __restrict__ out) {
    size_t i = ((size_t)blockIdx.x * 256 + threadIdx.x) * 4;
    float4 v = *(const float4*)(in + i);
    bf16x4 o;
    o[0] = (bf16_t)v.x; o[1] = (bf16_t)v.y; o[2] = (bf16_t)v.z; o[3] = (bf16_t)v.w;
    *(bf16x4*)(out + i) = o;
}

// ---------------------------------------------------------------------------
__global__ __launch_bounds__(256) void transpose_cast_w(const float* __restrict__ W,
                                                        bf16_t* __restrict__ WT,
                                                        int K, int N) {
    __shared__ float t[32][33];
    int tid = threadIdx.x;
    int rr = tid >> 3, cc = (tid & 7) * 4;
    int k0 = blockIdx.x * 32, n0 = blockIdx.y * 32;
    float4 v = *(const float4*)(W + (size_t)(k0 + rr) * N + n0 + cc);
    t[rr][cc + 0] = v.x; t[rr][cc + 1] = v.y; t[rr][cc + 2] = v.z; t[rr][cc + 3] = v.w;
    __syncthreads();
    bf16x4 o;
    o[0] = (bf16_t)t[cc + 0][rr]; o[1] = (bf16_t)t[cc + 1][rr];
    o[2] = (bf16_t)t[cc + 2][rr]; o[3] = (bf16_t)t[cc + 3][rr];
    *(bf16x4*)(WT + (size_t)(n0 + rr) * K + k0 + cc) = o;
}

// ---------------------------------------------------------------------------
__global__ __launch_bounds__(256) void transpose_v(const bf16_t* __restrict__ Vp,
                                                   bf16_t* __restrict__ VT) {
    __shared__ bf16_t t[32][34];
    int tid = threadIdx.x;
    int rr = tid >> 3, cc = (tid & 7) * 4;
    int bh = blockIdx.z;
    int b = bh >> 4, h = bh & 15;
    int s0 = blockIdx.x * 32, d0 = blockIdx.y * 32;
    bf16x4 v = *(const bf16x4*)(Vp + ((size_t)(b * S_SZ + s0 + rr)) * D_MODEL + h * HEAD_DIM + d0 + cc);
    t[rr][cc + 0] = v[0]; t[rr][cc + 1] = v[1]; t[rr][cc + 2] = v[2]; t[rr][cc + 3] = v[3];
    __syncthreads();
    bf16x4 o;
    o[0] = t[cc + 0][rr]; o[1] = t[cc + 1][rr]; o[2] = t[cc + 2][rr]; o[3] = t[cc + 3][rr];
    *(bf16x4*)(VT + ((size_t)(bh * HEAD_DIM + d0 + rr)) * S_SZ + s0 + cc) = o;
}

// ---------------------------------------------------------------------------
// GEMM core: C[128x128 tile at m0,n0] = A[:,0:Klen] @ Bt[:,0:Klen]^T (+bias)
// ---------------------------------------------------------------------------
template<bool RELU, bool OUT_BF16, bool OUT_F32>
__device__ __forceinline__ void gemm_core(const bf16_t* __restrict__ A, int lda,
                                          const bf16_t* __restrict__ Bt, int ldb,
                                          const float* __restrict__ bias, bool useBias,
                                          float* __restrict__ Cf,
                                          bf16_t* __restrict__ Cb,
                                          int N, int Klen, int m0, int n0,
                                          bf16_t* sA, bf16_t* sB) {
    const int tid = threadIdx.x;
    const int lane = tid & 63, wave = tid >> 6;
    const int g = lane >> 4, r = lane & 15;
    const int wm = (wave >> 1) * 64, wn = (wave & 1) * 64;

    const bf16_t* Ablk = A + (size_t)m0 * lda;
    const bf16_t* Bblk = Bt + (size_t)n0 * ldb;
    const int c0 = wave * 64 + lane;
    const int c1 = c0 + 256;

    f32x4 acc[4][4];
#pragma unroll
    for (int i = 0; i < 4; i++)
#pragma unroll
        for (int j = 0; j < 4; j++)
#pragma unroll
            for (int e = 0; e < 4; e++) acc[i][j][e] = 0.f;

    for (int k0 = 0; k0 < Klen; k0 += 32) {
        gload_lds16(Ablk + (size_t)(c0 >> 2) * lda + k0 + (c0 & 3) * 8, sA + wave * 512);
        gload_lds16(Ablk + (size_t)(c1 >> 2) * lda + k0 + (c1 & 3) * 8, sA + 2048 + wave * 512);
        gload_lds16(Bblk + (size_t)(c0 >> 2) * ldb + k0 + (c0 & 3) * 8, sB + wave * 512);
        gload_lds16(Bblk + (size_t)(c1 >> 2) * ldb + k0 + (c1 & 3) * 8, sB + 2048 + wave * 512);
        __syncthreads();

        bf16x8 a[4], b[4];
#pragma unroll
        for (int i = 0; i < 4; i++)
            a[i] = *(const bf16x8*)(sA + (wm + i * 16 + r) * 32 + g * 8);
#pragma unroll
        for (int j = 0; j < 4; j++)
            b[j] = *(const bf16x8*)(sB + (wn + j * 16 + r) * 32 + g * 8);
#pragma unroll
        for (int i = 0; i < 4; i++)
#pragma unroll
            for (int j = 0; j < 4; j++)
                acc[i][j] = mfma16(a[i], b[j], acc[i][j]);
        __syncthreads();
    }

#pragma unroll
    for (int j = 0; j < 4; j++) {
        int n = n0 + wn + j * 16 + r;
        float bv = useBias ? bias[n] : 0.f;
#pragma unroll
        for (int i = 0; i < 4; i++) {
#pragma unroll
            for (int rr = 0; rr < 4; rr++) {
                int mrow = m0 + wm + i * 16 + g * 4 + rr;
                float val = acc[i][j][rr] + bv;
                if (RELU) val = fmaxf(val, 0.f);
                if (OUT_F32) Cf[(size_t)mrow * N + n] = val;
                if (OUT_BF16) Cb[(size_t)mrow * N + n] = (bf16_t)val;
            }
        }
    }
}

// split-K wrapper (z = K-chunk); XCD-swizzled grid
template<bool RELU, bool OUT_BF16, bool OUT_F32>
__global__ __launch_bounds__(256) void gemm_bt(const bf16_t* __restrict__ A, int lda,
                                               const bf16_t* __restrict__ Bt, int ldb,
                                               const float* __restrict__ bias,
                                               float* __restrict__ Cf0,
                                               float* __restrict__ Cf1,
                                               bf16_t* __restrict__ Cb,
                                               int N, int Klen) {
    __shared__ bf16_t sA[128 * 32];
    __shared__ bf16_t sB[128 * 32];
    const int lin = blockIdx.x + gridDim.x * (blockIdx.y + gridDim.y * blockIdx.z);
    const int nwg = gridDim.x * gridDim.y * gridDim.z;
    const int swz = xcd_swz(lin, nwg);
    const int bx = swz % gridDim.x;
    const int rest = swz / gridDim.x;
    const int by = rest % gridDim.y;
    const int bz = rest / gridDim.y;
    const int koff = bz * Klen;
    gemm_core<RELU, OUT_BF16, OUT_F32>(A + koff, lda, Bt + koff, ldb, bias, bz == 0,
                                       bz ? Cf1 : Cf0, Cb, N, Klen, bx * 128, by * 128, sA, sB);
}

// grouped QKV: z selects (A, W, bias, C)
__global__ __launch_bounds__(256) void gemm_qkv(const bf16_t* __restrict__ A0,
                                                const bf16_t* __restrict__ A1,
                                                const bf16_t* __restrict__ A2,
                                                const bf16_t* __restrict__ B0,
                                                const bf16_t* __restrict__ B1,
                                                const bf16_t* __restrict__ B2,
                                                const float* __restrict__ b0,
                                                const float* __restrict__ b1,
                                                const float* __restrict__ b2,
                                                bf16_t* __restrict__ C0,
                                                bf16_t* __restrict__ C1,
                                                bf16_t* __restrict__ C2) {
    __shared__ bf16_t sA[128 * 32];
    __shared__ bf16_t sB[128 * 32];
    const int lin = blockIdx.x + gridDim.x * (blockIdx.y + gridDim.y * blockIdx.z);
    const int nwg = gridDim.x * gridDim.y * gridDim.z;
    const int swz = xcd_swz(lin, nwg);
    const int bx = swz % gridDim.x;
    const int rest = swz / gridDim.x;
    const int by = rest % gridDim.y;
    const int bz = rest / gridDim.y;
    const bf16_t* A = bz == 0 ? A0 : bz == 1 ? A1 : A2;
    const bf16_t* Bt = bz == 0 ? B0 : bz == 1 ? B1 : B2;
    const float* bias = bz == 0 ? b0 : bz == 1 ? b1 : b2;
    bf16_t* C = bz == 0 ? C0 : bz == 1 ? C1 : C2;
    gemm_core<false, true, false>(A, 1024, Bt, 1024, bias, true,
                                  nullptr, C, 1024, 1024, bx * 128, by * 128, sA, sB);
}

// ---------------------------------------------------------------------------
// Flash attention v4: LDS-staged K/V, BOTH tiles XOR-swizzled conflict-free,
// manual x2 unroll (compile-time buffers, hoisted LDS addrs), running global
// stage pointers, V-fragment reads issued before QK^T (latency under MFMA).
// K[32 kv][8 chunks]: slot c holds global chunk c^(kv&7); reader slot
//   c^(l31&7)  -> rows 0-7 cover 32 banks (verified).
// V[64 d][4 chunks]: slot c holds global chunk c^((d>>1)&3); reader slot
//   c^((l31>>1)&3) -> (row&1, slot) pairs cover all 8x4-bank groups.
// Block = 4 waves = 2 q-subtiles x 2 kv-halves; 1 barrier/tile; 2-way merge.
// ---------------------------------------------------------------------------
__device__ __forceinline__ void flash_tile(
    const char* kt, const char* vt, int l31, int hi,
    const bf16x8 (&bq)[4],
    f32x16& o0, f32x16& o1, float& mC, float& l_run)
{
    // K frags (conflict-free swizzled)
    bf16x8 ak[4];
#pragma unroll
    for (int kb = 0; kb < 4; kb++)
        ak[kb] = *(const bf16x8*)(kt + l31 * 128 + (((kb << 1) | hi) ^ (l31 & 7)) * 16);
    // V frags (conflict-free swizzled) - issued early, consumed after softmax
    bf16x8 av[4];
#pragma unroll
    for (int db = 0; db < 2; db++)
#pragma unroll
        for (int kb = 0; kb < 2; kb++)
            av[db * 2 + kb] = *(const bf16x8*)(vt + (db * 32 + l31) * 64 + ((((kb << 1) | hi)) ^ ((l31 >> 1) & 3)) * 16);

    // QK^T (swapped): s reg e -> E[kv = (e&3)+8*(e>>2)+4*hi][q = l31]
    f32x16 s;
#pragma unroll
    for (int e = 0; e < 16; e++) s[e] = 0.f;
#pragma unroll
    for (int kb = 0; kb < 4; kb++) s = mfma32(ak[kb], bq[kb], s);

    // in-lane max of 16
    float ma = fmaxf(fmaxf(s[0], s[1]), fmaxf(s[2], s[3]));
    float mb = fmaxf(fmaxf(s[4], s[5]), fmaxf(s[6], s[7]));
    float mc = fmaxf(fmaxf(s[8], s[9]), fmaxf(s[10], s[11]));
    float md = fmaxf(fmaxf(s[12], s[13]), fmaxf(s[14], s[15]));
    float pmaxC = fmaxf(fmaxf(ma, mb), fmaxf(mc, md)) * CF;

    // defer-max (wave-wide __all covers both hi halves of this wave's kv)
    if (!__all(pmaxC <= mC + THRC)) {
        int2v pr = plswap(__float_as_int(pmaxC), __float_as_int(pmaxC));
        float rowmaxC = fmaxf(__int_as_float(pr[0]), __int_as_float(pr[1]));
        float mnewC = fmaxf(mC, rowmaxC);
        float alpha = exp2f(mC - mnewC);
        mC = mnewC;
        l_run *= alpha;
#pragma unroll
        for (int e = 0; e < 16; e++) { o0[e] *= alpha; o1[e] *= alpha; }
    }

    // P = 2^(s*CF - mC); in-lane partial sum
#pragma unroll
    for (int e = 0; e < 16; e++) s[e] = exp2f(__builtin_fmaf(s[e], CF, -mC));
    float t0 = (s[0] + s[1]) + (s[2] + s[3]);
    float t1 = (s[4] + s[5]) + (s[6] + s[7]);
    float t2 = (s[8] + s[9]) + (s[10] + s[11]);
    float t3 = (s[12] + s[13]) + (s[14] + s[15]);
    l_run += (t0 + t1) + (t2 + t3);

    // pack P -> bf16 B-frags via permlane32_swap; PV
#pragma unroll
    for (int kb2 = 0; kb2 < 2; kb2++) {
        const int bse = kb2 * 8;
        int W0 = packbf(s[bse + 0], s[bse + 1]);
        int W1 = packbf(s[bse + 2], s[bse + 3]);
        int W2 = packbf(s[bse + 4], s[bse + 5]);
        int W3 = packbf(s[bse + 6], s[bse + 7]);
        int2v r02 = plswap(W0, W2);
        int2v r13 = plswap(W1, W3);
        int4v fw; fw[0] = r02[0]; fw[1] = r13[0]; fw[2] = r02[1]; fw[3] = r13[1];
        bf16x8 pf = __builtin_bit_cast(bf16x8, fw);
        o0 = mfma32(av[kb2], pf, o0);
        o1 = mfma32(av[2 + kb2], pf, o1);
    }
}

__global__ __launch_bounds__(256) void flash_attn(const bf16_t* __restrict__ Qp,
                                                  const bf16_t* __restrict__ Kp,
                                                  const bf16_t* __restrict__ VT,
                                                  bf16_t* __restrict__ Oa) {
    __shared__ alignas(16) char lds[2][2][8192];  // [buf][half][K 4KB | V 4KB]
    const int tid = threadIdx.x;
    const int lane = tid & 63;
    const int wave = tid >> 6;
    const int half = wave >> 1;     // kv half this wave computes
    const int qt = wave & 1;        // q sub-tile
    const int l31 = lane & 31, hi = lane >> 5;

    // XCD swizzle: 1024 blocks = 8 XCDs x 128 (=4 heads' worth each)
    const int lin = blockIdx.x + (blockIdx.y << 5) + (blockIdx.z << 9);
    const int swz = (lin & 7) * 128 + (lin >> 3);
    const int qb = swz & 31;
    const int h = (swz >> 5) & 15;
    const int b = swz >> 9;

    const int q0 = qb * 64 + qt * 32;

    const bf16_t* Qb = Qp + (size_t)b * S_SZ * D_MODEL + h * HEAD_DIM;
    const bf16_t* Kb = Kp + (size_t)b * S_SZ * D_MODEL + h * HEAD_DIM;
    const bf16_t* Vb = VT + ((size_t)(b * NUM_HEADS + h) * HEAD_DIM) * S_SZ;

    // stage roles: wave0/1 -> K halves 0/1; wave2/3 -> V halves 0/1
    const int sh = wave & 1;
    const int skvbase = sh * (S_SZ / 2);
    const bool kRole = wave < 2;

    // running source pointer (pre-swizzled per-lane chunk) + constant strides
    const bf16_t* src_run;
    size_t inner_stride;   // elements between the 4 gloads of one stage
    size_t tile_stride;    // elements between consecutive tiles
    char* dst0;
    char* dst1;
    if (kRole) {
        src_run = Kb + (size_t)(skvbase + (lane >> 3)) * D_MODEL + ((lane & 7) ^ (lane >> 3)) * 8;
        inner_stride = (size_t)8 * D_MODEL;
        tile_stride = (size_t)32 * D_MODEL;
        dst0 = &lds[0][sh][0] + lane * 16;
        dst1 = &lds[1][sh][0] + lane * 16;
    } else {
        src_run = Vb + (size_t)(lane >> 2) * S_SZ + skvbase + ((lane & 3) ^ ((lane >> 3) & 3)) * 8;
        inner_stride = (size_t)16 * S_SZ;
        tile_stride = 32;
        dst0 = &lds[0][sh][4096] + lane * 16;
        dst1 = &lds[1][sh][4096] + lane * 16;
    }

    // Q B-frags: lane holds Q[q0+l31][d = kb*16 + hi*8 + e]
    bf16x8 bq[4];
#pragma unroll
    for (int kb = 0; kb < 4; kb++)
        bq[kb] = *(const bf16x8*)(Qb + (size_t)(q0 + l31) * D_MODEL + kb * 16 + hi * 8);

    f32x16 o0, o1;
#pragma unroll
    for (int e = 0; e < 16; e++) { o0[e] = 0.f; o1[e] = 0.f; }
    float mC = -1e30f, l_run = 0.f;

    const char* kt0 = &lds[0][half][0];
    const char* vt0 = &lds[0][half][4096];
    const char* kt1 = &lds[1][half][0];
    const char* vt1 = &lds[1][half][4096];

    // prologue: stage tile 0 into buf0
#pragma unroll
    for (int ii = 0; ii < 4; ii++)
        gload_lds16(src_run + ii * inner_stride, dst0 + ii * 1024);
    src_run += tile_stride;
    __syncthreads();

    for (int t = 0; t < 32; t += 2) {
        // even tile (buf0); stage t+1 into buf1
#pragma unroll
        for (int ii = 0; ii < 4; ii++)
            gload_lds16(src_run + ii * inner_stride, dst1 + ii * 1024);
        src_run += tile_stride;
        flash_tile(kt0, vt0, l31, hi, bq, o0, o1, mC, l_run);
        __syncthreads();

        // odd tile (buf1); stage t+2 into buf0 (except last)
        if (t + 2 < 32) {
#pragma unroll
            for (int ii = 0; ii < 4; ii++)
                gload_lds16(src_run + ii * inner_stride, dst0 + ii * 1024);
            src_run += tile_stride;
        }
        flash_tile(kt1, vt1, l31, hi, bq, o0, o1, mC, l_run);
        __syncthreads();
    }

    // cross-half(hi) l combine: full half-l for q = l31
    int2v lp = plswap(__float_as_int(l_run), __float_as_int(l_run));
    l_run = __int_as_float(lp[0]) + __int_as_float(lp[1]);

    // 2-way KV-half merge via LDS aliased over staging buffers (dead now)
    float (*obuf)[2][64] = (float (*)[2][64])(&lds[0][0][0]);          // 16 KB
    float (*mrg)[64][2] = (float (*)[64][2])(&lds[0][0][0] + 16384);   // 1 KB
    if (half == 1) {
        mrg[qt][lane][0] = mC;
        mrg[qt][lane][1] = l_run;
#pragma unroll
        for (int e = 0; e < 16; e++) {
            obuf[e][qt][lane] = o0[e];
            obuf[16 + e][qt][lane] = o1[e];
        }
    }
    __syncthreads();
    if (half == 0) {
        const float m2C = mrg[qt][lane][0], l2 = mrg[qt][lane][1];
        const float mm = fmaxf(mC, m2C);
        const float e1 = exp2f(mC - mm);
        const float e2 = exp2f(m2C - mm);
        const float linv = 1.f / (l_run * e1 + l2 * e2);
        bf16_t* Orow = Oa + ((size_t)b * S_SZ + q0 + l31) * D_MODEL + h * HEAD_DIM;
#pragma unroll
        for (int db = 0; db < 2; db++) {
#pragma unroll
            for (int rq = 0; rq < 4; rq++) {
                bf16x4 st;
#pragma unroll
                for (int i = 0; i < 4; i++) {
                    const int e = rq * 4 + i;
                    const float own = db ? o1[e] : o0[e];
                    const float oth = obuf[db * 16 + e][qt][lane];
                    st[i] = (bf16_t)((own * e1 + oth * e2) * linv);
                }
                *(bf16x4*)(Orow + db * 32 + rq * 8 + hi * 4) = st;
            }
        }
    }
}

// ---------------------------------------------------------------------------
// LayerNorm over 1024 with fused residual + optional second addend
// ---------------------------------------------------------------------------
__global__ __launch_bounds__(256) void ln_fused(const float* __restrict__ A,
                                                const float* __restrict__ A2,
                                                const float* __restrict__ R,
                                                const float* __restrict__ gamma,
                                                const float* __restrict__ beta,
                                                float* __restrict__ Xf,
                                                bf16_t* __restrict__ Xb) {
    __shared__ float red[8];
    int row = blockIdx.x, tid = threadIdx.x;
    size_t base = (size_t)row * D_MODEL + tid * 4;
    float4 a = *(const float4*)(A + base);
    float4 rv = *(const float4*)(R + base);
    float v0 = a.x + rv.x, v1 = a.y + rv.y, v2 = a.z + rv.z, v3 = a.w + rv.w;
    if (A2) {
        float4 a2 = *(const float4*)(A2 + base);
        v0 += a2.x; v1 += a2.y; v2 += a2.z; v3 += a2.w;
    }
    float s = v0 + v1 + v2 + v3;
    float q = v0 * v0 + v1 * v1 + v2 * v2 + v3 * v3;
#pragma unroll
    for (int off = 32; off; off >>= 1) { s += __shfl_down(s, off); q += __shfl_down(q, off); }
    if ((tid & 63) == 0) { red[tid >> 6] = s; red[4 + (tid >> 6)] = q; }
    __syncthreads();
    s = red[0] + red[1] + red[2] + red[3];
    q = red[4] + red[5] + red[6] + red[7];
    float mean = s * (1.f / D_MODEL);
    float var = q * (1.f / D_MODEL) - mean * mean;
    float rstd = rsqrtf(var + 1e-5f);
    float4 gm = *(const float4*)(gamma + tid * 4);
    float4 bt = *(const float4*)(beta + tid * 4);
    float y0 = (v0 - mean) * rstd * gm.x + bt.x;
    float y1 = (v1 - mean) * rstd * gm.y + bt.y;
    float y2 = (v2 - mean) * rstd * gm.z + bt.z;
    float y3 = (v3 - mean) * rstd * gm.w + bt.w;
    float4 yo; yo.x = y0; yo.y = y1; yo.z = y2; yo.w = y3;
    *(float4*)(Xf + base) = yo;
    if (Xb) {
        bf16x4 ob; ob[0] = (bf16_t)y0; ob[1] = (bf16_t)y1; ob[2] = (bf16_t)y2; ob[3] = (bf16_t)y3;
        *(bf16x4*)(Xb + base) = ob;
    }
}

// ---------------------------------------------------------------------------
extern "C" void kernel_launch(void* const* d_in, const int* in_sizes, int n_in,
                              void* d_out, int out_size, void* d_ws, size_t ws_size,
                              hipStream_t stream) {
    const float* value = (const float*)d_in[0];
    const float* key   = (const float*)d_in[1];
    const float* query = (const float*)d_in[2];
    const float* wq = (const float*)d_in[3];
    const float* bq = (const float*)d_in[4];
    const float* wk = (const float*)d_in[5];
    const float* bk = (const float*)d_in[6];
    const float* wv = (const float*)d_in[7];
    const float* bv = (const float*)d_in[8];
    const float* wo = (const float*)d_in[9];
    const float* bo = (const float*)d_in[10];
    const float* g1 = (const float*)d_in[11];
    const float* beta1 = (const float*)d_in[12];
    const float* w1 = (const float*)d_in[13];
    const float* b1 = (const float*)d_in[14];
    const float* w2 = (const float*)d_in[15];
    const float* b2 = (const float*)d_in[16];
    const float* g2 = (const float*)d_in[17];
    const float* beta2 = (const float*)d_in[18];
    (void)in_sizes; (void)n_in; (void)out_size; (void)ws_size;

    const size_t MB = 1ull << 20;
    char* ws = (char*)d_ws;
    bf16_t* wqT = (bf16_t*)(ws + 0 * MB);
    bf16_t* wkT = (bf16_t*)(ws + 2 * MB);
    bf16_t* wvT = (bf16_t*)(ws + 4 * MB);
    bf16_t* woT = (bf16_t*)(ws + 6 * MB);
    bf16_t* w1T = (bf16_t*)(ws + 8 * MB);
    bf16_t* w2T = (bf16_t*)(ws + 16 * MB);
    bf16_t* q_bf = (bf16_t*)(ws + 24 * MB);
    bf16_t* k_bf = (bf16_t*)(ws + 32 * MB);
    bf16_t* v_bf = (bf16_t*)(ws + 40 * MB);
    bf16_t* Qp  = (bf16_t*)(ws + 48 * MB);
    bf16_t* Kp  = (bf16_t*)(ws + 56 * MB);
    bf16_t* Vp  = (bf16_t*)(ws + 64 * MB);
    bf16_t* VT  = (bf16_t*)(ws + 72 * MB);
    bf16_t* attn = (bf16_t*)(ws + 24 * MB);   // reuse q_bf (dead after QKV gemm)
    float*  woP0 = (float*)(ws + 32 * MB);    // reuse k_bf..Qp (dead after flash)
    float*  woP1 = (float*)(ws + 48 * MB);
    float*  x_f = (float*)(ws + 64 * MB);     // reuse Vp/VT (dead after flash)
    bf16_t* x_b = (bf16_t*)(ws + 24 * MB);    // reuse attn (dead after WO gemm)
    bf16_t* h_b = (bf16_t*)(ws + 32 * MB);    // reuse woP (dead after LN1), 32MB
    float*  ffP0 = (float*)(ws + 80 * MB);
    float*  ffP1 = (float*)(ws + 96 * MB);

    dim3 blk(256);

    // 1) casts + weight transposes
    cast_f32_bf16<<<4096, blk, 0, stream>>>(query, q_bf);
    cast_f32_bf16<<<4096, blk, 0, stream>>>(key, k_bf);
    cast_f32_bf16<<<4096, blk, 0, stream>>>(value, v_bf);
    transpose_cast_w<<<dim3(32, 32), blk, 0, stream>>>(wq, wqT, 1024, 1024);
    transpose_cast_w<<<dim3(32, 32), blk, 0, stream>>>(wk, wkT, 1024, 1024);
    transpose_cast_w<<<dim3(32, 32), blk, 0, stream>>>(wv, wvT, 1024, 1024);
    transpose_cast_w<<<dim3(32, 32), blk, 0, stream>>>(wo, woT, 1024, 1024);
    transpose_cast_w<<<dim3(32, 128), blk, 0, stream>>>(w1, w1T, 1024, 4096);
    transpose_cast_w<<<dim3(128, 32), blk, 0, stream>>>(w2, w2T, 4096, 1024);

    // 2) grouped QKV projection
    gemm_qkv<<<dim3(32, 8, 3), blk, 0, stream>>>(q_bf, k_bf, v_bf, wqT, wkT, wvT,
                                                 bq, bk, bv, Qp, Kp, Vp);

    // 3) V transpose for PV A-operand
    transpose_v<<<dim3(64, 2, 32), blk, 0, stream>>>(Vp, VT);

    // 4) flash attention v4 (LDS-staged, conflict-free both tiles)
    flash_attn<<<dim3(32, 16, 2), blk, 0, stream>>>(Qp, Kp, VT, attn);

    // 5) WO projection, split-K=2 (f32 partials)
    gemm_bt<false, false, true><<<dim3(32, 8, 2), blk, 0, stream>>>(attn, 1024, woT, 1024, bo, woP0, woP1, nullptr, D_MODEL, 512);

    // 6) LN1: x = LN(woP0 + woP1 + query)
    ln_fused<<<4096, blk, 0, stream>>>(woP0, woP1, query, g1, beta1, x_f, x_b);

    // 7) FF1 + ReLU (bf16 out)
    gemm_bt<true, true, false><<<dim3(32, 32, 1), blk, 0, stream>>>(x_b, 1024, w1T, 1024, b1, nullptr, nullptr, h_b, FF_DIM, 1024);

    // 8) FF2, split-K=2 (f32 partials)
    gemm_bt<false, false, true><<<dim3(32, 8, 2), blk, 0, stream>>>(h_b, 4096, w2T, 4096, b2, ffP0, ffP1, nullptr, D_MODEL, 2048);

    // 9) LN2 -> d_out
    ln_fused<<<4096, blk, 0, stream>>>(ffP0, ffP1, x_f, g2, beta2, (float*)d_out, nullptr);
}

// Round 10
// 297.373 us; speedup vs baseline: 2.4044x; 1.0130x over previous
//
#include <hip/hip_runtime.h>
#include <hip/hip_bf16.h>
#include <cstdint>
#include <math.h>

typedef __bf16 bf16_t;
typedef __attribute__((ext_vector_type(2))) __bf16 bf16x2;
typedef __attribute__((ext_vector_type(4))) __bf16 bf16x4;
typedef __attribute__((ext_vector_type(8))) __bf16 bf16x8;
typedef __attribute__((ext_vector_type(4))) float f32x4;
typedef __attribute__((ext_vector_type(16))) float f32x16;
typedef __attribute__((ext_vector_type(2))) int int2v;
typedef __attribute__((ext_vector_type(4))) int int4v;

#define B_SZ 2
#define S_SZ 2048
#define D_MODEL 1024
#define NUM_HEADS 16
#define HEAD_DIM 64
#define FF_DIM 4096
#define M_ROWS (B_SZ * S_SZ)   // 4096

// exp2-domain scale: 0.125 (1/sqrt(64)) * log2(e)
#define CF 0.180336880f
#define THRC 2.0f   // defer-max threshold in exp2 domain -> P bounded by 4

// ---------------------------------------------------------------------------
__device__ __forceinline__ void gload_lds16(const void* g, void* lds) {
    __builtin_amdgcn_global_load_lds(
        (const __attribute__((address_space(1))) void*)(uintptr_t)g,
        (__attribute__((address_space(3))) void*)(uint32_t)(uintptr_t)lds,
        16, 0, 0);
}

__device__ __forceinline__ f32x4 mfma16(bf16x8 a, bf16x8 b, f32x4 c) {
    return __builtin_amdgcn_mfma_f32_16x16x32_bf16(a, b, c, 0, 0, 0);
}
__device__ __forceinline__ f32x16 mfma32(bf16x8 a, bf16x8 b, f32x16 c) {
    return __builtin_amdgcn_mfma_f32_32x32x16_bf16(a, b, c, 0, 0, 0);
}
__device__ __forceinline__ int2v plswap(int a, int b) {
    return __builtin_amdgcn_permlane32_swap(a, b, false, false);
}
__device__ __forceinline__ int packbf(float a, float b) {
    bf16x2 t; t[0] = (bf16_t)a; t[1] = (bf16_t)b;
    return __builtin_bit_cast(int, t);
}

// XCD-aware bijective swizzle helper (nwg must be divisible by 8)
__device__ __forceinline__ int xcd_swz(int lin, int nwg) {
    return (lin & 7) * (nwg >> 3) + (lin >> 3);
}

// ---------------------------------------------------------------------------
__global__ __launch_bounds__(256) void cast_f32_bf16(const float* __restrict__ in,
                                                     bf16_t* __restrict__ out) {
    size_t i = ((size_t)blockIdx.x * 256 + threadIdx.x) * 4;
    float4 v = *(const float4*)(in + i);
    bf16x4 o;
    o[0] = (bf16_t)v.x; o[1] = (bf16_t)v.y; o[2] = (bf16_t)v.z; o[3] = (bf16_t)v.w;
    *(bf16x4*)(out + i) = o;
}

// ---------------------------------------------------------------------------
__global__ __launch_bounds__(256) void transpose_cast_w(const float* __restrict__ W,
                                                        bf16_t* __restrict__ WT,
                                                        int K, int N) {
    __shared__ float t[32][33];
    int tid = threadIdx.x;
    int rr = tid >> 3, cc = (tid & 7) * 4;
    int k0 = blockIdx.x * 32, n0 = blockIdx.y * 32;
    float4 v = *(const float4*)(W + (size_t)(k0 + rr) * N + n0 + cc);
    t[rr][cc + 0] = v.x; t[rr][cc + 1] = v.y; t[rr][cc + 2] = v.z; t[rr][cc + 3] = v.w;
    __syncthreads();
    bf16x4 o;
    o[0] = (bf16_t)t[cc + 0][rr]; o[1] = (bf16_t)t[cc + 1][rr];
    o[2] = (bf16_t)t[cc + 2][rr]; o[3] = (bf16_t)t[cc + 3][rr];
    *(bf16x4*)(WT + (size_t)(n0 + rr) * K + k0 + cc) = o;
}

// ---------------------------------------------------------------------------
__global__ __launch_bounds__(256) void transpose_v(const bf16_t* __restrict__ Vp,
                                                   bf16_t* __restrict__ VT) {
    __shared__ bf16_t t[32][34];
    int tid = threadIdx.x;
    int rr = tid >> 3, cc = (tid & 7) * 4;
    int bh = blockIdx.z;
    int b = bh >> 4, h = bh & 15;
    int s0 = blockIdx.x * 32, d0 = blockIdx.y * 32;
    bf16x4 v = *(const bf16x4*)(Vp + ((size_t)(b * S_SZ + s0 + rr)) * D_MODEL + h * HEAD_DIM + d0 + cc);
    t[rr][cc + 0] = v[0]; t[rr][cc + 1] = v[1]; t[rr][cc + 2] = v[2]; t[rr][cc + 3] = v[3];
    __syncthreads();
    bf16x4 o;
    o[0] = t[cc + 0][rr]; o[1] = t[cc + 1][rr]; o[2] = t[cc + 2][rr]; o[3] = t[cc + 3][rr];
    *(bf16x4*)(VT + ((size_t)(bh * HEAD_DIM + d0 + rr)) * S_SZ + s0 + cc) = o;
}

// ---------------------------------------------------------------------------
// GEMM core v2: 128x128 tile, BK=32, 4 waves, DOUBLE-BUFFERED LDS with
// stage(t+1) issued BEFORE compute(t) and ONE barrier per K-step.
// The barrier's implicit vmcnt(0) drain now lands AFTER the MFMA block,
// so global_load_lds latency overlaps compute instead of sitting naked
// between two barriers (R9 diagnosis: ~1575 cyc/K-step-slot exposed).
// Requires Klen % 64 == 0 (all call sites: 512/1024/2048).
// ---------------------------------------------------------------------------
template<bool RELU, bool OUT_BF16, bool OUT_F32>
__device__ __forceinline__ void gemm_core(const bf16_t* __restrict__ A, int lda,
                                          const bf16_t* __restrict__ Bt, int ldb,
                                          const float* __restrict__ bias, bool useBias,
                                          float* __restrict__ Cf,
                                          bf16_t* __restrict__ Cb,
                                          int N, int Klen, int m0, int n0,
                                          bf16_t* sA, bf16_t* sB) {  // each [2][4096]
    const int tid = threadIdx.x;
    const int lane = tid & 63, wave = tid >> 6;
    const int g = lane >> 4, r = lane & 15;
    const int wm = (wave >> 1) * 64, wn = (wave & 1) * 64;

    const bf16_t* Ablk = A + (size_t)m0 * lda;
    const bf16_t* Bblk = Bt + (size_t)n0 * ldb;
    const int c0 = wave * 64 + lane;
    const int c1 = c0 + 256;

    // per-lane running source pointers (col offset folded in)
    const bf16_t* a0 = Ablk + (size_t)(c0 >> 2) * lda + (c0 & 3) * 8;
    const bf16_t* a1 = Ablk + (size_t)(c1 >> 2) * lda + (c1 & 3) * 8;
    const bf16_t* b0 = Bblk + (size_t)(c0 >> 2) * ldb + (c0 & 3) * 8;
    const bf16_t* b1 = Bblk + (size_t)(c1 >> 2) * ldb + (c1 & 3) * 8;

    f32x4 acc[4][4];
#pragma unroll
    for (int i = 0; i < 4; i++)
#pragma unroll
        for (int j = 0; j < 4; j++)
#pragma unroll
            for (int e = 0; e < 4; e++) acc[i][j][e] = 0.f;

    auto stage = [&](int buf, int k0) {
        gload_lds16(a0 + k0, sA + buf * 4096 + wave * 512);
        gload_lds16(a1 + k0, sA + buf * 4096 + 2048 + wave * 512);
        gload_lds16(b0 + k0, sB + buf * 4096 + wave * 512);
        gload_lds16(b1 + k0, sB + buf * 4096 + 2048 + wave * 512);
    };
    auto compute = [&](int buf) {
        bf16x8 a[4], b[4];
#pragma unroll
        for (int i = 0; i < 4; i++)
            a[i] = *(const bf16x8*)(sA + buf * 4096 + (wm + i * 16 + r) * 32 + g * 8);
#pragma unroll
        for (int j = 0; j < 4; j++)
            b[j] = *(const bf16x8*)(sB + buf * 4096 + (wn + j * 16 + r) * 32 + g * 8);
#pragma unroll
        for (int i = 0; i < 4; i++)
#pragma unroll
            for (int j = 0; j < 4; j++)
                acc[i][j] = mfma16(a[i], b[j], acc[i][j]);
    };

    const int nk = Klen >> 5;   // even by construction
    stage(0, 0);
    __syncthreads();
    for (int ks = 0; ks < nk; ks += 2) {
        stage(1, ks * 32 + 32);      // prefetch t+1 (issued before compute)
        compute(0);
        __syncthreads();             // drains vmcnt AFTER compute -> overlap
        if (ks + 2 < nk) stage(0, ks * 32 + 64);
        compute(1);
        __syncthreads();
    }

#pragma unroll
    for (int j = 0; j < 4; j++) {
        int n = n0 + wn + j * 16 + r;
        float bv = useBias ? bias[n] : 0.f;
#pragma unroll
        for (int i = 0; i < 4; i++) {
#pragma unroll
            for (int rr = 0; rr < 4; rr++) {
                int mrow = m0 + wm + i * 16 + g * 4 + rr;
                float val = acc[i][j][rr] + bv;
                if (RELU) val = fmaxf(val, 0.f);
                if (OUT_F32) Cf[(size_t)mrow * N + n] = val;
                if (OUT_BF16) Cb[(size_t)mrow * N + n] = (bf16_t)val;
            }
        }
    }
}

// split-K wrapper (z = K-chunk); XCD-swizzled grid
template<bool RELU, bool OUT_BF16, bool OUT_F32>
__global__ __launch_bounds__(256) void gemm_bt(const bf16_t* __restrict__ A, int lda,
                                               const bf16_t* __restrict__ Bt, int ldb,
                                               const float* __restrict__ bias,
                                               float* __restrict__ Cf0,
                                               float* __restrict__ Cf1,
                                               bf16_t* __restrict__ Cb,
                                               int N, int Klen) {
    __shared__ bf16_t sA[2 * 4096];
    __shared__ bf16_t sB[2 * 4096];
    const int lin = blockIdx.x + gridDim.x * (blockIdx.y + gridDim.y * blockIdx.z);
    const int nwg = gridDim.x * gridDim.y * gridDim.z;
    const int swz = xcd_swz(lin, nwg);
    const int bx = swz % gridDim.x;
    const int rest = swz / gridDim.x;
    const int by = rest % gridDim.y;
    const int bz = rest / gridDim.y;
    const int koff = bz * Klen;
    gemm_core<RELU, OUT_BF16, OUT_F32>(A + koff, lda, Bt + koff, ldb, bias, bz == 0,
                                       bz ? Cf1 : Cf0, Cb, N, Klen, bx * 128, by * 128, sA, sB);
}

// grouped QKV: z selects (A, W, bias, C)
__global__ __launch_bounds__(256) void gemm_qkv(const bf16_t* __restrict__ A0,
                                                const bf16_t* __restrict__ A1,
                                                const bf16_t* __restrict__ A2,
                                                const bf16_t* __restrict__ B0,
                                                const bf16_t* __restrict__ B1,
                                                const bf16_t* __restrict__ B2,
                                                const float* __restrict__ b0,
                                                const float* __restrict__ b1,
                                                const float* __restrict__ b2,
                                                bf16_t* __restrict__ C0,
                                                bf16_t* __restrict__ C1,
                                                bf16_t* __restrict__ C2) {
    __shared__ bf16_t sA[2 * 4096];
    __shared__ bf16_t sB[2 * 4096];
    const int lin = blockIdx.x + gridDim.x * (blockIdx.y + gridDim.y * blockIdx.z);
    const int nwg = gridDim.x * gridDim.y * gridDim.z;
    const int swz = xcd_swz(lin, nwg);
    const int bx = swz % gridDim.x;
    const int rest = swz / gridDim.x;
    const int by = rest % gridDim.y;
    const int bz = rest / gridDim.y;
    const bf16_t* A = bz == 0 ? A0 : bz == 1 ? A1 : A2;
    const bf16_t* Bt = bz == 0 ? B0 : bz == 1 ? B1 : B2;
    const float* bias = bz == 0 ? b0 : bz == 1 ? b1 : b2;
    bf16_t* C = bz == 0 ? C0 : bz == 1 ? C1 : C2;
    gemm_core<false, true, false>(A, 1024, Bt, 1024, bias, true,
                                  nullptr, C, 1024, 1024, bx * 128, by * 128, sA, sB);
}

// ---------------------------------------------------------------------------
// Flash attention v4 (unchanged from R9): LDS-staged K/V, both tiles
// XOR-swizzled, manual x2 unroll, 2-way merge.
// ---------------------------------------------------------------------------
__device__ __forceinline__ void flash_tile(
    const char* kt, const char* vt, int l31, int hi,
    const bf16x8 (&bq)[4],
    f32x16& o0, f32x16& o1, float& mC, float& l_run)
{
    bf16x8 ak[4];
#pragma unroll
    for (int kb = 0; kb < 4; kb++)
        ak[kb] = *(const bf16x8*)(kt + l31 * 128 + (((kb << 1) | hi) ^ (l31 & 7)) * 16);
    bf16x8 av[4];
#pragma unroll
    for (int db = 0; db < 2; db++)
#pragma unroll
        for (int kb = 0; kb < 2; kb++)
            av[db * 2 + kb] = *(const bf16x8*)(vt + (db * 32 + l31) * 64 + ((((kb << 1) | hi)) ^ ((l31 >> 1) & 3)) * 16);

    f32x16 s;
#pragma unroll
    for (int e = 0; e < 16; e++) s[e] = 0.f;
#pragma unroll
    for (int kb = 0; kb < 4; kb++) s = mfma32(ak[kb], bq[kb], s);

    float ma = fmaxf(fmaxf(s[0], s[1]), fmaxf(s[2], s[3]));
    float mb = fmaxf(fmaxf(s[4], s[5]), fmaxf(s[6], s[7]));
    float mc = fmaxf(fmaxf(s[8], s[9]), fmaxf(s[10], s[11]));
    float md = fmaxf(fmaxf(s[12], s[13]), fmaxf(s[14], s[15]));
    float pmaxC = fmaxf(fmaxf(ma, mb), fmaxf(mc, md)) * CF;

    if (!__all(pmaxC <= mC + THRC)) {
        int2v pr = plswap(__float_as_int(pmaxC), __float_as_int(pmaxC));
        float rowmaxC = fmaxf(__int_as_float(pr[0]), __int_as_float(pr[1]));
        float mnewC = fmaxf(mC, rowmaxC);
        float alpha = exp2f(mC - mnewC);
        mC = mnewC;
        l_run *= alpha;
#pragma unroll
        for (int e = 0; e < 16; e++) { o0[e] *= alpha; o1[e] *= alpha; }
    }

#pragma unroll
    for (int e = 0; e < 16; e++) s[e] = exp2f(__builtin_fmaf(s[e], CF, -mC));
    float t0 = (s[0] + s[1]) + (s[2] + s[3]);
    float t1 = (s[4] + s[5]) + (s[6] + s[7]);
    float t2 = (s[8] + s[9]) + (s[10] + s[11]);
    float t3 = (s[12] + s[13]) + (s[14] + s[15]);
    l_run += (t0 + t1) + (t2 + t3);

#pragma unroll
    for (int kb2 = 0; kb2 < 2; kb2++) {
        const int bse = kb2 * 8;
        int W0 = packbf(s[bse + 0], s[bse + 1]);
        int W1 = packbf(s[bse + 2], s[bse + 3]);
        int W2 = packbf(s[bse + 4], s[bse + 5]);
        int W3 = packbf(s[bse + 6], s[bse + 7]);
        int2v r02 = plswap(W0, W2);
        int2v r13 = plswap(W1, W3);
        int4v fw; fw[0] = r02[0]; fw[1] = r13[0]; fw[2] = r02[1]; fw[3] = r13[1];
        bf16x8 pf = __builtin_bit_cast(bf16x8, fw);
        o0 = mfma32(av[kb2], pf, o0);
        o1 = mfma32(av[2 + kb2], pf, o1);
    }
}

__global__ __launch_bounds__(256) void flash_attn(const bf16_t* __restrict__ Qp,
                                                  const bf16_t* __restrict__ Kp,
                                                  const bf16_t* __restrict__ VT,
                                                  bf16_t* __restrict__ Oa) {
    __shared__ alignas(16) char lds[2][2][8192];  // [buf][half][K 4KB | V 4KB]
    const int tid = threadIdx.x;
    const int lane = tid & 63;
    const int wave = tid >> 6;
    const int half = wave >> 1;
    const int qt = wave & 1;
    const int l31 = lane & 31, hi = lane >> 5;

    const int lin = blockIdx.x + (blockIdx.y << 5) + (blockIdx.z << 9);
    const int swz = (lin & 7) * 128 + (lin >> 3);
    const int qb = swz & 31;
    const int h = (swz >> 5) & 15;
    const int b = swz >> 9;

    const int q0 = qb * 64 + qt * 32;

    const bf16_t* Qb = Qp + (size_t)b * S_SZ * D_MODEL + h * HEAD_DIM;
    const bf16_t* Kb = Kp + (size_t)b * S_SZ * D_MODEL + h * HEAD_DIM;
    const bf16_t* Vb = VT + ((size_t)(b * NUM_HEADS + h) * HEAD_DIM) * S_SZ;

    const int sh = wave & 1;
    const int skvbase = sh * (S_SZ / 2);
    const bool kRole = wave < 2;

    const bf16_t* src_run;
    size_t inner_stride;
    size_t tile_stride;
    char* dst0;
    char* dst1;
    if (kRole) {
        src_run = Kb + (size_t)(skvbase + (lane >> 3)) * D_MODEL + ((lane & 7) ^ (lane >> 3)) * 8;
        inner_stride = (size_t)8 * D_MODEL;
        tile_stride = (size_t)32 * D_MODEL;
        dst0 = &lds[0][sh][0] + lane * 16;
        dst1 = &lds[1][sh][0] + lane * 16;
    } else {
        src_run = Vb + (size_t)(lane >> 2) * S_SZ + skvbase + ((lane & 3) ^ ((lane >> 3) & 3)) * 8;
        inner_stride = (size_t)16 * S_SZ;
        tile_stride = 32;
        dst0 = &lds[0][sh][4096] + lane * 16;
        dst1 = &lds[1][sh][4096] + lane * 16;
    }

    bf16x8 bq[4];
#pragma unroll
    for (int kb = 0; kb < 4; kb++)
        bq[kb] = *(const bf16x8*)(Qb + (size_t)(q0 + l31) * D_MODEL + kb * 16 + hi * 8);

    f32x16 o0, o1;
#pragma unroll
    for (int e = 0; e < 16; e++) { o0[e] = 0.f; o1[e] = 0.f; }
    float mC = -1e30f, l_run = 0.f;

    const char* kt0 = &lds[0][half][0];
    const char* vt0 = &lds[0][half][4096];
    const char* kt1 = &lds[1][half][0];
    const char* vt1 = &lds[1][half][4096];

#pragma unroll
    for (int ii = 0; ii < 4; ii++)
        gload_lds16(src_run + ii * inner_stride, dst0 + ii * 1024);
    src_run += tile_stride;
    __syncthreads();

    for (int t = 0; t < 32; t += 2) {
#pragma unroll
        for (int ii = 0; ii < 4; ii++)
            gload_lds16(src_run + ii * inner_stride, dst1 + ii * 1024);
        src_run += tile_stride;
        flash_tile(kt0, vt0, l31, hi, bq, o0, o1, mC, l_run);
        __syncthreads();

        if (t + 2 < 32) {
#pragma unroll
            for (int ii = 0; ii < 4; ii++)
                gload_lds16(src_run + ii * inner_stride, dst0 + ii * 1024);
            src_run += tile_stride;
        }
        flash_tile(kt1, vt1, l31, hi, bq, o0, o1, mC, l_run);
        __syncthreads();
    }

    int2v lp = plswap(__float_as_int(l_run), __float_as_int(l_run));
    l_run = __int_as_float(lp[0]) + __int_as_float(lp[1]);

    float (*obuf)[2][64] = (float (*)[2][64])(&lds[0][0][0]);
    float (*mrg)[64][2] = (float (*)[64][2])(&lds[0][0][0] + 16384);
    if (half == 1) {
        mrg[qt][lane][0] = mC;
        mrg[qt][lane][1] = l_run;
#pragma unroll
        for (int e = 0; e < 16; e++) {
            obuf[e][qt][lane] = o0[e];
            obuf[16 + e][qt][lane] = o1[e];
        }
    }
    __syncthreads();
    if (half == 0) {
        const float m2C = mrg[qt][lane][0], l2 = mrg[qt][lane][1];
        const float mm = fmaxf(mC, m2C);
        const float e1 = exp2f(mC - mm);
        const float e2 = exp2f(m2C - mm);
        const float linv = 1.f / (l_run * e1 + l2 * e2);
        bf16_t* Orow = Oa + ((size_t)b * S_SZ + q0 + l31) * D_MODEL + h * HEAD_DIM;
#pragma unroll
        for (int db = 0; db < 2; db++) {
#pragma unroll
            for (int rq = 0; rq < 4; rq++) {
                bf16x4 st;
#pragma unroll
                for (int i = 0; i < 4; i++) {
                    const int e = rq * 4 + i;
                    const float own = db ? o1[e] : o0[e];
                    const float oth = obuf[db * 16 + e][qt][lane];
                    st[i] = (bf16_t)((own * e1 + oth * e2) * linv);
                }
                *(bf16x4*)(Orow + db * 32 + rq * 8 + hi * 4) = st;
            }
        }
    }
}

// ---------------------------------------------------------------------------
// LayerNorm over 1024 with fused residual + optional second addend
// ---------------------------------------------------------------------------
__global__ __launch_bounds__(256) void ln_fused(const float* __restrict__ A,
                                                const float* __restrict__ A2,
                                                const float* __restrict__ R,
                                                const float* __restrict__ gamma,
                                                const float* __restrict__ beta,
                                                float* __restrict__ Xf,
                                                bf16_t* __restrict__ Xb) {
    __shared__ float red[8];
    int row = blockIdx.x, tid = threadIdx.x;
    size_t base = (size_t)row * D_MODEL + tid * 4;
    float4 a = *(const float4*)(A + base);
    float4 rv = *(const float4*)(R + base);
    float v0 = a.x + rv.x, v1 = a.y + rv.y, v2 = a.z + rv.z, v3 = a.w + rv.w;
    if (A2) {
        float4 a2 = *(const float4*)(A2 + base);
        v0 += a2.x; v1 += a2.y; v2 += a2.z; v3 += a2.w;
    }
    float s = v0 + v1 + v2 + v3;
    float q = v0 * v0 + v1 * v1 + v2 * v2 + v3 * v3;
#pragma unroll
    for (int off = 32; off; off >>= 1) { s += __shfl_down(s, off); q += __shfl_down(q, off); }
    if ((tid & 63) == 0) { red[tid >> 6] = s; red[4 + (tid >> 6)] = q; }
    __syncthreads();
    s = red[0] + red[1] + red[2] + red[3];
    q = red[4] + red[5] + red[6] + red[7];
    float mean = s * (1.f / D_MODEL);
    float var = q * (1.f / D_MODEL) - mean * mean;
    float rstd = rsqrtf(var + 1e-5f);
    float4 gm = *(const float4*)(gamma + tid * 4);
    float4 bt = *(const float4*)(beta + tid * 4);
    float y0 = (v0 - mean) * rstd * gm.x + bt.x;
    float y1 = (v1 - mean) * rstd * gm.y + bt.y;
    float y2 = (v2 - mean) * rstd * gm.z + bt.z;
    float y3 = (v3 - mean) * rstd * gm.w + bt.w;
    float4 yo; yo.x = y0; yo.y = y1; yo.z = y2; yo.w = y3;
    *(float4*)(Xf + base) = yo;
    if (Xb) {
        bf16x4 ob; ob[0] = (bf16_t)y0; ob[1] = (bf16_t)y1; ob[2] = (bf16_t)y2; ob[3] = (bf16_t)y3;
        *(bf16x4*)(Xb + base) = ob;
    }
}

// ---------------------------------------------------------------------------
extern "C" void kernel_launch(void* const* d_in, const int* in_sizes, int n_in,
                              void* d_out, int out_size, void* d_ws, size_t ws_size,
                              hipStream_t stream) {
    const float* value = (const float*)d_in[0];
    const float* key   = (const float*)d_in[1];
    const float* query = (const float*)d_in[2];
    const float* wq = (const float*)d_in[3];
    const float* bq = (const float*)d_in[4];
    const float* wk = (const float*)d_in[5];
    const float* bk = (const float*)d_in[6];
    const float* wv = (const float*)d_in[7];
    const float* bv = (const float*)d_in[8];
    const float* wo = (const float*)d_in[9];
    const float* bo = (const float*)d_in[10];
    const float* g1 = (const float*)d_in[11];
    const float* beta1 = (const float*)d_in[12];
    const float* w1 = (const float*)d_in[13];
    const float* b1 = (const float*)d_in[14];
    const float* w2 = (const float*)d_in[15];
    const float* b2 = (const float*)d_in[16];
    const float* g2 = (const float*)d_in[17];
    const float* beta2 = (const float*)d_in[18];
    (void)in_sizes; (void)n_in; (void)out_size; (void)ws_size;

    const size_t MB = 1ull << 20;
    char* ws = (char*)d_ws;
    bf16_t* wqT = (bf16_t*)(ws + 0 * MB);
    bf16_t* wkT = (bf16_t*)(ws + 2 * MB);
    bf16_t* wvT = (bf16_t*)(ws + 4 * MB);
    bf16_t* woT = (bf16_t*)(ws + 6 * MB);
    bf16_t* w1T = (bf16_t*)(ws + 8 * MB);
    bf16_t* w2T = (bf16_t*)(ws + 16 * MB);
    bf16_t* q_bf = (bf16_t*)(ws + 24 * MB);
    bf16_t* k_bf = (bf16_t*)(ws + 32 * MB);
    bf16_t* v_bf = (bf16_t*)(ws + 40 * MB);
    bf16_t* Qp  = (bf16_t*)(ws + 48 * MB);
    bf16_t* Kp  = (bf16_t*)(ws + 56 * MB);
    bf16_t* Vp  = (bf16_t*)(ws + 64 * MB);
    bf16_t* VT  = (bf16_t*)(ws + 72 * MB);
    bf16_t* attn = (bf16_t*)(ws + 24 * MB);   // reuse q_bf (dead after QKV gemm)
    float*  woP0 = (float*)(ws + 32 * MB);    // reuse k_bf..Qp (dead after flash)
    float*  woP1 = (float*)(ws + 48 * MB);
    float*  x_f = (float*)(ws + 64 * MB);     // reuse Vp/VT (dead after flash)
    bf16_t* x_b = (bf16_t*)(ws + 24 * MB);    // reuse attn (dead after WO gemm)
    bf16_t* h_b = (bf16_t*)(ws + 32 * MB);    // reuse woP (dead after LN1), 32MB
    float*  ffP0 = (float*)(ws + 80 * MB);
    float*  ffP1 = (float*)(ws + 96 * MB);

    dim3 blk(256);

    // 1) casts + weight transposes
    cast_f32_bf16<<<4096, blk, 0, stream>>>(query, q_bf);
    cast_f32_bf16<<<4096, blk, 0, stream>>>(key, k_bf);
    cast_f32_bf16<<<4096, blk, 0, stream>>>(value, v_bf);
    transpose_cast_w<<<dim3(32, 32), blk, 0, stream>>>(wq, wqT, 1024, 1024);
    transpose_cast_w<<<dim3(32, 32), blk, 0, stream>>>(wk, wkT, 1024, 1024);
    transpose_cast_w<<<dim3(32, 32), blk, 0, stream>>>(wv, wvT, 1024, 1024);
    transpose_cast_w<<<dim3(32, 32), blk, 0, stream>>>(wo, woT, 1024, 1024);
    transpose_cast_w<<<dim3(32, 128), blk, 0, stream>>>(w1, w1T, 1024, 4096);
    transpose_cast_w<<<dim3(128, 32), blk, 0, stream>>>(w2, w2T, 4096, 1024);

    // 2) grouped QKV projection
    gemm_qkv<<<dim3(32, 8, 3), blk, 0, stream>>>(q_bf, k_bf, v_bf, wqT, wkT, wvT,
                                                 bq, bk, bv, Qp, Kp, Vp);

    // 3) V transpose for PV A-operand
    transpose_v<<<dim3(64, 2, 32), blk, 0, stream>>>(Vp, VT);

    // 4) flash attention v4
    flash_attn<<<dim3(32, 16, 2), blk, 0, stream>>>(Qp, Kp, VT, attn);

    // 5) WO projection, split-K=2 (f32 partials)
    gemm_bt<false, false, true><<<dim3(32, 8, 2), blk, 0, stream>>>(attn, 1024, woT, 1024, bo, woP0, woP1, nullptr, D_MODEL, 512);

    // 6) LN1: x = LN(woP0 + woP1 + query)
    ln_fused<<<4096, blk, 0, stream>>>(woP0, woP1, query, g1, beta1, x_f, x_b);

    // 7) FF1 + ReLU (bf16 out)
    gemm_bt<true, true, false><<<dim3(32, 32, 1), blk, 0, stream>>>(x_b, 1024, w1T, 1024, b1, nullptr, nullptr, h_b, FF_DIM, 1024);

    // 8) FF2, split-K=2 (f32 partials)
    gemm_bt<false, false, true><<<dim3(32, 8, 2), blk, 0, stream>>>(h_b, 4096, w2T, 4096, b2, ffP0, ffP1, nullptr, D_MODEL, 2048);

    // 9) LN2 -> d_out
    ln_fused<<<4096, blk, 0, stream>>>(ffP0, ffP1, x_f, g2, beta2, (float*)d_out, nullptr);
}

// Round 11
// 284.236 us; speedup vs baseline: 2.5155x; 1.0462x over previous
//
#include <hip/hip_runtime.h>
#include <hip/hip_bf16.h>
#include <cstdint>
#include <math.h>

typedef __bf16 bf16_t;
typedef __attribute__((ext_vector_type(2))) __bf16 bf16x2;
typedef __attribute__((ext_vector_type(4))) __bf16 bf16x4;
typedef __attribute__((ext_vector_type(8))) __bf16 bf16x8;
typedef __attribute__((ext_vector_type(4))) float f32x4;
typedef __attribute__((ext_vector_type(16))) float f32x16;
typedef __attribute__((ext_vector_type(2))) int int2v;
typedef __attribute__((ext_vector_type(4))) int int4v;

#define B_SZ 2
#define S_SZ 2048
#define D_MODEL 1024
#define NUM_HEADS 16
#define HEAD_DIM 64
#define FF_DIM 4096
#define M_ROWS (B_SZ * S_SZ)   // 4096

// exp2-domain scale: 0.125 (1/sqrt(64)) * log2(e)
#define CF 0.180336880f
#define THRC 2.0f   // defer-max threshold in exp2 domain -> P bounded by 4

// ---------------------------------------------------------------------------
__device__ __forceinline__ void gload_lds16(const void* g, void* lds) {
    __builtin_amdgcn_global_load_lds(
        (const __attribute__((address_space(1))) void*)(uintptr_t)g,
        (__attribute__((address_space(3))) void*)(uint32_t)(uintptr_t)lds,
        16, 0, 0);
}

__device__ __forceinline__ f32x4 mfma16(bf16x8 a, bf16x8 b, f32x4 c) {
    return __builtin_amdgcn_mfma_f32_16x16x32_bf16(a, b, c, 0, 0, 0);
}
__device__ __forceinline__ f32x16 mfma32(bf16x8 a, bf16x8 b, f32x16 c) {
    return __builtin_amdgcn_mfma_f32_32x32x16_bf16(a, b, c, 0, 0, 0);
}
__device__ __forceinline__ int2v plswap(int a, int b) {
    return __builtin_amdgcn_permlane32_swap(a, b, false, false);
}
__device__ __forceinline__ int packbf(float a, float b) {
    bf16x2 t; t[0] = (bf16_t)a; t[1] = (bf16_t)b;
    return __builtin_bit_cast(int, t);
}

// XCD-aware bijective swizzle helper (nwg must be divisible by 8)
__device__ __forceinline__ int xcd_swz(int lin, int nwg) {
    return (lin & 7) * (nwg >> 3) + (lin >> 3);
}

// ---------------------------------------------------------------------------
__global__ __launch_bounds__(256) void cast_f32_bf16(const float* __restrict__ in,
                                                     bf16_t* __restrict__ out) {
    size_t i = ((size_t)blockIdx.x * 256 + threadIdx.x) * 4;
    float4 v = *(const float4*)(in + i);
    bf16x4 o;
    o[0] = (bf16_t)v.x; o[1] = (bf16_t)v.y; o[2] = (bf16_t)v.z; o[3] = (bf16_t)v.w;
    *(bf16x4*)(out + i) = o;
}

// ---------------------------------------------------------------------------
__global__ __launch_bounds__(256) void transpose_cast_w(const float* __restrict__ W,
                                                        bf16_t* __restrict__ WT,
                                                        int K, int N) {
    __shared__ float t[32][33];
    int tid = threadIdx.x;
    int rr = tid >> 3, cc = (tid & 7) * 4;
    int k0 = blockIdx.x * 32, n0 = blockIdx.y * 32;
    float4 v = *(const float4*)(W + (size_t)(k0 + rr) * N + n0 + cc);
    t[rr][cc + 0] = v.x; t[rr][cc + 1] = v.y; t[rr][cc + 2] = v.z; t[rr][cc + 3] = v.w;
    __syncthreads();
    bf16x4 o;
    o[0] = (bf16_t)t[cc + 0][rr]; o[1] = (bf16_t)t[cc + 1][rr];
    o[2] = (bf16_t)t[cc + 2][rr]; o[3] = (bf16_t)t[cc + 3][rr];
    *(bf16x4*)(WT + (size_t)(n0 + rr) * K + k0 + cc) = o;
}

// ---------------------------------------------------------------------------
__global__ __launch_bounds__(256) void transpose_v(const bf16_t* __restrict__ Vp,
                                                   bf16_t* __restrict__ VT) {
    __shared__ bf16_t t[32][34];
    int tid = threadIdx.x;
    int rr = tid >> 3, cc = (tid & 7) * 4;
    int bh = blockIdx.z;
    int b = bh >> 4, h = bh & 15;
    int s0 = blockIdx.x * 32, d0 = blockIdx.y * 32;
    bf16x4 v = *(const bf16x4*)(Vp + ((size_t)(b * S_SZ + s0 + rr)) * D_MODEL + h * HEAD_DIM + d0 + cc);
    t[rr][cc + 0] = v[0]; t[rr][cc + 1] = v[1]; t[rr][cc + 2] = v[2]; t[rr][cc + 3] = v[3];
    __syncthreads();
    bf16x4 o;
    o[0] = t[cc + 0][rr]; o[1] = t[cc + 1][rr]; o[2] = t[cc + 2][rr]; o[3] = t[cc + 3][rr];
    *(bf16x4*)(VT + ((size_t)(bh * HEAD_DIM + d0 + rr)) * S_SZ + s0 + cc) = o;
}

// ---------------------------------------------------------------------------
// GEMM core v3: 128x128 tile, BK=32, 4 waves, COUNTED-VMCNT 3-BUFFER RING.
// stage(s+2) issued while computing s -> each load gets ~2 compute phases of
// latency cover. Raw s_barrier + inline-asm s_waitcnt vmcnt(8) (never 0 in
// the main loop) replaces __syncthreads' forced vmcnt(0) drain (the m97-
// structure ~20% stall). sched_barrier(0) fences stop hipcc hoisting
// ds_reads across the wait (rule #18). Ring safety: 2 barriers/K-step;
// stage(s+3) (into buf s%3) can only issue after barrier#2(s), which all
// waves reach only after finishing reads of buf s%3.
// ---------------------------------------------------------------------------
template<bool RELU, bool OUT_BF16, bool OUT_F32>
__device__ __forceinline__ void gemm_core(const bf16_t* __restrict__ A, int lda,
                                          const bf16_t* __restrict__ Bt, int ldb,
                                          const float* __restrict__ bias, bool useBias,
                                          float* __restrict__ Cf,
                                          bf16_t* __restrict__ Cb,
                                          int N, int Klen, int m0, int n0,
                                          bf16_t* sA, bf16_t* sB) {  // each [3][4096]
    const int tid = threadIdx.x;
    const int lane = tid & 63, wave = tid >> 6;
    const int g = lane >> 4, r = lane & 15;
    const int wm = (wave >> 1) * 64, wn = (wave & 1) * 64;

    const bf16_t* Ablk = A + (size_t)m0 * lda;
    const bf16_t* Bblk = Bt + (size_t)n0 * ldb;
    const int c0 = wave * 64 + lane;
    const int c1 = c0 + 256;

    const bf16_t* a0 = Ablk + (size_t)(c0 >> 2) * lda + (c0 & 3) * 8;
    const bf16_t* a1 = Ablk + (size_t)(c1 >> 2) * lda + (c1 & 3) * 8;
    const bf16_t* b0 = Bblk + (size_t)(c0 >> 2) * ldb + (c0 & 3) * 8;
    const bf16_t* b1 = Bblk + (size_t)(c1 >> 2) * ldb + (c1 & 3) * 8;

    f32x4 acc[4][4];
#pragma unroll
    for (int i = 0; i < 4; i++)
#pragma unroll
        for (int j = 0; j < 4; j++)
#pragma unroll
            for (int e = 0; e < 4; e++) acc[i][j][e] = 0.f;

    auto stage = [&](int buf, int k0) {
        gload_lds16(a0 + k0, sA + buf * 4096 + wave * 512);
        gload_lds16(a1 + k0, sA + buf * 4096 + 2048 + wave * 512);
        gload_lds16(b0 + k0, sB + buf * 4096 + wave * 512);
        gload_lds16(b1 + k0, sB + buf * 4096 + 2048 + wave * 512);
    };
    auto compute = [&](int buf) {
        bf16x8 a[4], b[4];
#pragma unroll
        for (int i = 0; i < 4; i++)
            a[i] = *(const bf16x8*)(sA + buf * 4096 + (wm + i * 16 + r) * 32 + g * 8);
#pragma unroll
        for (int j = 0; j < 4; j++)
            b[j] = *(const bf16x8*)(sB + buf * 4096 + (wn + j * 16 + r) * 32 + g * 8);
#pragma unroll
        for (int i = 0; i < 4; i++)
#pragma unroll
            for (int j = 0; j < 4; j++)
                acc[i][j] = mfma16(a[i], b[j], acc[i][j]);
    };

    const int nk = Klen >> 5;   // >= 16 at all call sites
    stage(0, 0);
    stage(1, 32);
    int bc = 0, bs = 2;
    for (int s = 0; s < nk; ++s) {
        if (s + 2 < nk) {
            stage(bs, (s + 2) * 32);
            asm volatile("s_waitcnt vmcnt(8)" ::: "memory");   // stage s landed
        } else if (s + 1 < nk) {
            asm volatile("s_waitcnt vmcnt(4)" ::: "memory");
        } else {
            asm volatile("s_waitcnt vmcnt(0)" ::: "memory");
        }
        __builtin_amdgcn_s_barrier();            // raw: no forced drain
        __builtin_amdgcn_sched_barrier(0);       // no ds_read hoist above
        compute(bc);
        __builtin_amdgcn_sched_barrier(0);       // no ds_read sink below
        __builtin_amdgcn_s_barrier();            // reads done before re-stage
        bc = (bc + 1 == 3) ? 0 : bc + 1;
        bs = (bs + 1 == 3) ? 0 : bs + 1;
    }

#pragma unroll
    for (int j = 0; j < 4; j++) {
        int n = n0 + wn + j * 16 + r;
        float bv = useBias ? bias[n] : 0.f;
#pragma unroll
        for (int i = 0; i < 4; i++) {
#pragma unroll
            for (int rr = 0; rr < 4; rr++) {
                int mrow = m0 + wm + i * 16 + g * 4 + rr;
                float val = acc[i][j][rr] + bv;
                if (RELU) val = fmaxf(val, 0.f);
                if (OUT_F32) Cf[(size_t)mrow * N + n] = val;
                if (OUT_BF16) Cb[(size_t)mrow * N + n] = (bf16_t)val;
            }
        }
    }
}

// split-K wrapper (z = K-chunk); XCD-swizzled grid
template<bool RELU, bool OUT_BF16, bool OUT_F32>
__global__ __launch_bounds__(256) void gemm_bt(const bf16_t* __restrict__ A, int lda,
                                               const bf16_t* __restrict__ Bt, int ldb,
                                               const float* __restrict__ bias,
                                               float* __restrict__ Cf0,
                                               float* __restrict__ Cf1,
                                               bf16_t* __restrict__ Cb,
                                               int N, int Klen) {
    __shared__ bf16_t sA[3 * 4096];
    __shared__ bf16_t sB[3 * 4096];
    const int lin = blockIdx.x + gridDim.x * (blockIdx.y + gridDim.y * blockIdx.z);
    const int nwg = gridDim.x * gridDim.y * gridDim.z;
    const int swz = xcd_swz(lin, nwg);
    const int bx = swz % gridDim.x;
    const int rest = swz / gridDim.x;
    const int by = rest % gridDim.y;
    const int bz = rest / gridDim.y;
    const int koff = bz * Klen;
    gemm_core<RELU, OUT_BF16, OUT_F32>(A + koff, lda, Bt + koff, ldb, bias, bz == 0,
                                       bz ? Cf1 : Cf0, Cb, N, Klen, bx * 128, by * 128, sA, sB);
}

// grouped QKV: z selects (A, W, bias, C)
__global__ __launch_bounds__(256) void gemm_qkv(const bf16_t* __restrict__ A0,
                                                const bf16_t* __restrict__ A1,
                                                const bf16_t* __restrict__ A2,
                                                const bf16_t* __restrict__ B0,
                                                const bf16_t* __restrict__ B1,
                                                const bf16_t* __restrict__ B2,
                                                const float* __restrict__ b0,
                                                const float* __restrict__ b1,
                                                const float* __restrict__ b2,
                                                bf16_t* __restrict__ C0,
                                                bf16_t* __restrict__ C1,
                                                bf16_t* __restrict__ C2) {
    __shared__ bf16_t sA[3 * 4096];
    __shared__ bf16_t sB[3 * 4096];
    const int lin = blockIdx.x + gridDim.x * (blockIdx.y + gridDim.y * blockIdx.z);
    const int nwg = gridDim.x * gridDim.y * gridDim.z;
    const int swz = xcd_swz(lin, nwg);
    const int bx = swz % gridDim.x;
    const int rest = swz / gridDim.x;
    const int by = rest % gridDim.y;
    const int bz = rest / gridDim.y;
    const bf16_t* A = bz == 0 ? A0 : bz == 1 ? A1 : A2;
    const bf16_t* Bt = bz == 0 ? B0 : bz == 1 ? B1 : B2;
    const float* bias = bz == 0 ? b0 : bz == 1 ? b1 : b2;
    bf16_t* C = bz == 0 ? C0 : bz == 1 ? C1 : C2;
    gemm_core<false, true, false>(A, 1024, Bt, 1024, bias, true,
                                  nullptr, C, 1024, 1024, bx * 128, by * 128, sA, sB);
}

// ---------------------------------------------------------------------------
// Flash attention v4 (unchanged from R9/R10): LDS-staged K/V, both tiles
// XOR-swizzled, manual x2 unroll, 2-way merge. VALU-bound at ~80 us.
// ---------------------------------------------------------------------------
__device__ __forceinline__ void flash_tile(
    const char* kt, const char* vt, int l31, int hi,
    const bf16x8 (&bq)[4],
    f32x16& o0, f32x16& o1, float& mC, float& l_run)
{
    bf16x8 ak[4];
#pragma unroll
    for (int kb = 0; kb < 4; kb++)
        ak[kb] = *(const bf16x8*)(kt + l31 * 128 + (((kb << 1) | hi) ^ (l31 & 7)) * 16);
    bf16x8 av[4];
#pragma unroll
    for (int db = 0; db < 2; db++)
#pragma unroll
        for (int kb = 0; kb < 2; kb++)
            av[db * 2 + kb] = *(const bf16x8*)(vt + (db * 32 + l31) * 64 + ((((kb << 1) | hi)) ^ ((l31 >> 1) & 3)) * 16);

    f32x16 s;
#pragma unroll
    for (int e = 0; e < 16; e++) s[e] = 0.f;
#pragma unroll
    for (int kb = 0; kb < 4; kb++) s = mfma32(ak[kb], bq[kb], s);

    float ma = fmaxf(fmaxf(s[0], s[1]), fmaxf(s[2], s[3]));
    float mb = fmaxf(fmaxf(s[4], s[5]), fmaxf(s[6], s[7]));
    float mc = fmaxf(fmaxf(s[8], s[9]), fmaxf(s[10], s[11]));
    float md = fmaxf(fmaxf(s[12], s[13]), fmaxf(s[14], s[15]));
    float pmaxC = fmaxf(fmaxf(ma, mb), fmaxf(mc, md)) * CF;

    if (!__all(pmaxC <= mC + THRC)) {
        int2v pr = plswap(__float_as_int(pmaxC), __float_as_int(pmaxC));
        float rowmaxC = fmaxf(__int_as_float(pr[0]), __int_as_float(pr[1]));
        float mnewC = fmaxf(mC, rowmaxC);
        float alpha = exp2f(mC - mnewC);
        mC = mnewC;
        l_run *= alpha;
#pragma unroll
        for (int e = 0; e < 16; e++) { o0[e] *= alpha; o1[e] *= alpha; }
    }

#pragma unroll
    for (int e = 0; e < 16; e++) s[e] = exp2f(__builtin_fmaf(s[e], CF, -mC));
    float t0 = (s[0] + s[1]) + (s[2] + s[3]);
    float t1 = (s[4] + s[5]) + (s[6] + s[7]);
    float t2 = (s[8] + s[9]) + (s[10] + s[11]);
    float t3 = (s[12] + s[13]) + (s[14] + s[15]);
    l_run += (t0 + t1) + (t2 + t3);

#pragma unroll
    for (int kb2 = 0; kb2 < 2; kb2++) {
        const int bse = kb2 * 8;
        int W0 = packbf(s[bse + 0], s[bse + 1]);
        int W1 = packbf(s[bse + 2], s[bse + 3]);
        int W2 = packbf(s[bse + 4], s[bse + 5]);
        int W3 = packbf(s[bse + 6], s[bse + 7]);
        int2v r02 = plswap(W0, W2);
        int2v r13 = plswap(W1, W3);
        int4v fw; fw[0] = r02[0]; fw[1] = r13[0]; fw[2] = r02[1]; fw[3] = r13[1];
        bf16x8 pf = __builtin_bit_cast(bf16x8, fw);
        o0 = mfma32(av[kb2], pf, o0);
        o1 = mfma32(av[2 + kb2], pf, o1);
    }
}

__global__ __launch_bounds__(256) void flash_attn(const bf16_t* __restrict__ Qp,
                                                  const bf16_t* __restrict__ Kp,
                                                  const bf16_t* __restrict__ VT,
                                                  bf16_t* __restrict__ Oa) {
    __shared__ alignas(16) char lds[2][2][8192];  // [buf][half][K 4KB | V 4KB]
    const int tid = threadIdx.x;
    const int lane = tid & 63;
    const int wave = tid >> 6;
    const int half = wave >> 1;
    const int qt = wave & 1;
    const int l31 = lane & 31, hi = lane >> 5;

    const int lin = blockIdx.x + (blockIdx.y << 5) + (blockIdx.z << 9);
    const int swz = (lin & 7) * 128 + (lin >> 3);
    const int qb = swz & 31;
    const int h = (swz >> 5) & 15;
    const int b = swz >> 9;

    const int q0 = qb * 64 + qt * 32;

    const bf16_t* Qb = Qp + (size_t)b * S_SZ * D_MODEL + h * HEAD_DIM;
    const bf16_t* Kb = Kp + (size_t)b * S_SZ * D_MODEL + h * HEAD_DIM;
    const bf16_t* Vb = VT + ((size_t)(b * NUM_HEADS + h) * HEAD_DIM) * S_SZ;

    const int sh = wave & 1;
    const int skvbase = sh * (S_SZ / 2);
    const bool kRole = wave < 2;

    const bf16_t* src_run;
    size_t inner_stride;
    size_t tile_stride;
    char* dst0;
    char* dst1;
    if (kRole) {
        src_run = Kb + (size_t)(skvbase + (lane >> 3)) * D_MODEL + ((lane & 7) ^ (lane >> 3)) * 8;
        inner_stride = (size_t)8 * D_MODEL;
        tile_stride = (size_t)32 * D_MODEL;
        dst0 = &lds[0][sh][0] + lane * 16;
        dst1 = &lds[1][sh][0] + lane * 16;
    } else {
        src_run = Vb + (size_t)(lane >> 2) * S_SZ + skvbase + ((lane & 3) ^ ((lane >> 3) & 3)) * 8;
        inner_stride = (size_t)16 * S_SZ;
        tile_stride = 32;
        dst0 = &lds[0][sh][4096] + lane * 16;
        dst1 = &lds[1][sh][4096] + lane * 16;
    }

    bf16x8 bq[4];
#pragma unroll
    for (int kb = 0; kb < 4; kb++)
        bq[kb] = *(const bf16x8*)(Qb + (size_t)(q0 + l31) * D_MODEL + kb * 16 + hi * 8);

    f32x16 o0, o1;
#pragma unroll
    for (int e = 0; e < 16; e++) { o0[e] = 0.f; o1[e] = 0.f; }
    float mC = -1e30f, l_run = 0.f;

    const char* kt0 = &lds[0][half][0];
    const char* vt0 = &lds[0][half][4096];
    const char* kt1 = &lds[1][half][0];
    const char* vt1 = &lds[1][half][4096];

#pragma unroll
    for (int ii = 0; ii < 4; ii++)
        gload_lds16(src_run + ii * inner_stride, dst0 + ii * 1024);
    src_run += tile_stride;
    __syncthreads();

    for (int t = 0; t < 32; t += 2) {
#pragma unroll
        for (int ii = 0; ii < 4; ii++)
            gload_lds16(src_run + ii * inner_stride, dst1 + ii * 1024);
        src_run += tile_stride;
        flash_tile(kt0, vt0, l31, hi, bq, o0, o1, mC, l_run);
        __syncthreads();

        if (t + 2 < 32) {
#pragma unroll
            for (int ii = 0; ii < 4; ii++)
                gload_lds16(src_run + ii * inner_stride, dst0 + ii * 1024);
            src_run += tile_stride;
        }
        flash_tile(kt1, vt1, l31, hi, bq, o0, o1, mC, l_run);
        __syncthreads();
    }

    int2v lp = plswap(__float_as_int(l_run), __float_as_int(l_run));
    l_run = __int_as_float(lp[0]) + __int_as_float(lp[1]);

    float (*obuf)[2][64] = (float (*)[2][64])(&lds[0][0][0]);
    float (*mrg)[64][2] = (float (*)[64][2])(&lds[0][0][0] + 16384);
    if (half == 1) {
        mrg[qt][lane][0] = mC;
        mrg[qt][lane][1] = l_run;
#pragma unroll
        for (int e = 0; e < 16; e++) {
            obuf[e][qt][lane] = o0[e];
            obuf[16 + e][qt][lane] = o1[e];
        }
    }
    __syncthreads();
    if (half == 0) {
        const float m2C = mrg[qt][lane][0], l2 = mrg[qt][lane][1];
        const float mm = fmaxf(mC, m2C);
        const float e1 = exp2f(mC - mm);
        const float e2 = exp2f(m2C - mm);
        const float linv = 1.f / (l_run * e1 + l2 * e2);
        bf16_t* Orow = Oa + ((size_t)b * S_SZ + q0 + l31) * D_MODEL + h * HEAD_DIM;
#pragma unroll
        for (int db = 0; db < 2; db++) {
#pragma unroll
            for (int rq = 0; rq < 4; rq++) {
                bf16x4 st;
#pragma unroll
                for (int i = 0; i < 4; i++) {
                    const int e = rq * 4 + i;
                    const float own = db ? o1[e] : o0[e];
                    const float oth = obuf[db * 16 + e][qt][lane];
                    st[i] = (bf16_t)((own * e1 + oth * e2) * linv);
                }
                *(bf16x4*)(Orow + db * 32 + rq * 8 + hi * 4) = st;
            }
        }
    }
}

// ---------------------------------------------------------------------------
// LayerNorm over 1024 with fused residual + optional second addend
// ---------------------------------------------------------------------------
__global__ __launch_bounds__(256) void ln_fused(const float* __restrict__ A,
                                                const float* __restrict__ A2,
                                                const float* __restrict__ R,
                                                const float* __restrict__ gamma,
                                                const float* __restrict__ beta,
                                                float* __restrict__ Xf,
                                                bf16_t* __restrict__ Xb) {
    __shared__ float red[8];
    int row = blockIdx.x, tid = threadIdx.x;
    size_t base = (size_t)row * D_MODEL + tid * 4;
    float4 a = *(const float4*)(A + base);
    float4 rv = *(const float4*)(R + base);
    float v0 = a.x + rv.x, v1 = a.y + rv.y, v2 = a.z + rv.z, v3 = a.w + rv.w;
    if (A2) {
        float4 a2 = *(const float4*)(A2 + base);
        v0 += a2.x; v1 += a2.y; v2 += a2.z; v3 += a2.w;
    }
    float s = v0 + v1 + v2 + v3;
    float q = v0 * v0 + v1 * v1 + v2 * v2 + v3 * v3;
#pragma unroll
    for (int off = 32; off; off >>= 1) { s += __shfl_down(s, off); q += __shfl_down(q, off); }
    if ((tid & 63) == 0) { red[tid >> 6] = s; red[4 + (tid >> 6)] = q; }
    __syncthreads();
    s = red[0] + red[1] + red[2] + red[3];
    q = red[4] + red[5] + red[6] + red[7];
    float mean = s * (1.f / D_MODEL);
    float var = q * (1.f / D_MODEL) - mean * mean;
    float rstd = rsqrtf(var + 1e-5f);
    float4 gm = *(const float4*)(gamma + tid * 4);
    float4 bt = *(const float4*)(beta + tid * 4);
    float y0 = (v0 - mean) * rstd * gm.x + bt.x;
    float y1 = (v1 - mean) * rstd * gm.y + bt.y;
    float y2 = (v2 - mean) * rstd * gm.z + bt.z;
    float y3 = (v3 - mean) * rstd * gm.w + bt.w;
    float4 yo; yo.x = y0; yo.y = y1; yo.z = y2; yo.w = y3;
    *(float4*)(Xf + base) = yo;
    if (Xb) {
        bf16x4 ob; ob[0] = (bf16_t)y0; ob[1] = (bf16_t)y1; ob[2] = (bf16_t)y2; ob[3] = (bf16_t)y3;
        *(bf16x4*)(Xb + base) = ob;
    }
}

// ---------------------------------------------------------------------------
extern "C" void kernel_launch(void* const* d_in, const int* in_sizes, int n_in,
                              void* d_out, int out_size, void* d_ws, size_t ws_size,
                              hipStream_t stream) {
    const float* value = (const float*)d_in[0];
    const float* key   = (const float*)d_in[1];
    const float* query = (const float*)d_in[2];
    const float* wq = (const float*)d_in[3];
    const float* bq = (const float*)d_in[4];
    const float* wk = (const float*)d_in[5];
    const float* bk = (const float*)d_in[6];
    const float* wv = (const float*)d_in[7];
    const float* bv = (const float*)d_in[8];
    const float* wo = (const float*)d_in[9];
    const float* bo = (const float*)d_in[10];
    const float* g1 = (const float*)d_in[11];
    const float* beta1 = (const float*)d_in[12];
    const float* w1 = (const float*)d_in[13];
    const float* b1 = (const float*)d_in[14];
    const float* w2 = (const float*)d_in[15];
    const float* b2 = (const float*)d_in[16];
    const float* g2 = (const float*)d_in[17];
    const float* beta2 = (const float*)d_in[18];
    (void)in_sizes; (void)n_in; (void)out_size; (void)ws_size;

    const size_t MB = 1ull << 20;
    char* ws = (char*)d_ws;
    bf16_t* wqT = (bf16_t*)(ws + 0 * MB);
    bf16_t* wkT = (bf16_t*)(ws + 2 * MB);
    bf16_t* wvT = (bf16_t*)(ws + 4 * MB);
    bf16_t* woT = (bf16_t*)(ws + 6 * MB);
    bf16_t* w1T = (bf16_t*)(ws + 8 * MB);
    bf16_t* w2T = (bf16_t*)(ws + 16 * MB);
    bf16_t* q_bf = (bf16_t*)(ws + 24 * MB);
    bf16_t* k_bf = (bf16_t*)(ws + 32 * MB);
    bf16_t* v_bf = (bf16_t*)(ws + 40 * MB);
    bf16_t* Qp  = (bf16_t*)(ws + 48 * MB);
    bf16_t* Kp  = (bf16_t*)(ws + 56 * MB);
    bf16_t* Vp  = (bf16_t*)(ws + 64 * MB);
    bf16_t* VT  = (bf16_t*)(ws + 72 * MB);
    bf16_t* attn = (bf16_t*)(ws + 24 * MB);   // reuse q_bf (dead after QKV gemm)
    float*  woP0 = (float*)(ws + 32 * MB);    // reuse k_bf..Qp (dead after flash)
    float*  woP1 = (float*)(ws + 48 * MB);
    float*  x_f = (float*)(ws + 64 * MB);     // reuse Vp/VT (dead after flash)
    bf16_t* x_b = (bf16_t*)(ws + 24 * MB);    // reuse attn (dead after WO gemm)
    bf16_t* h_b = (bf16_t*)(ws + 32 * MB);    // reuse woP (dead after LN1), 32MB
    float*  ffP0 = (float*)(ws + 80 * MB);
    float*  ffP1 = (float*)(ws + 96 * MB);

    dim3 blk(256);

    // 1) casts + weight transposes
    cast_f32_bf16<<<4096, blk, 0, stream>>>(query, q_bf);
    cast_f32_bf16<<<4096, blk, 0, stream>>>(key, k_bf);
    cast_f32_bf16<<<4096, blk, 0, stream>>>(value, v_bf);
    transpose_cast_w<<<dim3(32, 32), blk, 0, stream>>>(wq, wqT, 1024, 1024);
    transpose_cast_w<<<dim3(32, 32), blk, 0, stream>>>(wk, wkT, 1024, 1024);
    transpose_cast_w<<<dim3(32, 32), blk, 0, stream>>>(wv, wvT, 1024, 1024);
    transpose_cast_w<<<dim3(32, 32), blk, 0, stream>>>(wo, woT, 1024, 1024);
    transpose_cast_w<<<dim3(32, 128), blk, 0, stream>>>(w1, w1T, 1024, 4096);
    transpose_cast_w<<<dim3(128, 32), blk, 0, stream>>>(w2, w2T, 4096, 1024);

    // 2) grouped QKV projection
    gemm_qkv<<<dim3(32, 8, 3), blk, 0, stream>>>(q_bf, k_bf, v_bf, wqT, wkT, wvT,
                                                 bq, bk, bv, Qp, Kp, Vp);

    // 3) V transpose for PV A-operand
    transpose_v<<<dim3(64, 2, 32), blk, 0, stream>>>(Vp, VT);

    // 4) flash attention v4
    flash_attn<<<dim3(32, 16, 2), blk, 0, stream>>>(Qp, Kp, VT, attn);

    // 5) WO projection, split-K=2 (f32 partials)
    gemm_bt<false, false, true><<<dim3(32, 8, 2), blk, 0, stream>>>(attn, 1024, woT, 1024, bo, woP0, woP1, nullptr, D_MODEL, 512);

    // 6) LN1: x = LN(woP0 + woP1 + query)
    ln_fused<<<4096, blk, 0, stream>>>(woP0, woP1, query, g1, beta1, x_f, x_b);

    // 7) FF1 + ReLU (bf16 out)
    gemm_bt<true, true, false><<<dim3(32, 32, 1), blk, 0, stream>>>(x_b, 1024, w1T, 1024, b1, nullptr, nullptr, h_b, FF_DIM, 1024);

    // 8) FF2, split-K=2 (f32 partials)
    gemm_bt<false, false, true><<<dim3(32, 8, 2), blk, 0, stream>>>(h_b, 4096, w2T, 4096, b2, ffP0, ffP1, nullptr, D_MODEL, 2048);

    // 9) LN2 -> d_out
    ln_fused<<<4096, blk, 0, stream>>>(ffP0, ffP1, x_f, g2, beta2, (float*)d_out, nullptr);
}

// Round 12
// 263.564 us; speedup vs baseline: 2.7128x; 1.0784x over previous
//
#include <hip/hip_runtime.h>
#include <hip/hip_bf16.h>
#include <cstdint>
#include <math.h>

typedef __bf16 bf16_t;
typedef __attribute__((ext_vector_type(2))) __bf16 bf16x2;
typedef __attribute__((ext_vector_type(4))) __bf16 bf16x4;
typedef __attribute__((ext_vector_type(8))) __bf16 bf16x8;
typedef __attribute__((ext_vector_type(4))) float f32x4;
typedef __attribute__((ext_vector_type(16))) float f32x16;
typedef __attribute__((ext_vector_type(2))) int int2v;
typedef __attribute__((ext_vector_type(4))) int int4v;

#define B_SZ 2
#define S_SZ 2048
#define D_MODEL 1024
#define NUM_HEADS 16
#define HEAD_DIM 64
#define FF_DIM 4096
#define M_ROWS (B_SZ * S_SZ)   // 4096

// exp2-domain scale: 0.125 (1/sqrt(64)) * log2(e)
#define CF 0.180336880f
#define THRC 2.0f   // defer-max threshold in exp2 domain -> P bounded by 4

// single v_exp_f32 (2^x), NOT the precise OCML exp2f path (~10 instrs)
__device__ __forceinline__ float fexp2(float x) { return __builtin_amdgcn_exp2f(x); }

// ---------------------------------------------------------------------------
__device__ __forceinline__ void gload_lds16(const void* g, void* lds) {
    __builtin_amdgcn_global_load_lds(
        (const __attribute__((address_space(1))) void*)(uintptr_t)g,
        (__attribute__((address_space(3))) void*)(uint32_t)(uintptr_t)lds,
        16, 0, 0);
}

__device__ __forceinline__ f32x4 mfma16(bf16x8 a, bf16x8 b, f32x4 c) {
    return __builtin_amdgcn_mfma_f32_16x16x32_bf16(a, b, c, 0, 0, 0);
}
__device__ __forceinline__ f32x16 mfma32(bf16x8 a, bf16x8 b, f32x16 c) {
    return __builtin_amdgcn_mfma_f32_32x32x16_bf16(a, b, c, 0, 0, 0);
}
__device__ __forceinline__ int2v plswap(int a, int b) {
    return __builtin_amdgcn_permlane32_swap(a, b, false, false);
}
__device__ __forceinline__ int packbf(float a, float b) {
    bf16x2 t; t[0] = (bf16_t)a; t[1] = (bf16_t)b;
    return __builtin_bit_cast(int, t);
}

// XCD-aware bijective swizzle helper (nwg must be divisible by 8)
__device__ __forceinline__ int xcd_swz(int lin, int nwg) {
    return (lin & 7) * (nwg >> 3) + (lin >> 3);
}

// ---------------------------------------------------------------------------
// fused 3-input cast f32 -> bf16 (one launch instead of three)
// grid 12288 blocks; 4096 per input
// ---------------------------------------------------------------------------
__global__ __launch_bounds__(256) void cast3_f32_bf16(const float* __restrict__ in0,
                                                      const float* __restrict__ in1,
                                                      const float* __restrict__ in2,
                                                      bf16_t* __restrict__ out0,
                                                      bf16_t* __restrict__ out1,
                                                      bf16_t* __restrict__ out2) {
    int which = blockIdx.x >> 12;
    int blk = blockIdx.x & 4095;
    const float* in = which == 0 ? in0 : which == 1 ? in1 : in2;
    bf16_t* out = which == 0 ? out0 : which == 1 ? out1 : out2;
    size_t i = ((size_t)blk * 256 + threadIdx.x) * 4;
    float4 v = *(const float4*)(in + i);
    bf16x4 o;
    o[0] = (bf16_t)v.x; o[1] = (bf16_t)v.y; o[2] = (bf16_t)v.z; o[3] = (bf16_t)v.w;
    *(bf16x4*)(out + i) = o;
}

// ---------------------------------------------------------------------------
// W [K][N] f32 -> WT [N][K] bf16 (32x32 tiles); z selects among 4 square Ws
// ---------------------------------------------------------------------------
__global__ __launch_bounds__(256) void transpose_cast_w4(const float* __restrict__ W0,
                                                         const float* __restrict__ W1,
                                                         const float* __restrict__ W2,
                                                         const float* __restrict__ W3,
                                                         bf16_t* __restrict__ T0,
                                                         bf16_t* __restrict__ T1,
                                                         bf16_t* __restrict__ T2,
                                                         bf16_t* __restrict__ T3) {
    __shared__ float t[32][33];
    const int K = 1024, N = 1024;
    const float* W = blockIdx.z == 0 ? W0 : blockIdx.z == 1 ? W1 : blockIdx.z == 2 ? W2 : W3;
    bf16_t* WT = blockIdx.z == 0 ? T0 : blockIdx.z == 1 ? T1 : blockIdx.z == 2 ? T2 : T3;
    int tid = threadIdx.x;
    int rr = tid >> 3, cc = (tid & 7) * 4;
    int k0 = blockIdx.x * 32, n0 = blockIdx.y * 32;
    float4 v = *(const float4*)(W + (size_t)(k0 + rr) * N + n0 + cc);
    t[rr][cc + 0] = v.x; t[rr][cc + 1] = v.y; t[rr][cc + 2] = v.z; t[rr][cc + 3] = v.w;
    __syncthreads();
    bf16x4 o;
    o[0] = (bf16_t)t[cc + 0][rr]; o[1] = (bf16_t)t[cc + 1][rr];
    o[2] = (bf16_t)t[cc + 2][rr]; o[3] = (bf16_t)t[cc + 3][rr];
    *(bf16x4*)(WT + (size_t)(n0 + rr) * K + k0 + cc) = o;
}

__global__ __launch_bounds__(256) void transpose_cast_w(const float* __restrict__ W,
                                                        bf16_t* __restrict__ WT,
                                                        int K, int N) {
    __shared__ float t[32][33];
    int tid = threadIdx.x;
    int rr = tid >> 3, cc = (tid & 7) * 4;
    int k0 = blockIdx.x * 32, n0 = blockIdx.y * 32;
    float4 v = *(const float4*)(W + (size_t)(k0 + rr) * N + n0 + cc);
    t[rr][cc + 0] = v.x; t[rr][cc + 1] = v.y; t[rr][cc + 2] = v.z; t[rr][cc + 3] = v.w;
    __syncthreads();
    bf16x4 o;
    o[0] = (bf16_t)t[cc + 0][rr]; o[1] = (bf16_t)t[cc + 1][rr];
    o[2] = (bf16_t)t[cc + 2][rr]; o[3] = (bf16_t)t[cc + 3][rr];
    *(bf16x4*)(WT + (size_t)(n0 + rr) * K + k0 + cc) = o;
}

// ---------------------------------------------------------------------------
__global__ __launch_bounds__(256) void transpose_v(const bf16_t* __restrict__ Vp,
                                                   bf16_t* __restrict__ VT) {
    __shared__ bf16_t t[32][34];
    int tid = threadIdx.x;
    int rr = tid >> 3, cc = (tid & 7) * 4;
    int bh = blockIdx.z;
    int b = bh >> 4, h = bh & 15;
    int s0 = blockIdx.x * 32, d0 = blockIdx.y * 32;
    bf16x4 v = *(const bf16x4*)(Vp + ((size_t)(b * S_SZ + s0 + rr)) * D_MODEL + h * HEAD_DIM + d0 + cc);
    t[rr][cc + 0] = v[0]; t[rr][cc + 1] = v[1]; t[rr][cc + 2] = v[2]; t[rr][cc + 3] = v[3];
    __syncthreads();
    bf16x4 o;
    o[0] = t[cc + 0][rr]; o[1] = t[cc + 1][rr]; o[2] = t[cc + 2][rr]; o[3] = t[cc + 3][rr];
    *(bf16x4*)(VT + ((size_t)(bh * HEAD_DIM + d0 + rr)) * S_SZ + s0 + cc) = o;
}

// ---------------------------------------------------------------------------
// GEMM core v3 (unchanged from R11): counted-vmcnt 3-buffer ring.
// ---------------------------------------------------------------------------
template<bool RELU, bool OUT_BF16, bool OUT_F32>
__device__ __forceinline__ void gemm_core(const bf16_t* __restrict__ A, int lda,
                                          const bf16_t* __restrict__ Bt, int ldb,
                                          const float* __restrict__ bias, bool useBias,
                                          float* __restrict__ Cf,
                                          bf16_t* __restrict__ Cb,
                                          int N, int Klen, int m0, int n0,
                                          bf16_t* sA, bf16_t* sB) {  // each [3][4096]
    const int tid = threadIdx.x;
    const int lane = tid & 63, wave = tid >> 6;
    const int g = lane >> 4, r = lane & 15;
    const int wm = (wave >> 1) * 64, wn = (wave & 1) * 64;

    const bf16_t* Ablk = A + (size_t)m0 * lda;
    const bf16_t* Bblk = Bt + (size_t)n0 * ldb;
    const int c0 = wave * 64 + lane;
    const int c1 = c0 + 256;

    const bf16_t* a0 = Ablk + (size_t)(c0 >> 2) * lda + (c0 & 3) * 8;
    const bf16_t* a1 = Ablk + (size_t)(c1 >> 2) * lda + (c1 & 3) * 8;
    const bf16_t* b0 = Bblk + (size_t)(c0 >> 2) * ldb + (c0 & 3) * 8;
    const bf16_t* b1 = Bblk + (size_t)(c1 >> 2) * ldb + (c1 & 3) * 8;

    f32x4 acc[4][4];
#pragma unroll
    for (int i = 0; i < 4; i++)
#pragma unroll
        for (int j = 0; j < 4; j++)
#pragma unroll
            for (int e = 0; e < 4; e++) acc[i][j][e] = 0.f;

    auto stage = [&](int buf, int k0) {
        gload_lds16(a0 + k0, sA + buf * 4096 + wave * 512);
        gload_lds16(a1 + k0, sA + buf * 4096 + 2048 + wave * 512);
        gload_lds16(b0 + k0, sB + buf * 4096 + wave * 512);
        gload_lds16(b1 + k0, sB + buf * 4096 + 2048 + wave * 512);
    };
    auto compute = [&](int buf) {
        bf16x8 a[4], b[4];
#pragma unroll
        for (int i = 0; i < 4; i++)
            a[i] = *(const bf16x8*)(sA + buf * 4096 + (wm + i * 16 + r) * 32 + g * 8);
#pragma unroll
        for (int j = 0; j < 4; j++)
            b[j] = *(const bf16x8*)(sB + buf * 4096 + (wn + j * 16 + r) * 32 + g * 8);
#pragma unroll
        for (int i = 0; i < 4; i++)
#pragma unroll
            for (int j = 0; j < 4; j++)
                acc[i][j] = mfma16(a[i], b[j], acc[i][j]);
    };

    const int nk = Klen >> 5;
    stage(0, 0);
    stage(1, 32);
    int bc = 0, bs = 2;
    for (int s = 0; s < nk; ++s) {
        if (s + 2 < nk) {
            stage(bs, (s + 2) * 32);
            asm volatile("s_waitcnt vmcnt(8)" ::: "memory");
        } else if (s + 1 < nk) {
            asm volatile("s_waitcnt vmcnt(4)" ::: "memory");
        } else {
            asm volatile("s_waitcnt vmcnt(0)" ::: "memory");
        }
        __builtin_amdgcn_s_barrier();
        __builtin_amdgcn_sched_barrier(0);
        compute(bc);
        __builtin_amdgcn_sched_barrier(0);
        __builtin_amdgcn_s_barrier();
        bc = (bc + 1 == 3) ? 0 : bc + 1;
        bs = (bs + 1 == 3) ? 0 : bs + 1;
    }

#pragma unroll
    for (int j = 0; j < 4; j++) {
        int n = n0 + wn + j * 16 + r;
        float bv = useBias ? bias[n] : 0.f;
#pragma unroll
        for (int i = 0; i < 4; i++) {
#pragma unroll
            for (int rr = 0; rr < 4; rr++) {
                int mrow = m0 + wm + i * 16 + g * 4 + rr;
                float val = acc[i][j][rr] + bv;
                if (RELU) val = fmaxf(val, 0.f);
                if (OUT_F32) Cf[(size_t)mrow * N + n] = val;
                if (OUT_BF16) Cb[(size_t)mrow * N + n] = (bf16_t)val;
            }
        }
    }
}

// split-K wrapper (z = K-chunk); XCD-swizzled grid
template<bool RELU, bool OUT_BF16, bool OUT_F32>
__global__ __launch_bounds__(256) void gemm_bt(const bf16_t* __restrict__ A, int lda,
                                               const bf16_t* __restrict__ Bt, int ldb,
                                               const float* __restrict__ bias,
                                               float* __restrict__ Cf0,
                                               float* __restrict__ Cf1,
                                               bf16_t* __restrict__ Cb,
                                               int N, int Klen) {
    __shared__ bf16_t sA[3 * 4096];
    __shared__ bf16_t sB[3 * 4096];
    const int lin = blockIdx.x + gridDim.x * (blockIdx.y + gridDim.y * blockIdx.z);
    const int nwg = gridDim.x * gridDim.y * gridDim.z;
    const int swz = xcd_swz(lin, nwg);
    const int bx = swz % gridDim.x;
    const int rest = swz / gridDim.x;
    const int by = rest % gridDim.y;
    const int bz = rest / gridDim.y;
    const int koff = bz * Klen;
    gemm_core<RELU, OUT_BF16, OUT_F32>(A + koff, lda, Bt + koff, ldb, bias, bz == 0,
                                       bz ? Cf1 : Cf0, Cb, N, Klen, bx * 128, by * 128, sA, sB);
}

// grouped QKV: z selects (A, W, bias, C)
__global__ __launch_bounds__(256) void gemm_qkv(const bf16_t* __restrict__ A0,
                                                const bf16_t* __restrict__ A1,
                                                const bf16_t* __restrict__ A2,
                                                const bf16_t* __restrict__ B0,
                                                const bf16_t* __restrict__ B1,
                                                const bf16_t* __restrict__ B2,
                                                const float* __restrict__ b0,
                                                const float* __restrict__ b1,
                                                const float* __restrict__ b2,
                                                bf16_t* __restrict__ C0,
                                                bf16_t* __restrict__ C1,
                                                bf16_t* __restrict__ C2) {
    __shared__ bf16_t sA[3 * 4096];
    __shared__ bf16_t sB[3 * 4096];
    const int lin = blockIdx.x + gridDim.x * (blockIdx.y + gridDim.y * blockIdx.z);
    const int nwg = gridDim.x * gridDim.y * gridDim.z;
    const int swz = xcd_swz(lin, nwg);
    const int bx = swz % gridDim.x;
    const int rest = swz / gridDim.x;
    const int by = rest % gridDim.y;
    const int bz = rest / gridDim.y;
    const bf16_t* A = bz == 0 ? A0 : bz == 1 ? A1 : A2;
    const bf16_t* Bt = bz == 0 ? B0 : bz == 1 ? B1 : B2;
    const float* bias = bz == 0 ? b0 : bz == 1 ? b1 : b2;
    bf16_t* C = bz == 0 ? C0 : bz == 1 ? C1 : C2;
    gemm_core<false, true, false>(A, 1024, Bt, 1024, bias, true,
                                  nullptr, C, 1024, 1024, bx * 128, by * 128, sA, sB);
}

// ---------------------------------------------------------------------------
// Flash attention v5: v4 structure + single-instruction v_exp_f32 exponentials
// (plain exp2f lowers to the precise OCML path ~10 instrs without fast-math —
// R4..R10 were paying ~150 extra VALU ops/tile for it).
// ---------------------------------------------------------------------------
__device__ __forceinline__ void flash_tile(
    const char* kt, const char* vt, int l31, int hi,
    const bf16x8 (&bq)[4],
    f32x16& o0, f32x16& o1, float& mC, float& l_run)
{
    bf16x8 ak[4];
#pragma unroll
    for (int kb = 0; kb < 4; kb++)
        ak[kb] = *(const bf16x8*)(kt + l31 * 128 + (((kb << 1) | hi) ^ (l31 & 7)) * 16);
    bf16x8 av[4];
#pragma unroll
    for (int db = 0; db < 2; db++)
#pragma unroll
        for (int kb = 0; kb < 2; kb++)
            av[db * 2 + kb] = *(const bf16x8*)(vt + (db * 32 + l31) * 64 + ((((kb << 1) | hi)) ^ ((l31 >> 1) & 3)) * 16);

    f32x16 s;
#pragma unroll
    for (int e = 0; e < 16; e++) s[e] = 0.f;
#pragma unroll
    for (int kb = 0; kb < 4; kb++) s = mfma32(ak[kb], bq[kb], s);

    float ma = fmaxf(fmaxf(s[0], s[1]), fmaxf(s[2], s[3]));
    float mb = fmaxf(fmaxf(s[4], s[5]), fmaxf(s[6], s[7]));
    float mc = fmaxf(fmaxf(s[8], s[9]), fmaxf(s[10], s[11]));
    float md = fmaxf(fmaxf(s[12], s[13]), fmaxf(s[14], s[15]));
    float pmaxC = fmaxf(fmaxf(ma, mb), fmaxf(mc, md)) * CF;

    if (!__all(pmaxC <= mC + THRC)) {
        int2v pr = plswap(__float_as_int(pmaxC), __float_as_int(pmaxC));
        float rowmaxC = fmaxf(__int_as_float(pr[0]), __int_as_float(pr[1]));
        float mnewC = fmaxf(mC, rowmaxC);
        float alpha = fexp2(mC - mnewC);
        mC = mnewC;
        l_run *= alpha;
#pragma unroll
        for (int e = 0; e < 16; e++) { o0[e] *= alpha; o1[e] *= alpha; }
    }

#pragma unroll
    for (int e = 0; e < 16; e++) s[e] = fexp2(__builtin_fmaf(s[e], CF, -mC));
    float t0 = (s[0] + s[1]) + (s[2] + s[3]);
    float t1 = (s[4] + s[5]) + (s[6] + s[7]);
    float t2 = (s[8] + s[9]) + (s[10] + s[11]);
    float t3 = (s[12] + s[13]) + (s[14] + s[15]);
    l_run += (t0 + t1) + (t2 + t3);

#pragma unroll
    for (int kb2 = 0; kb2 < 2; kb2++) {
        const int bse = kb2 * 8;
        int W0 = packbf(s[bse + 0], s[bse + 1]);
        int W1 = packbf(s[bse + 2], s[bse + 3]);
        int W2 = packbf(s[bse + 4], s[bse + 5]);
        int W3 = packbf(s[bse + 6], s[bse + 7]);
        int2v r02 = plswap(W0, W2);
        int2v r13 = plswap(W1, W3);
        int4v fw; fw[0] = r02[0]; fw[1] = r13[0]; fw[2] = r02[1]; fw[3] = r13[1];
        bf16x8 pf = __builtin_bit_cast(bf16x8, fw);
        o0 = mfma32(av[kb2], pf, o0);
        o1 = mfma32(av[2 + kb2], pf, o1);
    }
}

__global__ __launch_bounds__(256) void flash_attn(const bf16_t* __restrict__ Qp,
                                                  const bf16_t* __restrict__ Kp,
                                                  const bf16_t* __restrict__ VT,
                                                  bf16_t* __restrict__ Oa) {
    __shared__ alignas(16) char lds[2][2][8192];  // [buf][half][K 4KB | V 4KB]
    const int tid = threadIdx.x;
    const int lane = tid & 63;
    const int wave = tid >> 6;
    const int half = wave >> 1;
    const int qt = wave & 1;
    const int l31 = lane & 31, hi = lane >> 5;

    const int lin = blockIdx.x + (blockIdx.y << 5) + (blockIdx.z << 9);
    const int swz = (lin & 7) * 128 + (lin >> 3);
    const int qb = swz & 31;
    const int h = (swz >> 5) & 15;
    const int b = swz >> 9;

    const int q0 = qb * 64 + qt * 32;

    const bf16_t* Qb = Qp + (size_t)b * S_SZ * D_MODEL + h * HEAD_DIM;
    const bf16_t* Kb = Kp + (size_t)b * S_SZ * D_MODEL + h * HEAD_DIM;
    const bf16_t* Vb = VT + ((size_t)(b * NUM_HEADS + h) * HEAD_DIM) * S_SZ;

    const int sh = wave & 1;
    const int skvbase = sh * (S_SZ / 2);
    const bool kRole = wave < 2;

    const bf16_t* src_run;
    size_t inner_stride;
    size_t tile_stride;
    char* dst0;
    char* dst1;
    if (kRole) {
        src_run = Kb + (size_t)(skvbase + (lane >> 3)) * D_MODEL + ((lane & 7) ^ (lane >> 3)) * 8;
        inner_stride = (size_t)8 * D_MODEL;
        tile_stride = (size_t)32 * D_MODEL;
        dst0 = &lds[0][sh][0] + lane * 16;
        dst1 = &lds[1][sh][0] + lane * 16;
    } else {
        src_run = Vb + (size_t)(lane >> 2) * S_SZ + skvbase + ((lane & 3) ^ ((lane >> 3) & 3)) * 8;
        inner_stride = (size_t)16 * S_SZ;
        tile_stride = 32;
        dst0 = &lds[0][sh][4096] + lane * 16;
        dst1 = &lds[1][sh][4096] + lane * 16;
    }

    bf16x8 bq[4];
#pragma unroll
    for (int kb = 0; kb < 4; kb++)
        bq[kb] = *(const bf16x8*)(Qb + (size_t)(q0 + l31) * D_MODEL + kb * 16 + hi * 8);

    f32x16 o0, o1;
#pragma unroll
    for (int e = 0; e < 16; e++) { o0[e] = 0.f; o1[e] = 0.f; }
    float mC = -1e30f, l_run = 0.f;

    const char* kt0 = &lds[0][half][0];
    const char* vt0 = &lds[0][half][4096];
    const char* kt1 = &lds[1][half][0];
    const char* vt1 = &lds[1][half][4096];

#pragma unroll
    for (int ii = 0; ii < 4; ii++)
        gload_lds16(src_run + ii * inner_stride, dst0 + ii * 1024);
    src_run += tile_stride;
    __syncthreads();

    for (int t = 0; t < 32; t += 2) {
#pragma unroll
        for (int ii = 0; ii < 4; ii++)
            gload_lds16(src_run + ii * inner_stride, dst1 + ii * 1024);
        src_run += tile_stride;
        flash_tile(kt0, vt0, l31, hi, bq, o0, o1, mC, l_run);
        __syncthreads();

        if (t + 2 < 32) {
#pragma unroll
            for (int ii = 0; ii < 4; ii++)
                gload_lds16(src_run + ii * inner_stride, dst0 + ii * 1024);
            src_run += tile_stride;
        }
        flash_tile(kt1, vt1, l31, hi, bq, o0, o1, mC, l_run);
        __syncthreads();
    }

    int2v lp = plswap(__float_as_int(l_run), __float_as_int(l_run));
    l_run = __int_as_float(lp[0]) + __int_as_float(lp[1]);

    float (*obuf)[2][64] = (float (*)[2][64])(&lds[0][0][0]);
    float (*mrg)[64][2] = (float (*)[64][2])(&lds[0][0][0] + 16384);
    if (half == 1) {
        mrg[qt][lane][0] = mC;
        mrg[qt][lane][1] = l_run;
#pragma unroll
        for (int e = 0; e < 16; e++) {
            obuf[e][qt][lane] = o0[e];
            obuf[16 + e][qt][lane] = o1[e];
        }
    }
    __syncthreads();
    if (half == 0) {
        const float m2C = mrg[qt][lane][0], l2 = mrg[qt][lane][1];
        const float mm = fmaxf(mC, m2C);
        const float e1 = fexp2(mC - mm);
        const float e2 = fexp2(m2C - mm);
        const float linv = 1.f / (l_run * e1 + l2 * e2);
        bf16_t* Orow = Oa + ((size_t)b * S_SZ + q0 + l31) * D_MODEL + h * HEAD_DIM;
#pragma unroll
        for (int db = 0; db < 2; db++) {
#pragma unroll
            for (int rq = 0; rq < 4; rq++) {
                bf16x4 st;
#pragma unroll
                for (int i = 0; i < 4; i++) {
                    const int e = rq * 4 + i;
                    const float own = db ? o1[e] : o0[e];
                    const float oth = obuf[db * 16 + e][qt][lane];
                    st[i] = (bf16_t)((own * e1 + oth * e2) * linv);
                }
                *(bf16x4*)(Orow + db * 32 + rq * 8 + hi * 4) = st;
            }
        }
    }
}

// ---------------------------------------------------------------------------
// LayerNorm over 1024 with fused residual + optional second addend
// ---------------------------------------------------------------------------
__global__ __launch_bounds__(256) void ln_fused(const float* __restrict__ A,
                                                const float* __restrict__ A2,
                                                const float* __restrict__ R,
                                                const float* __restrict__ gamma,
                                                const float* __restrict__ beta,
                                                float* __restrict__ Xf,
                                                bf16_t* __restrict__ Xb) {
    __shared__ float red[8];
    int row = blockIdx.x, tid = threadIdx.x;
    size_t base = (size_t)row * D_MODEL + tid * 4;
    float4 a = *(const float4*)(A + base);
    float4 rv = *(const float4*)(R + base);
    float v0 = a.x + rv.x, v1 = a.y + rv.y, v2 = a.z + rv.z, v3 = a.w + rv.w;
    if (A2) {
        float4 a2 = *(const float4*)(A2 + base);
        v0 += a2.x; v1 += a2.y; v2 += a2.z; v3 += a2.w;
    }
    float s = v0 + v1 + v2 + v3;
    float q = v0 * v0 + v1 * v1 + v2 * v2 + v3 * v3;
#pragma unroll
    for (int off = 32; off; off >>= 1) { s += __shfl_down(s, off); q += __shfl_down(q, off); }
    if ((tid & 63) == 0) { red[tid >> 6] = s; red[4 + (tid >> 6)] = q; }
    __syncthreads();
    s = red[0] + red[1] + red[2] + red[3];
    q = red[4] + red[5] + red[6] + red[7];
    float mean = s * (1.f / D_MODEL);
    float var = q * (1.f / D_MODEL) - mean * mean;
    float rstd = rsqrtf(var + 1e-5f);
    float4 gm = *(const float4*)(gamma + tid * 4);
    float4 bt = *(const float4*)(beta + tid * 4);
    float y0 = (v0 - mean) * rstd * gm.x + bt.x;
    float y1 = (v1 - mean) * rstd * gm.y + bt.y;
    float y2 = (v2 - mean) * rstd * gm.z + bt.z;
    float y3 = (v3 - mean) * rstd * gm.w + bt.w;
    float4 yo; yo.x = y0; yo.y = y1; yo.z = y2; yo.w = y3;
    *(float4*)(Xf + base) = yo;
    if (Xb) {
        bf16x4 ob; ob[0] = (bf16_t)y0; ob[1] = (bf16_t)y1; ob[2] = (bf16_t)y2; ob[3] = (bf16_t)y3;
        *(bf16x4*)(Xb + base) = ob;
    }
}

// ---------------------------------------------------------------------------
extern "C" void kernel_launch(void* const* d_in, const int* in_sizes, int n_in,
                              void* d_out, int out_size, void* d_ws, size_t ws_size,
                              hipStream_t stream) {
    const float* value = (const float*)d_in[0];
    const float* key   = (const float*)d_in[1];
    const float* query = (const float*)d_in[2];
    const float* wq = (const float*)d_in[3];
    const float* bq = (const float*)d_in[4];
    const float* wk = (const float*)d_in[5];
    const float* bk = (const float*)d_in[6];
    const float* wv = (const float*)d_in[7];
    const float* bv = (const float*)d_in[8];
    const float* wo = (const float*)d_in[9];
    const float* bo = (const float*)d_in[10];
    const float* g1 = (const float*)d_in[11];
    const float* beta1 = (const float*)d_in[12];
    const float* w1 = (const float*)d_in[13];
    const float* b1 = (const float*)d_in[14];
    const float* w2 = (const float*)d_in[15];
    const float* b2 = (const float*)d_in[16];
    const float* g2 = (const float*)d_in[17];
    const float* beta2 = (const float*)d_in[18];
    (void)in_sizes; (void)n_in; (void)out_size; (void)ws_size;

    const size_t MB = 1ull << 20;
    char* ws = (char*)d_ws;
    bf16_t* wqT = (bf16_t*)(ws + 0 * MB);
    bf16_t* wkT = (bf16_t*)(ws + 2 * MB);
    bf16_t* wvT = (bf16_t*)(ws + 4 * MB);
    bf16_t* woT = (bf16_t*)(ws + 6 * MB);
    bf16_t* w1T = (bf16_t*)(ws + 8 * MB);
    bf16_t* w2T = (bf16_t*)(ws + 16 * MB);
    bf16_t* q_bf = (bf16_t*)(ws + 24 * MB);
    bf16_t* k_bf = (bf16_t*)(ws + 32 * MB);
    bf16_t* v_bf = (bf16_t*)(ws + 40 * MB);
    bf16_t* Qp  = (bf16_t*)(ws + 48 * MB);
    bf16_t* Kp  = (bf16_t*)(ws + 56 * MB);
    bf16_t* Vp  = (bf16_t*)(ws + 64 * MB);
    bf16_t* VT  = (bf16_t*)(ws + 72 * MB);
    bf16_t* attn = (bf16_t*)(ws + 24 * MB);   // reuse q_bf (dead after QKV gemm)
    float*  woP0 = (float*)(ws + 32 * MB);    // reuse k_bf..Qp (dead after flash)
    float*  woP1 = (float*)(ws + 48 * MB);
    float*  x_f = (float*)(ws + 64 * MB);     // reuse Vp/VT (dead after flash)
    bf16_t* x_b = (bf16_t*)(ws + 24 * MB);    // reuse attn (dead after WO gemm)
    bf16_t* h_b = (bf16_t*)(ws + 32 * MB);    // reuse woP (dead after LN1), 32MB
    float*  ffP0 = (float*)(ws + 80 * MB);
    float*  ffP1 = (float*)(ws + 96 * MB);

    dim3 blk(256);

    // 1) casts (one launch) + weight transposes (one launch for the 4 square)
    cast3_f32_bf16<<<12288, blk, 0, stream>>>(query, key, value, q_bf, k_bf, v_bf);
    transpose_cast_w4<<<dim3(32, 32, 4), blk, 0, stream>>>(wq, wk, wv, wo, wqT, wkT, wvT, woT);
    transpose_cast_w<<<dim3(32, 128), blk, 0, stream>>>(w1, w1T, 1024, 4096);
    transpose_cast_w<<<dim3(128, 32), blk, 0, stream>>>(w2, w2T, 4096, 1024);

    // 2) grouped QKV projection
    gemm_qkv<<<dim3(32, 8, 3), blk, 0, stream>>>(q_bf, k_bf, v_bf, wqT, wkT, wvT,
                                                 bq, bk, bv, Qp, Kp, Vp);

    // 3) V transpose for PV A-operand
    transpose_v<<<dim3(64, 2, 32), blk, 0, stream>>>(Vp, VT);

    // 4) flash attention v5 (fast exp2)
    flash_attn<<<dim3(32, 16, 2), blk, 0, stream>>>(Qp, Kp, VT, attn);

    // 5) WO projection, split-K=2 (f32 partials)
    gemm_bt<false, false, true><<<dim3(32, 8, 2), blk, 0, stream>>>(attn, 1024, woT, 1024, bo, woP0, woP1, nullptr, D_MODEL, 512);

    // 6) LN1: x = LN(woP0 + woP1 + query)
    ln_fused<<<4096, blk, 0, stream>>>(woP0, woP1, query, g1, beta1, x_f, x_b);

    // 7) FF1 + ReLU (bf16 out)
    gemm_bt<true, true, false><<<dim3(32, 32, 1), blk, 0, stream>>>(x_b, 1024, w1T, 1024, b1, nullptr, nullptr, h_b, FF_DIM, 1024);

    // 8) FF2, split-K=2 (f32 partials)
    gemm_bt<false, false, true><<<dim3(32, 8, 2), blk, 0, stream>>>(h_b, 4096, w2T, 4096, b2, ffP0, ffP1, nullptr, D_MODEL, 2048);

    // 9) LN2 -> d_out
    ln_fused<<<4096, blk, 0, stream>>>(ffP0, ffP1, x_f, g2, beta2, (float*)d_out, nullptr);
}

// Round 13
// 259.680 us; speedup vs baseline: 2.7533x; 1.0150x over previous
//
#include <hip/hip_runtime.h>
#include <hip/hip_bf16.h>
#include <cstdint>
#include <math.h>

typedef __bf16 bf16_t;
typedef __attribute__((ext_vector_type(2))) __bf16 bf16x2;
typedef __attribute__((ext_vector_type(4))) __bf16 bf16x4;
typedef __attribute__((ext_vector_type(8))) __bf16 bf16x8;
typedef __attribute__((ext_vector_type(4))) float f32x4;
typedef __attribute__((ext_vector_type(16))) float f32x16;
typedef __attribute__((ext_vector_type(2))) int int2v;
typedef __attribute__((ext_vector_type(4))) int int4v;

#define B_SZ 2
#define S_SZ 2048
#define D_MODEL 1024
#define NUM_HEADS 16
#define HEAD_DIM 64
#define FF_DIM 4096
#define M_ROWS (B_SZ * S_SZ)   // 4096

// exp2-domain scale: 0.125 (1/sqrt(64)) * log2(e)
#define CF 0.180336880f
#define THRC 2.0f

__device__ __forceinline__ float fexp2(float x) { return __builtin_amdgcn_exp2f(x); }

// ---------------------------------------------------------------------------
__device__ __forceinline__ void gload_lds16(const void* g, void* lds) {
    __builtin_amdgcn_global_load_lds(
        (const __attribute__((address_space(1))) void*)(uintptr_t)g,
        (__attribute__((address_space(3))) void*)(uint32_t)(uintptr_t)lds,
        16, 0, 0);
}

__device__ __forceinline__ f32x4 mfma16(bf16x8 a, bf16x8 b, f32x4 c) {
    return __builtin_amdgcn_mfma_f32_16x16x32_bf16(a, b, c, 0, 0, 0);
}
__device__ __forceinline__ f32x16 mfma32(bf16x8 a, bf16x8 b, f32x16 c) {
    return __builtin_amdgcn_mfma_f32_32x32x16_bf16(a, b, c, 0, 0, 0);
}
__device__ __forceinline__ int2v plswap(int a, int b) {
    return __builtin_amdgcn_permlane32_swap(a, b, false, false);
}
__device__ __forceinline__ int packbf(float a, float b) {
    bf16x2 t; t[0] = (bf16_t)a; t[1] = (bf16_t)b;
    return __builtin_bit_cast(int, t);
}

__device__ __forceinline__ int xcd_swz(int lin, int nwg) {
    return (lin & 7) * (nwg >> 3) + (lin >> 3);
}

// ---------------------------------------------------------------------------
__global__ __launch_bounds__(256) void cast3_f32_bf16(const float* __restrict__ in0,
                                                      const float* __restrict__ in1,
                                                      const float* __restrict__ in2,
                                                      bf16_t* __restrict__ out0,
                                                      bf16_t* __restrict__ out1,
                                                      bf16_t* __restrict__ out2) {
    int which = blockIdx.x >> 12;
    int blk = blockIdx.x & 4095;
    const float* in = which == 0 ? in0 : which == 1 ? in1 : in2;
    bf16_t* out = which == 0 ? out0 : which == 1 ? out1 : out2;
    size_t i = ((size_t)blk * 256 + threadIdx.x) * 4;
    float4 v = *(const float4*)(in + i);
    bf16x4 o;
    o[0] = (bf16_t)v.x; o[1] = (bf16_t)v.y; o[2] = (bf16_t)v.z; o[3] = (bf16_t)v.w;
    *(bf16x4*)(out + i) = o;
}

// ---------------------------------------------------------------------------
__global__ __launch_bounds__(256) void transpose_cast_w4(const float* __restrict__ W0,
                                                         const float* __restrict__ W1,
                                                         const float* __restrict__ W2,
                                                         const float* __restrict__ W3,
                                                         bf16_t* __restrict__ T0,
                                                         bf16_t* __restrict__ T1,
                                                         bf16_t* __restrict__ T2,
                                                         bf16_t* __restrict__ T3) {
    __shared__ float t[32][33];
    const int K = 1024, N = 1024;
    const float* W = blockIdx.z == 0 ? W0 : blockIdx.z == 1 ? W1 : blockIdx.z == 2 ? W2 : W3;
    bf16_t* WT = blockIdx.z == 0 ? T0 : blockIdx.z == 1 ? T1 : blockIdx.z == 2 ? T2 : T3;
    int tid = threadIdx.x;
    int rr = tid >> 3, cc = (tid & 7) * 4;
    int k0 = blockIdx.x * 32, n0 = blockIdx.y * 32;
    float4 v = *(const float4*)(W + (size_t)(k0 + rr) * N + n0 + cc);
    t[rr][cc + 0] = v.x; t[rr][cc + 1] = v.y; t[rr][cc + 2] = v.z; t[rr][cc + 3] = v.w;
    __syncthreads();
    bf16x4 o;
    o[0] = (bf16_t)t[cc + 0][rr]; o[1] = (bf16_t)t[cc + 1][rr];
    o[2] = (bf16_t)t[cc + 2][rr]; o[3] = (bf16_t)t[cc + 3][rr];
    *(bf16x4*)(WT + (size_t)(n0 + rr) * K + k0 + cc) = o;
}

__global__ __launch_bounds__(256) void transpose_cast_w(const float* __restrict__ W,
                                                        bf16_t* __restrict__ WT,
                                                        int K, int N) {
    __shared__ float t[32][33];
    int tid = threadIdx.x;
    int rr = tid >> 3, cc = (tid & 7) * 4;
    int k0 = blockIdx.x * 32, n0 = blockIdx.y * 32;
    float4 v = *(const float4*)(W + (size_t)(k0 + rr) * N + n0 + cc);
    t[rr][cc + 0] = v.x; t[rr][cc + 1] = v.y; t[rr][cc + 2] = v.z; t[rr][cc + 3] = v.w;
    __syncthreads();
    bf16x4 o;
    o[0] = (bf16_t)t[cc + 0][rr]; o[1] = (bf16_t)t[cc + 1][rr];
    o[2] = (bf16_t)t[cc + 2][rr]; o[3] = (bf16_t)t[cc + 3][rr];
    *(bf16x4*)(WT + (size_t)(n0 + rr) * K + k0 + cc) = o;
}

// ---------------------------------------------------------------------------
__global__ __launch_bounds__(256) void transpose_v(const bf16_t* __restrict__ Vp,
                                                   bf16_t* __restrict__ VT) {
    __shared__ bf16_t t[32][34];
    int tid = threadIdx.x;
    int rr = tid >> 3, cc = (tid & 7) * 4;
    int bh = blockIdx.z;
    int b = bh >> 4, h = bh & 15;
    int s0 = blockIdx.x * 32, d0 = blockIdx.y * 32;
    bf16x4 v = *(const bf16x4*)(Vp + ((size_t)(b * S_SZ + s0 + rr)) * D_MODEL + h * HEAD_DIM + d0 + cc);
    t[rr][cc + 0] = v[0]; t[rr][cc + 1] = v[1]; t[rr][cc + 2] = v[2]; t[rr][cc + 3] = v[3];
    __syncthreads();
    bf16x4 o;
    o[0] = t[cc + 0][rr]; o[1] = t[cc + 1][rr]; o[2] = t[cc + 2][rr]; o[3] = t[cc + 3][rr];
    *(bf16x4*)(VT + ((size_t)(bh * HEAD_DIM + d0 + rr)) * S_SZ + s0 + cc) = o;
}

// ---------------------------------------------------------------------------
// GEMM core 256: BM=256 tile, BK=32, 8 waves (512 thr) = 2M x 4N.
// BNF = B-frags per wave (4 -> BN=256, 2 -> BN=128). Per-wave out 128x(16*BNF).
// Counted-vmcnt 3-buffer ring (R11-validated): stage(s+2) while compute(s),
// vmcnt(2L/L/0) where L = loads/stage (4 for BNF4, 3 for BNF2), raw s_barrier,
// sched_barrier fences (rule #18). 2-4x MFMA per barrier & per staged byte vs
// the 128^2 core (R12 diagnosis: too little compute per K-step to cover
// latency at low occupancy).
// ---------------------------------------------------------------------------
template<int BNF, bool RELU, bool OUT_BF16, bool OUT_F32>
__device__ __forceinline__ void gemm_core256(const bf16_t* __restrict__ A, int lda,
                                             const bf16_t* __restrict__ Bt, int ldb,
                                             const float* __restrict__ bias, bool useBias,
                                             float* __restrict__ Cf,
                                             bf16_t* __restrict__ Cb,
                                             int N, int Klen, int m0, int n0,
                                             bf16_t* sA, bf16_t* sB) {
    const int tid = threadIdx.x;            // 0..511
    const int lane = tid & 63, w = tid >> 6;
    const int g = lane >> 4, r = lane & 15;
    const int wm = (w >> 2) * 128;
    const int wn = (w & 3) * (16 * BNF);
    const int ABUF = 8192;                   // elements per A buffer (256x32)
    const int BBUF = (BNF == 4) ? 8192 : 4096;

    const bf16_t* Ablk = A + (size_t)m0 * lda;
    const bf16_t* Bblk = Bt + (size_t)n0 * ldb;
    const bf16_t* a0 = Ablk + (size_t)(tid >> 2) * lda + (tid & 3) * 8;
    const bf16_t* a1 = a0 + (size_t)128 * lda;
    const bf16_t* b0 = Bblk + (size_t)(tid >> 2) * ldb + (tid & 3) * 8;
    const bf16_t* b1 = b0 + (size_t)128 * ldb;   // used only when BNF==4

    f32x4 acc[8][BNF];
#pragma unroll
    for (int i = 0; i < 8; i++)
#pragma unroll
        for (int j = 0; j < BNF; j++)
#pragma unroll
            for (int e = 0; e < 4; e++) acc[i][j][e] = 0.f;

    auto stage = [&](int buf, int k0) {
        gload_lds16(a0 + k0, sA + buf * ABUF + tid * 8);
        gload_lds16(a1 + k0, sA + buf * ABUF + 4096 + tid * 8);
        gload_lds16(b0 + k0, sB + buf * BBUF + tid * 8);
        if (BNF == 4) gload_lds16(b1 + k0, sB + buf * BBUF + 4096 + tid * 8);
    };
    auto compute = [&](int buf) {
        bf16x8 a[8], b[BNF];
#pragma unroll
        for (int i = 0; i < 8; i++)
            a[i] = *(const bf16x8*)(sA + buf * ABUF + (wm + i * 16 + r) * 32 + g * 8);
#pragma unroll
        for (int j = 0; j < BNF; j++)
            b[j] = *(const bf16x8*)(sB + buf * BBUF + (wn + j * 16 + r) * 32 + g * 8);
#pragma unroll
        for (int i = 0; i < 8; i++)
#pragma unroll
            for (int j = 0; j < BNF; j++)
                acc[i][j] = mfma16(a[i], b[j], acc[i][j]);
    };

    const int nk = Klen >> 5;   // >= 16 at all call sites
    stage(0, 0);
    stage(1, 32);
    int bc = 0, bs = 2;
    for (int s = 0; s < nk; ++s) {
        if (s + 2 < nk) {
            stage(bs, (s + 2) * 32);
            if (BNF == 4) asm volatile("s_waitcnt vmcnt(8)" ::: "memory");
            else          asm volatile("s_waitcnt vmcnt(6)" ::: "memory");
        } else if (s + 1 < nk) {
            if (BNF == 4) asm volatile("s_waitcnt vmcnt(4)" ::: "memory");
            else          asm volatile("s_waitcnt vmcnt(3)" ::: "memory");
        } else {
            asm volatile("s_waitcnt vmcnt(0)" ::: "memory");
        }
        __builtin_amdgcn_s_barrier();
        __builtin_amdgcn_sched_barrier(0);
        compute(bc);
        __builtin_amdgcn_sched_barrier(0);
        __builtin_amdgcn_s_barrier();
        bc = (bc + 1 == 3) ? 0 : bc + 1;
        bs = (bs + 1 == 3) ? 0 : bs + 1;
    }

#pragma unroll
    for (int j = 0; j < BNF; j++) {
        int n = n0 + wn + j * 16 + r;
        float bv = useBias ? bias[n] : 0.f;
#pragma unroll
        for (int i = 0; i < 8; i++) {
#pragma unroll
            for (int rr = 0; rr < 4; rr++) {
                int mrow = m0 + wm + i * 16 + g * 4 + rr;
                float val = acc[i][j][rr] + bv;
                if (RELU) val = fmaxf(val, 0.f);
                if (OUT_F32) Cf[(size_t)mrow * N + n] = val;
                if (OUT_BF16) Cb[(size_t)mrow * N + n] = (bf16_t)val;
            }
        }
    }
}

// split-K wrapper (z = K-chunk); XCD-swizzled grid
template<int BNF, bool RELU, bool OUT_BF16, bool OUT_F32>
__global__ __launch_bounds__(512, 2) void gemm_bt256(const bf16_t* __restrict__ A, int lda,
                                                     const bf16_t* __restrict__ Bt, int ldb,
                                                     const float* __restrict__ bias,
                                                     float* __restrict__ Cf0,
                                                     float* __restrict__ Cf1,
                                                     bf16_t* __restrict__ Cb,
                                                     int N, int Klen) {
    __shared__ bf16_t sA[3 * 8192];
    __shared__ bf16_t sB[3 * ((BNF == 4) ? 8192 : 4096)];
    const int lin = blockIdx.x + gridDim.x * (blockIdx.y + gridDim.y * blockIdx.z);
    const int nwg = gridDim.x * gridDim.y * gridDim.z;
    const int swz = xcd_swz(lin, nwg);
    const int bx = swz % gridDim.x;
    const int rest = swz / gridDim.x;
    const int by = rest % gridDim.y;
    const int bz = rest / gridDim.y;
    const int koff = bz * Klen;
    gemm_core256<BNF, RELU, OUT_BF16, OUT_F32>(A + koff, lda, Bt + koff, ldb, bias, bz == 0,
                                               bz ? Cf1 : Cf0, Cb, N, Klen,
                                               bx * 256, by * (64 * BNF), sA, sB);
}

// grouped QKV: z selects (A, W, bias, C); BNF=4 (N=1024 -> by 0..3)
__global__ __launch_bounds__(512, 2) void gemm_qkv256(const bf16_t* __restrict__ A0,
                                                      const bf16_t* __restrict__ A1,
                                                      const bf16_t* __restrict__ A2,
                                                      const bf16_t* __restrict__ B0,
                                                      const bf16_t* __restrict__ B1,
                                                      const bf16_t* __restrict__ B2,
                                                      const float* __restrict__ b0,
                                                      const float* __restrict__ b1,
                                                      const float* __restrict__ b2,
                                                      bf16_t* __restrict__ C0,
                                                      bf16_t* __restrict__ C1,
                                                      bf16_t* __restrict__ C2) {
    __shared__ bf16_t sA[3 * 8192];
    __shared__ bf16_t sB[3 * 8192];
    const int lin = blockIdx.x + gridDim.x * (blockIdx.y + gridDim.y * blockIdx.z);
    const int nwg = gridDim.x * gridDim.y * gridDim.z;
    const int swz = xcd_swz(lin, nwg);
    const int bx = swz % gridDim.x;
    const int rest = swz / gridDim.x;
    const int by = rest % gridDim.y;
    const int bz = rest / gridDim.y;
    const bf16_t* A = bz == 0 ? A0 : bz == 1 ? A1 : A2;
    const bf16_t* Bt = bz == 0 ? B0 : bz == 1 ? B1 : B2;
    const float* bias = bz == 0 ? b0 : bz == 1 ? b1 : b2;
    bf16_t* C = bz == 0 ? C0 : bz == 1 ? C1 : C2;
    gemm_core256<4, false, true, false>(A, 1024, Bt, 1024, bias, true,
                                        nullptr, C, 1024, 1024, bx * 256, by * 256, sA, sB);
}

// ---------------------------------------------------------------------------
// Flash attention v5 (unchanged from R12)
// ---------------------------------------------------------------------------
__device__ __forceinline__ void flash_tile(
    const char* kt, const char* vt, int l31, int hi,
    const bf16x8 (&bq)[4],
    f32x16& o0, f32x16& o1, float& mC, float& l_run)
{
    bf16x8 ak[4];
#pragma unroll
    for (int kb = 0; kb < 4; kb++)
        ak[kb] = *(const bf16x8*)(kt + l31 * 128 + (((kb << 1) | hi) ^ (l31 & 7)) * 16);
    bf16x8 av[4];
#pragma unroll
    for (int db = 0; db < 2; db++)
#pragma unroll
        for (int kb = 0; kb < 2; kb++)
            av[db * 2 + kb] = *(const bf16x8*)(vt + (db * 32 + l31) * 64 + ((((kb << 1) | hi)) ^ ((l31 >> 1) & 3)) * 16);

    f32x16 s;
#pragma unroll
    for (int e = 0; e < 16; e++) s[e] = 0.f;
#pragma unroll
    for (int kb = 0; kb < 4; kb++) s = mfma32(ak[kb], bq[kb], s);

    float ma = fmaxf(fmaxf(s[0], s[1]), fmaxf(s[2], s[3]));
    float mb = fmaxf(fmaxf(s[4], s[5]), fmaxf(s[6], s[7]));
    float mc = fmaxf(fmaxf(s[8], s[9]), fmaxf(s[10], s[11]));
    float md = fmaxf(fmaxf(s[12], s[13]), fmaxf(s[14], s[15]));
    float pmaxC = fmaxf(fmaxf(ma, mb), fmaxf(mc, md)) * CF;

    if (!__all(pmaxC <= mC + THRC)) {
        int2v pr = plswap(__float_as_int(pmaxC), __float_as_int(pmaxC));
        float rowmaxC = fmaxf(__int_as_float(pr[0]), __int_as_float(pr[1]));
        float mnewC = fmaxf(mC, rowmaxC);
        float alpha = fexp2(mC - mnewC);
        mC = mnewC;
        l_run *= alpha;
#pragma unroll
        for (int e = 0; e < 16; e++) { o0[e] *= alpha; o1[e] *= alpha; }
    }

#pragma unroll
    for (int e = 0; e < 16; e++) s[e] = fexp2(__builtin_fmaf(s[e], CF, -mC));
    float t0 = (s[0] + s[1]) + (s[2] + s[3]);
    float t1 = (s[4] + s[5]) + (s[6] + s[7]);
    float t2 = (s[8] + s[9]) + (s[10] + s[11]);
    float t3 = (s[12] + s[13]) + (s[14] + s[15]);
    l_run += (t0 + t1) + (t2 + t3);

#pragma unroll
    for (int kb2 = 0; kb2 < 2; kb2++) {
        const int bse = kb2 * 8;
        int W0 = packbf(s[bse + 0], s[bse + 1]);
        int W1 = packbf(s[bse + 2], s[bse + 3]);
        int W2 = packbf(s[bse + 4], s[bse + 5]);
        int W3 = packbf(s[bse + 6], s[bse + 7]);
        int2v r02 = plswap(W0, W2);
        int2v r13 = plswap(W1, W3);
        int4v fw; fw[0] = r02[0]; fw[1] = r13[0]; fw[2] = r02[1]; fw[3] = r13[1];
        bf16x8 pf = __builtin_bit_cast(bf16x8, fw);
        o0 = mfma32(av[kb2], pf, o0);
        o1 = mfma32(av[2 + kb2], pf, o1);
    }
}

__global__ __launch_bounds__(256) void flash_attn(const bf16_t* __restrict__ Qp,
                                                  const bf16_t* __restrict__ Kp,
                                                  const bf16_t* __restrict__ VT,
                                                  bf16_t* __restrict__ Oa) {
    __shared__ alignas(16) char lds[2][2][8192];
    const int tid = threadIdx.x;
    const int lane = tid & 63;
    const int wave = tid >> 6;
    const int half = wave >> 1;
    const int qt = wave & 1;
    const int l31 = lane & 31, hi = lane >> 5;

    const int lin = blockIdx.x + (blockIdx.y << 5) + (blockIdx.z << 9);
    const int swz = (lin & 7) * 128 + (lin >> 3);
    const int qb = swz & 31;
    const int h = (swz >> 5) & 15;
    const int b = swz >> 9;

    const int q0 = qb * 64 + qt * 32;

    const bf16_t* Qb = Qp + (size_t)b * S_SZ * D_MODEL + h * HEAD_DIM;
    const bf16_t* Kb = Kp + (size_t)b * S_SZ * D_MODEL + h * HEAD_DIM;
    const bf16_t* Vb = VT + ((size_t)(b * NUM_HEADS + h) * HEAD_DIM) * S_SZ;

    const int sh = wave & 1;
    const int skvbase = sh * (S_SZ / 2);
    const bool kRole = wave < 2;

    const bf16_t* src_run;
    size_t inner_stride;
    size_t tile_stride;
    char* dst0;
    char* dst1;
    if (kRole) {
        src_run = Kb + (size_t)(skvbase + (lane >> 3)) * D_MODEL + ((lane & 7) ^ (lane >> 3)) * 8;
        inner_stride = (size_t)8 * D_MODEL;
        tile_stride = (size_t)32 * D_MODEL;
        dst0 = &lds[0][sh][0] + lane * 16;
        dst1 = &lds[1][sh][0] + lane * 16;
    } else {
        src_run = Vb + (size_t)(lane >> 2) * S_SZ + skvbase + ((lane & 3) ^ ((lane >> 3) & 3)) * 8;
        inner_stride = (size_t)16 * S_SZ;
        tile_stride = 32;
        dst0 = &lds[0][sh][4096] + lane * 16;
        dst1 = &lds[1][sh][4096] + lane * 16;
    }

    bf16x8 bq[4];
#pragma unroll
    for (int kb = 0; kb < 4; kb++)
        bq[kb] = *(const bf16x8*)(Qb + (size_t)(q0 + l31) * D_MODEL + kb * 16 + hi * 8);

    f32x16 o0, o1;
#pragma unroll
    for (int e = 0; e < 16; e++) { o0[e] = 0.f; o1[e] = 0.f; }
    float mC = -1e30f, l_run = 0.f;

    const char* kt0 = &lds[0][half][0];
    const char* vt0 = &lds[0][half][4096];
    const char* kt1 = &lds[1][half][0];
    const char* vt1 = &lds[1][half][4096];

#pragma unroll
    for (int ii = 0; ii < 4; ii++)
        gload_lds16(src_run + ii * inner_stride, dst0 + ii * 1024);
    src_run += tile_stride;
    __syncthreads();

    for (int t = 0; t < 32; t += 2) {
#pragma unroll
        for (int ii = 0; ii < 4; ii++)
            gload_lds16(src_run + ii * inner_stride, dst1 + ii * 1024);
        src_run += tile_stride;
        flash_tile(kt0, vt0, l31, hi, bq, o0, o1, mC, l_run);
        __syncthreads();

        if (t + 2 < 32) {
#pragma unroll
            for (int ii = 0; ii < 4; ii++)
                gload_lds16(src_run + ii * inner_stride, dst0 + ii * 1024);
            src_run += tile_stride;
        }
        flash_tile(kt1, vt1, l31, hi, bq, o0, o1, mC, l_run);
        __syncthreads();
    }

    int2v lp = plswap(__float_as_int(l_run), __float_as_int(l_run));
    l_run = __int_as_float(lp[0]) + __int_as_float(lp[1]);

    float (*obuf)[2][64] = (float (*)[2][64])(&lds[0][0][0]);
    float (*mrg)[64][2] = (float (*)[64][2])(&lds[0][0][0] + 16384);
    if (half == 1) {
        mrg[qt][lane][0] = mC;
        mrg[qt][lane][1] = l_run;
#pragma unroll
        for (int e = 0; e < 16; e++) {
            obuf[e][qt][lane] = o0[e];
            obuf[16 + e][qt][lane] = o1[e];
        }
    }
    __syncthreads();
    if (half == 0) {
        const float m2C = mrg[qt][lane][0], l2 = mrg[qt][lane][1];
        const float mm = fmaxf(mC, m2C);
        const float e1 = fexp2(mC - mm);
        const float e2 = fexp2(m2C - mm);
        const float linv = 1.f / (l_run * e1 + l2 * e2);
        bf16_t* Orow = Oa + ((size_t)b * S_SZ + q0 + l31) * D_MODEL + h * HEAD_DIM;
#pragma unroll
        for (int db = 0; db < 2; db++) {
#pragma unroll
            for (int rq = 0; rq < 4; rq++) {
                bf16x4 st;
#pragma unroll
                for (int i = 0; i < 4; i++) {
                    const int e = rq * 4 + i;
                    const float own = db ? o1[e] : o0[e];
                    const float oth = obuf[db * 16 + e][qt][lane];
                    st[i] = (bf16_t)((own * e1 + oth * e2) * linv);
                }
                *(bf16x4*)(Orow + db * 32 + rq * 8 + hi * 4) = st;
            }
        }
    }
}

// ---------------------------------------------------------------------------
// LayerNorm over 1024 with fused residual + optional second addend
// ---------------------------------------------------------------------------
__global__ __launch_bounds__(256) void ln_fused(const float* __restrict__ A,
                                                const float* __restrict__ A2,
                                                const float* __restrict__ R,
                                                const float* __restrict__ gamma,
                                                const float* __restrict__ beta,
                                                float* __restrict__ Xf,
                                                bf16_t* __restrict__ Xb) {
    __shared__ float red[8];
    int row = blockIdx.x, tid = threadIdx.x;
    size_t base = (size_t)row * D_MODEL + tid * 4;
    float4 a = *(const float4*)(A + base);
    float4 rv = *(const float4*)(R + base);
    float v0 = a.x + rv.x, v1 = a.y + rv.y, v2 = a.z + rv.z, v3 = a.w + rv.w;
    if (A2) {
        float4 a2 = *(const float4*)(A2 + base);
        v0 += a2.x; v1 += a2.y; v2 += a2.z; v3 += a2.w;
    }
    float s = v0 + v1 + v2 + v3;
    float q = v0 * v0 + v1 * v1 + v2 * v2 + v3 * v3;
#pragma unroll
    for (int off = 32; off; off >>= 1) { s += __shfl_down(s, off); q += __shfl_down(q, off); }
    if ((tid & 63) == 0) { red[tid >> 6] = s; red[4 + (tid >> 6)] = q; }
    __syncthreads();
    s = red[0] + red[1] + red[2] + red[3];
    q = red[4] + red[5] + red[6] + red[7];
    float mean = s * (1.f / D_MODEL);
    float var = q * (1.f / D_MODEL) - mean * mean;
    float rstd = rsqrtf(var + 1e-5f);
    float4 gm = *(const float4*)(gamma + tid * 4);
    float4 bt = *(const float4*)(beta + tid * 4);
    float y0 = (v0 - mean) * rstd * gm.x + bt.x;
    float y1 = (v1 - mean) * rstd * gm.y + bt.y;
    float y2 = (v2 - mean) * rstd * gm.z + bt.z;
    float y3 = (v3 - mean) * rstd * gm.w + bt.w;
    float4 yo; yo.x = y0; yo.y = y1; yo.z = y2; yo.w = y3;
    *(float4*)(Xf + base) = yo;
    if (Xb) {
        bf16x4 ob; ob[0] = (bf16_t)y0; ob[1] = (bf16_t)y1; ob[2] = (bf16_t)y2; ob[3] = (bf16_t)y3;
        *(bf16x4*)(Xb + base) = ob;
    }
}

// ---------------------------------------------------------------------------
extern "C" void kernel_launch(void* const* d_in, const int* in_sizes, int n_in,
                              void* d_out, int out_size, void* d_ws, size_t ws_size,
                              hipStream_t stream) {
    const float* value = (const float*)d_in[0];
    const float* key   = (const float*)d_in[1];
    const float* query = (const float*)d_in[2];
    const float* wq = (const float*)d_in[3];
    const float* bq = (const float*)d_in[4];
    const float* wk = (const float*)d_in[5];
    const float* bk = (const float*)d_in[6];
    const float* wv = (const float*)d_in[7];
    const float* bv = (const float*)d_in[8];
    const float* wo = (const float*)d_in[9];
    const float* bo = (const float*)d_in[10];
    const float* g1 = (const float*)d_in[11];
    const float* beta1 = (const float*)d_in[12];
    const float* w1 = (const float*)d_in[13];
    const float* b1 = (const float*)d_in[14];
    const float* w2 = (const float*)d_in[15];
    const float* b2 = (const float*)d_in[16];
    const float* g2 = (const float*)d_in[17];
    const float* beta2 = (const float*)d_in[18];
    (void)in_sizes; (void)n_in; (void)out_size; (void)ws_size;

    const size_t MB = 1ull << 20;
    char* ws = (char*)d_ws;
    bf16_t* wqT = (bf16_t*)(ws + 0 * MB);
    bf16_t* wkT = (bf16_t*)(ws + 2 * MB);
    bf16_t* wvT = (bf16_t*)(ws + 4 * MB);
    bf16_t* woT = (bf16_t*)(ws + 6 * MB);
    bf16_t* w1T = (bf16_t*)(ws + 8 * MB);
    bf16_t* w2T = (bf16_t*)(ws + 16 * MB);
    bf16_t* q_bf = (bf16_t*)(ws + 24 * MB);
    bf16_t* k_bf = (bf16_t*)(ws + 32 * MB);
    bf16_t* v_bf = (bf16_t*)(ws + 40 * MB);
    bf16_t* Qp  = (bf16_t*)(ws + 48 * MB);
    bf16_t* Kp  = (bf16_t*)(ws + 56 * MB);
    bf16_t* Vp  = (bf16_t*)(ws + 64 * MB);
    bf16_t* VT  = (bf16_t*)(ws + 72 * MB);
    bf16_t* attn = (bf16_t*)(ws + 24 * MB);   // reuse q_bf (dead after QKV gemm)
    float*  woP0 = (float*)(ws + 32 * MB);    // reuse k_bf..Qp (dead after flash)
    float*  woP1 = (float*)(ws + 48 * MB);
    float*  x_f = (float*)(ws + 64 * MB);     // reuse Vp/VT (dead after flash)
    bf16_t* x_b = (bf16_t*)(ws + 24 * MB);    // reuse attn (dead after WO gemm)
    bf16_t* h_b = (bf16_t*)(ws + 32 * MB);    // reuse woP (dead after LN1), 32MB
    float*  ffP0 = (float*)(ws + 80 * MB);
    float*  ffP1 = (float*)(ws + 96 * MB);

    dim3 blk(256);
    dim3 blk512(512);

    // 1) casts + weight transposes
    cast3_f32_bf16<<<12288, blk, 0, stream>>>(query, key, value, q_bf, k_bf, v_bf);
    transpose_cast_w4<<<dim3(32, 32, 4), blk, 0, stream>>>(wq, wk, wv, wo, wqT, wkT, wvT, woT);
    transpose_cast_w<<<dim3(32, 128), blk, 0, stream>>>(w1, w1T, 1024, 4096);
    transpose_cast_w<<<dim3(128, 32), blk, 0, stream>>>(w2, w2T, 4096, 1024);

    // 2) grouped QKV projection (256-tile, 192 blocks)
    gemm_qkv256<<<dim3(16, 4, 3), blk512, 0, stream>>>(q_bf, k_bf, v_bf, wqT, wkT, wvT,
                                                       bq, bk, bv, Qp, Kp, Vp);

    // 3) V transpose for PV A-operand
    transpose_v<<<dim3(64, 2, 32), blk, 0, stream>>>(Vp, VT);

    // 4) flash attention v5
    flash_attn<<<dim3(32, 16, 2), blk, 0, stream>>>(Qp, Kp, VT, attn);

    // 5) WO projection (256x128 tile, split-K=2, 256 blocks)
    gemm_bt256<2, false, false, true><<<dim3(16, 8, 2), blk512, 0, stream>>>(attn, 1024, woT, 1024, bo, woP0, woP1, nullptr, D_MODEL, 512);

    // 6) LN1: x = LN(woP0 + woP1 + query)
    ln_fused<<<4096, blk, 0, stream>>>(woP0, woP1, query, g1, beta1, x_f, x_b);

    // 7) FF1 + ReLU (256x256 tile, 256 blocks)
    gemm_bt256<4, true, true, false><<<dim3(16, 16, 1), blk512, 0, stream>>>(x_b, 1024, w1T, 1024, b1, nullptr, nullptr, h_b, FF_DIM, 1024);

    // 8) FF2 (256x128 tile, split-K=2, 256 blocks)
    gemm_bt256<2, false, false, true><<<dim3(16, 8, 2), blk512, 0, stream>>>(h_b, 4096, w2T, 4096, b2, ffP0, ffP1, nullptr, D_MODEL, 2048);

    // 9) LN2 -> d_out
    ln_fused<<<4096, blk, 0, stream>>>(ffP0, ffP1, x_f, g2, beta2, (float*)d_out, nullptr);
}

// Round 14
// 253.791 us; speedup vs baseline: 2.8172x; 1.0232x over previous
//
#include <hip/hip_runtime.h>
#include <hip/hip_bf16.h>
#include <cstdint>
#include <math.h>

typedef __bf16 bf16_t;
typedef __attribute__((ext_vector_type(2))) __bf16 bf16x2;
typedef __attribute__((ext_vector_type(4))) __bf16 bf16x4;
typedef __attribute__((ext_vector_type(8))) __bf16 bf16x8;
typedef __attribute__((ext_vector_type(4))) float f32x4;
typedef __attribute__((ext_vector_type(16))) float f32x16;
typedef __attribute__((ext_vector_type(2))) int int2v;
typedef __attribute__((ext_vector_type(4))) int int4v;

#define B_SZ 2
#define S_SZ 2048
#define D_MODEL 1024
#define NUM_HEADS 16
#define HEAD_DIM 64
#define FF_DIM 4096
#define M_ROWS (B_SZ * S_SZ)   // 4096

// exp2-domain scale: 0.125 (1/sqrt(64)) * log2(e)
#define CF 0.180336880f
#define THRC 2.0f

__device__ __forceinline__ float fexp2(float x) { return __builtin_amdgcn_exp2f(x); }

// ---------------------------------------------------------------------------
__device__ __forceinline__ void gload_lds16(const void* g, void* lds) {
    __builtin_amdgcn_global_load_lds(
        (const __attribute__((address_space(1))) void*)(uintptr_t)g,
        (__attribute__((address_space(3))) void*)(uint32_t)(uintptr_t)lds,
        16, 0, 0);
}

__device__ __forceinline__ f32x4 mfma16(bf16x8 a, bf16x8 b, f32x4 c) {
    return __builtin_amdgcn_mfma_f32_16x16x32_bf16(a, b, c, 0, 0, 0);
}
__device__ __forceinline__ f32x16 mfma32(bf16x8 a, bf16x8 b, f32x16 c) {
    return __builtin_amdgcn_mfma_f32_32x32x16_bf16(a, b, c, 0, 0, 0);
}
__device__ __forceinline__ int2v plswap(int a, int b) {
    return __builtin_amdgcn_permlane32_swap(a, b, false, false);
}
__device__ __forceinline__ int packbf(float a, float b) {
    bf16x2 t; t[0] = (bf16_t)a; t[1] = (bf16_t)b;
    return __builtin_bit_cast(int, t);
}

__device__ __forceinline__ int xcd_swz(int lin, int nwg) {
    return (lin & 7) * (nwg >> 3) + (lin >> 3);
}

// ---------------------------------------------------------------------------
__global__ __launch_bounds__(256) void cast3_f32_bf16(const float* __restrict__ in0,
                                                      const float* __restrict__ in1,
                                                      const float* __restrict__ in2,
                                                      bf16_t* __restrict__ out0,
                                                      bf16_t* __restrict__ out1,
                                                      bf16_t* __restrict__ out2) {
    int which = blockIdx.x >> 12;
    int blk = blockIdx.x & 4095;
    const float* in = which == 0 ? in0 : which == 1 ? in1 : in2;
    bf16_t* out = which == 0 ? out0 : which == 1 ? out1 : out2;
    size_t i = ((size_t)blk * 256 + threadIdx.x) * 4;
    float4 v = *(const float4*)(in + i);
    bf16x4 o;
    o[0] = (bf16_t)v.x; o[1] = (bf16_t)v.y; o[2] = (bf16_t)v.z; o[3] = (bf16_t)v.w;
    *(bf16x4*)(out + i) = o;
}

// ---------------------------------------------------------------------------
__global__ __launch_bounds__(256) void transpose_cast_w4(const float* __restrict__ W0,
                                                         const float* __restrict__ W1,
                                                         const float* __restrict__ W2,
                                                         const float* __restrict__ W3,
                                                         bf16_t* __restrict__ T0,
                                                         bf16_t* __restrict__ T1,
                                                         bf16_t* __restrict__ T2,
                                                         bf16_t* __restrict__ T3) {
    __shared__ float t[32][33];
    const int K = 1024, N = 1024;
    const float* W = blockIdx.z == 0 ? W0 : blockIdx.z == 1 ? W1 : blockIdx.z == 2 ? W2 : W3;
    bf16_t* WT = blockIdx.z == 0 ? T0 : blockIdx.z == 1 ? T1 : blockIdx.z == 2 ? T2 : T3;
    int tid = threadIdx.x;
    int rr = tid >> 3, cc = (tid & 7) * 4;
    int k0 = blockIdx.x * 32, n0 = blockIdx.y * 32;
    float4 v = *(const float4*)(W + (size_t)(k0 + rr) * N + n0 + cc);
    t[rr][cc + 0] = v.x; t[rr][cc + 1] = v.y; t[rr][cc + 2] = v.z; t[rr][cc + 3] = v.w;
    __syncthreads();
    bf16x4 o;
    o[0] = (bf16_t)t[cc + 0][rr]; o[1] = (bf16_t)t[cc + 1][rr];
    o[2] = (bf16_t)t[cc + 2][rr]; o[3] = (bf16_t)t[cc + 3][rr];
    *(bf16x4*)(WT + (size_t)(n0 + rr) * K + k0 + cc) = o;
}

__global__ __launch_bounds__(256) void transpose_cast_w(const float* __restrict__ W,
                                                        bf16_t* __restrict__ WT,
                                                        int K, int N) {
    __shared__ float t[32][33];
    int tid = threadIdx.x;
    int rr = tid >> 3, cc = (tid & 7) * 4;
    int k0 = blockIdx.x * 32, n0 = blockIdx.y * 32;
    float4 v = *(const float4*)(W + (size_t)(k0 + rr) * N + n0 + cc);
    t[rr][cc + 0] = v.x; t[rr][cc + 1] = v.y; t[rr][cc + 2] = v.z; t[rr][cc + 3] = v.w;
    __syncthreads();
    bf16x4 o;
    o[0] = (bf16_t)t[cc + 0][rr]; o[1] = (bf16_t)t[cc + 1][rr];
    o[2] = (bf16_t)t[cc + 2][rr]; o[3] = (bf16_t)t[cc + 3][rr];
    *(bf16x4*)(WT + (size_t)(n0 + rr) * K + k0 + cc) = o;
}

// ---------------------------------------------------------------------------
__global__ __launch_bounds__(256) void transpose_v(const bf16_t* __restrict__ Vp,
                                                   bf16_t* __restrict__ VT) {
    __shared__ bf16_t t[32][34];
    int tid = threadIdx.x;
    int rr = tid >> 3, cc = (tid & 7) * 4;
    int bh = blockIdx.z;
    int b = bh >> 4, h = bh & 15;
    int s0 = blockIdx.x * 32, d0 = blockIdx.y * 32;
    bf16x4 v = *(const bf16x4*)(Vp + ((size_t)(b * S_SZ + s0 + rr)) * D_MODEL + h * HEAD_DIM + d0 + cc);
    t[rr][cc + 0] = v[0]; t[rr][cc + 1] = v[1]; t[rr][cc + 2] = v[2]; t[rr][cc + 3] = v[3];
    __syncthreads();
    bf16x4 o;
    o[0] = t[cc + 0][rr]; o[1] = t[cc + 1][rr]; o[2] = t[cc + 2][rr]; o[3] = t[cc + 3][rr];
    *(bf16x4*)(VT + ((size_t)(bh * HEAD_DIM + d0 + rr)) * S_SZ + s0 + cc) = o;
}

// ---------------------------------------------------------------------------
// GEMM core 256 v2: BM=256, BK=32, 8 waves, counted-vmcnt 3-buffer ring
// + XOR-SWIZZLED A/B tiles (T2). Rows are 64B = 16 banks, so the old linear
// layout 8-way-conflicted every ds_read_b128 (R13 diagnosis: ~2800 of the
// ~2500 cyc/K-step). Slot c of row p holds global chunk c^((p>>1)&3)
// (pre-swizzled SOURCE, linear gload_lds dest - m173 pattern); reader uses
// slot g^((r>>1)&3). Rows 0..7 cover all 32 banks -> residual 2-way (free).
// ---------------------------------------------------------------------------
template<int BNF, bool RELU, bool OUT_BF16, bool OUT_F32>
__device__ __forceinline__ void gemm_core256(const bf16_t* __restrict__ A, int lda,
                                             const bf16_t* __restrict__ Bt, int ldb,
                                             const float* __restrict__ bias, bool useBias,
                                             float* __restrict__ Cf,
                                             bf16_t* __restrict__ Cb,
                                             int N, int Klen, int m0, int n0,
                                             bf16_t* sA, bf16_t* sB) {
    const int tid = threadIdx.x;            // 0..511
    const int lane = tid & 63, w = tid >> 6;
    const int g = lane >> 4, r = lane & 15;
    const int wm = (w >> 2) * 128;
    const int wn = (w & 3) * (16 * BNF);
    const int ABUF = 8192;
    const int BBUF = (BNF == 4) ? 8192 : 4096;
    const int swz = (g ^ ((r >> 1) & 3)) * 8;   // reader chunk slot (elements)

    const bf16_t* Ablk = A + (size_t)m0 * lda;
    const bf16_t* Bblk = Bt + (size_t)n0 * ldb;
    // pre-swizzled global source: dest slot (tid&3) of row (tid>>2) must hold
    // global chunk (tid&3)^((tid>>3)&3)   [(row>>1)&3 == (tid>>3)&3]
    const int scol = ((tid & 3) ^ ((tid >> 3) & 3)) * 8;
    const bf16_t* a0 = Ablk + (size_t)(tid >> 2) * lda + scol;
    const bf16_t* a1 = a0 + (size_t)128 * lda;   // row+128: same swizzle term
    const bf16_t* b0 = Bblk + (size_t)(tid >> 2) * ldb + scol;
    const bf16_t* b1 = b0 + (size_t)128 * ldb;

    f32x4 acc[8][BNF];
#pragma unroll
    for (int i = 0; i < 8; i++)
#pragma unroll
        for (int j = 0; j < BNF; j++)
#pragma unroll
            for (int e = 0; e < 4; e++) acc[i][j][e] = 0.f;

    auto stage = [&](int buf, int k0) {
        gload_lds16(a0 + k0, sA + buf * ABUF + tid * 8);
        gload_lds16(a1 + k0, sA + buf * ABUF + 4096 + tid * 8);
        gload_lds16(b0 + k0, sB + buf * BBUF + tid * 8);
        if (BNF == 4) gload_lds16(b1 + k0, sB + buf * BBUF + 4096 + tid * 8);
    };
    auto compute = [&](int buf) {
        bf16x8 a[8], b[BNF];
#pragma unroll
        for (int i = 0; i < 8; i++)
            a[i] = *(const bf16x8*)(sA + buf * ABUF + (wm + i * 16 + r) * 32 + swz);
#pragma unroll
        for (int j = 0; j < BNF; j++)
            b[j] = *(const bf16x8*)(sB + buf * BBUF + (wn + j * 16 + r) * 32 + swz);
#pragma unroll
        for (int i = 0; i < 8; i++)
#pragma unroll
            for (int j = 0; j < BNF; j++)
                acc[i][j] = mfma16(a[i], b[j], acc[i][j]);
    };

    const int nk = Klen >> 5;
    stage(0, 0);
    stage(1, 32);
    int bc = 0, bs = 2;
    for (int s = 0; s < nk; ++s) {
        if (s + 2 < nk) {
            stage(bs, (s + 2) * 32);
            if (BNF == 4) asm volatile("s_waitcnt vmcnt(8)" ::: "memory");
            else          asm volatile("s_waitcnt vmcnt(6)" ::: "memory");
        } else if (s + 1 < nk) {
            if (BNF == 4) asm volatile("s_waitcnt vmcnt(4)" ::: "memory");
            else          asm volatile("s_waitcnt vmcnt(3)" ::: "memory");
        } else {
            asm volatile("s_waitcnt vmcnt(0)" ::: "memory");
        }
        __builtin_amdgcn_s_barrier();
        __builtin_amdgcn_sched_barrier(0);
        compute(bc);
        __builtin_amdgcn_sched_barrier(0);
        __builtin_amdgcn_s_barrier();
        bc = (bc + 1 == 3) ? 0 : bc + 1;
        bs = (bs + 1 == 3) ? 0 : bs + 1;
    }

#pragma unroll
    for (int j = 0; j < BNF; j++) {
        int n = n0 + wn + j * 16 + r;
        float bv = useBias ? bias[n] : 0.f;
#pragma unroll
        for (int i = 0; i < 8; i++) {
#pragma unroll
            for (int rr = 0; rr < 4; rr++) {
                int mrow = m0 + wm + i * 16 + g * 4 + rr;
                float val = acc[i][j][rr] + bv;
                if (RELU) val = fmaxf(val, 0.f);
                if (OUT_F32) Cf[(size_t)mrow * N + n] = val;
                if (OUT_BF16) Cb[(size_t)mrow * N + n] = (bf16_t)val;
            }
        }
    }
}

// split-K wrapper (z = K-chunk); XCD-swizzled grid
template<int BNF, bool RELU, bool OUT_BF16, bool OUT_F32>
__global__ __launch_bounds__(512, 2) void gemm_bt256(const bf16_t* __restrict__ A, int lda,
                                                     const bf16_t* __restrict__ Bt, int ldb,
                                                     const float* __restrict__ bias,
                                                     float* __restrict__ Cf0,
                                                     float* __restrict__ Cf1,
                                                     bf16_t* __restrict__ Cb,
                                                     int N, int Klen) {
    __shared__ bf16_t sA[3 * 8192];
    __shared__ bf16_t sB[3 * ((BNF == 4) ? 8192 : 4096)];
    const int lin = blockIdx.x + gridDim.x * (blockIdx.y + gridDim.y * blockIdx.z);
    const int nwg = gridDim.x * gridDim.y * gridDim.z;
    const int swz = xcd_swz(lin, nwg);
    const int bx = swz % gridDim.x;
    const int rest = swz / gridDim.x;
    const int by = rest % gridDim.y;
    const int bz = rest / gridDim.y;
    const int koff = bz * Klen;
    gemm_core256<BNF, RELU, OUT_BF16, OUT_F32>(A + koff, lda, Bt + koff, ldb, bias, bz == 0,
                                               bz ? Cf1 : Cf0, Cb, N, Klen,
                                               bx * 256, by * (64 * BNF), sA, sB);
}

// grouped QKV: z selects (A, W, bias, C); BNF=4
__global__ __launch_bounds__(512, 2) void gemm_qkv256(const bf16_t* __restrict__ A0,
                                                      const bf16_t* __restrict__ A1,
                                                      const bf16_t* __restrict__ A2,
                                                      const bf16_t* __restrict__ B0,
                                                      const bf16_t* __restrict__ B1,
                                                      const bf16_t* __restrict__ B2,
                                                      const float* __restrict__ b0,
                                                      const float* __restrict__ b1,
                                                      const float* __restrict__ b2,
                                                      bf16_t* __restrict__ C0,
                                                      bf16_t* __restrict__ C1,
                                                      bf16_t* __restrict__ C2) {
    __shared__ bf16_t sA[3 * 8192];
    __shared__ bf16_t sB[3 * 8192];
    const int lin = blockIdx.x + gridDim.x * (blockIdx.y + gridDim.y * blockIdx.z);
    const int nwg = gridDim.x * gridDim.y * gridDim.z;
    const int swz = xcd_swz(lin, nwg);
    const int bx = swz % gridDim.x;
    const int rest = swz / gridDim.x;
    const int by = rest % gridDim.y;
    const int bz = rest / gridDim.y;
    const bf16_t* A = bz == 0 ? A0 : bz == 1 ? A1 : A2;
    const bf16_t* Bt = bz == 0 ? B0 : bz == 1 ? B1 : B2;
    const float* bias = bz == 0 ? b0 : bz == 1 ? b1 : b2;
    bf16_t* C = bz == 0 ? C0 : bz == 1 ? C1 : C2;
    gemm_core256<4, false, true, false>(A, 1024, Bt, 1024, bias, true,
                                        nullptr, C, 1024, 1024, bx * 256, by * 256, sA, sB);
}

// ---------------------------------------------------------------------------
// Flash attention v5 (unchanged)
// ---------------------------------------------------------------------------
__device__ __forceinline__ void flash_tile(
    const char* kt, const char* vt, int l31, int hi,
    const bf16x8 (&bq)[4],
    f32x16& o0, f32x16& o1, float& mC, float& l_run)
{
    bf16x8 ak[4];
#pragma unroll
    for (int kb = 0; kb < 4; kb++)
        ak[kb] = *(const bf16x8*)(kt + l31 * 128 + (((kb << 1) | hi) ^ (l31 & 7)) * 16);
    bf16x8 av[4];
#pragma unroll
    for (int db = 0; db < 2; db++)
#pragma unroll
        for (int kb = 0; kb < 2; kb++)
            av[db * 2 + kb] = *(const bf16x8*)(vt + (db * 32 + l31) * 64 + ((((kb << 1) | hi)) ^ ((l31 >> 1) & 3)) * 16);

    f32x16 s;
#pragma unroll
    for (int e = 0; e < 16; e++) s[e] = 0.f;
#pragma unroll
    for (int kb = 0; kb < 4; kb++) s = mfma32(ak[kb], bq[kb], s);

    float ma = fmaxf(fmaxf(s[0], s[1]), fmaxf(s[2], s[3]));
    float mb = fmaxf(fmaxf(s[4], s[5]), fmaxf(s[6], s[7]));
    float mc = fmaxf(fmaxf(s[8], s[9]), fmaxf(s[10], s[11]));
    float md = fmaxf(fmaxf(s[12], s[13]), fmaxf(s[14], s[15]));
    float pmaxC = fmaxf(fmaxf(ma, mb), fmaxf(mc, md)) * CF;

    if (!__all(pmaxC <= mC + THRC)) {
        int2v pr = plswap(__float_as_int(pmaxC), __float_as_int(pmaxC));
        float rowmaxC = fmaxf(__int_as_float(pr[0]), __int_as_float(pr[1]));
        float mnewC = fmaxf(mC, rowmaxC);
        float alpha = fexp2(mC - mnewC);
        mC = mnewC;
        l_run *= alpha;
#pragma unroll
        for (int e = 0; e < 16; e++) { o0[e] *= alpha; o1[e] *= alpha; }
    }

#pragma unroll
    for (int e = 0; e < 16; e++) s[e] = fexp2(__builtin_fmaf(s[e], CF, -mC));
    float t0 = (s[0] + s[1]) + (s[2] + s[3]);
    float t1 = (s[4] + s[5]) + (s[6] + s[7]);
    float t2 = (s[8] + s[9]) + (s[10] + s[11]);
    float t3 = (s[12] + s[13]) + (s[14] + s[15]);
    l_run += (t0 + t1) + (t2 + t3);

#pragma unroll
    for (int kb2 = 0; kb2 < 2; kb2++) {
        const int bse = kb2 * 8;
        int W0 = packbf(s[bse + 0], s[bse + 1]);
        int W1 = packbf(s[bse + 2], s[bse + 3]);
        int W2 = packbf(s[bse + 4], s[bse + 5]);
        int W3 = packbf(s[bse + 6], s[bse + 7]);
        int2v r02 = plswap(W0, W2);
        int2v r13 = plswap(W1, W3);
        int4v fw; fw[0] = r02[0]; fw[1] = r13[0]; fw[2] = r02[1]; fw[3] = r13[1];
        bf16x8 pf = __builtin_bit_cast(bf16x8, fw);
        o0 = mfma32(av[kb2], pf, o0);
        o1 = mfma32(av[2 + kb2], pf, o1);
    }
}

__global__ __launch_bounds__(256) void flash_attn(const bf16_t* __restrict__ Qp,
                                                  const bf16_t* __restrict__ Kp,
                                                  const bf16_t* __restrict__ VT,
                                                  bf16_t* __restrict__ Oa) {
    __shared__ alignas(16) char lds[2][2][8192];
    const int tid = threadIdx.x;
    const int lane = tid & 63;
    const int wave = tid >> 6;
    const int half = wave >> 1;
    const int qt = wave & 1;
    const int l31 = lane & 31, hi = lane >> 5;

    const int lin = blockIdx.x + (blockIdx.y << 5) + (blockIdx.z << 9);
    const int swz = (lin & 7) * 128 + (lin >> 3);
    const int qb = swz & 31;
    const int h = (swz >> 5) & 15;
    const int b = swz >> 9;

    const int q0 = qb * 64 + qt * 32;

    const bf16_t* Qb = Qp + (size_t)b * S_SZ * D_MODEL + h * HEAD_DIM;
    const bf16_t* Kb = Kp + (size_t)b * S_SZ * D_MODEL + h * HEAD_DIM;
    const bf16_t* Vb = VT + ((size_t)(b * NUM_HEADS + h) * HEAD_DIM) * S_SZ;

    const int sh = wave & 1;
    const int skvbase = sh * (S_SZ / 2);
    const bool kRole = wave < 2;

    const bf16_t* src_run;
    size_t inner_stride;
    size_t tile_stride;
    char* dst0;
    char* dst1;
    if (kRole) {
        src_run = Kb + (size_t)(skvbase + (lane >> 3)) * D_MODEL + ((lane & 7) ^ (lane >> 3)) * 8;
        inner_stride = (size_t)8 * D_MODEL;
        tile_stride = (size_t)32 * D_MODEL;
        dst0 = &lds[0][sh][0] + lane * 16;
        dst1 = &lds[1][sh][0] + lane * 16;
    } else {
        src_run = Vb + (size_t)(lane >> 2) * S_SZ + skvbase + ((lane & 3) ^ ((lane >> 3) & 3)) * 8;
        inner_stride = (size_t)16 * S_SZ;
        tile_stride = 32;
        dst0 = &lds[0][sh][4096] + lane * 16;
        dst1 = &lds[1][sh][4096] + lane * 16;
    }

    bf16x8 bq[4];
#pragma unroll
    for (int kb = 0; kb < 4; kb++)
        bq[kb] = *(const bf16x8*)(Qb + (size_t)(q0 + l31) * D_MODEL + kb * 16 + hi * 8);

    f32x16 o0, o1;
#pragma unroll
    for (int e = 0; e < 16; e++) { o0[e] = 0.f; o1[e] = 0.f; }
    float mC = -1e30f, l_run = 0.f;

    const char* kt0 = &lds[0][half][0];
    const char* vt0 = &lds[0][half][4096];
    const char* kt1 = &lds[1][half][0];
    const char* vt1 = &lds[1][half][4096];

#pragma unroll
    for (int ii = 0; ii < 4; ii++)
        gload_lds16(src_run + ii * inner_stride, dst0 + ii * 1024);
    src_run += tile_stride;
    __syncthreads();

    for (int t = 0; t < 32; t += 2) {
#pragma unroll
        for (int ii = 0; ii < 4; ii++)
            gload_lds16(src_run + ii * inner_stride, dst1 + ii * 1024);
        src_run += tile_stride;
        flash_tile(kt0, vt0, l31, hi, bq, o0, o1, mC, l_run);
        __syncthreads();

        if (t + 2 < 32) {
#pragma unroll
            for (int ii = 0; ii < 4; ii++)
                gload_lds16(src_run + ii * inner_stride, dst0 + ii * 1024);
            src_run += tile_stride;
        }
        flash_tile(kt1, vt1, l31, hi, bq, o0, o1, mC, l_run);
        __syncthreads();
    }

    int2v lp = plswap(__float_as_int(l_run), __float_as_int(l_run));
    l_run = __int_as_float(lp[0]) + __int_as_float(lp[1]);

    float (*obuf)[2][64] = (float (*)[2][64])(&lds[0][0][0]);
    float (*mrg)[64][2] = (float (*)[64][2])(&lds[0][0][0] + 16384);
    if (half == 1) {
        mrg[qt][lane][0] = mC;
        mrg[qt][lane][1] = l_run;
#pragma unroll
        for (int e = 0; e < 16; e++) {
            obuf[e][qt][lane] = o0[e];
            obuf[16 + e][qt][lane] = o1[e];
        }
    }
    __syncthreads();
    if (half == 0) {
        const float m2C = mrg[qt][lane][0], l2 = mrg[qt][lane][1];
        const float mm = fmaxf(mC, m2C);
        const float e1 = fexp2(mC - mm);
        const float e2 = fexp2(m2C - mm);
        const float linv = 1.f / (l_run * e1 + l2 * e2);
        bf16_t* Orow = Oa + ((size_t)b * S_SZ + q0 + l31) * D_MODEL + h * HEAD_DIM;
#pragma unroll
        for (int db = 0; db < 2; db++) {
#pragma unroll
            for (int rq = 0; rq < 4; rq++) {
                bf16x4 st;
#pragma unroll
                for (int i = 0; i < 4; i++) {
                    const int e = rq * 4 + i;
                    const float own = db ? o1[e] : o0[e];
                    const float oth = obuf[db * 16 + e][qt][lane];
                    st[i] = (bf16_t)((own * e1 + oth * e2) * linv);
                }
                *(bf16x4*)(Orow + db * 32 + rq * 8 + hi * 4) = st;
            }
        }
    }
}

// ---------------------------------------------------------------------------
// LayerNorm over 1024 with fused residual + optional second addend
// ---------------------------------------------------------------------------
__global__ __launch_bounds__(256) void ln_fused(const float* __restrict__ A,
                                                const float* __restrict__ A2,
                                                const float* __restrict__ R,
                                                const float* __restrict__ gamma,
                                                const float* __restrict__ beta,
                                                float* __restrict__ Xf,
                                                bf16_t* __restrict__ Xb) {
    __shared__ float red[8];
    int row = blockIdx.x, tid = threadIdx.x;
    size_t base = (size_t)row * D_MODEL + tid * 4;
    float4 a = *(const float4*)(A + base);
    float4 rv = *(const float4*)(R + base);
    float v0 = a.x + rv.x, v1 = a.y + rv.y, v2 = a.z + rv.z, v3 = a.w + rv.w;
    if (A2) {
        float4 a2 = *(const float4*)(A2 + base);
        v0 += a2.x; v1 += a2.y; v2 += a2.z; v3 += a2.w;
    }
    float s = v0 + v1 + v2 + v3;
    float q = v0 * v0 + v1 * v1 + v2 * v2 + v3 * v3;
#pragma unroll
    for (int off = 32; off; off >>= 1) { s += __shfl_down(s, off); q += __shfl_down(q, off); }
    if ((tid & 63) == 0) { red[tid >> 6] = s; red[4 + (tid >> 6)] = q; }
    __syncthreads();
    s = red[0] + red[1] + red[2] + red[3];
    q = red[4] + red[5] + red[6] + red[7];
    float mean = s * (1.f / D_MODEL);
    float var = q * (1.f / D_MODEL) - mean * mean;
    float rstd = rsqrtf(var + 1e-5f);
    float4 gm = *(const float4*)(gamma + tid * 4);
    float4 bt = *(const float4*)(beta + tid * 4);
    float y0 = (v0 - mean) * rstd * gm.x + bt.x;
    float y1 = (v1 - mean) * rstd * gm.y + bt.y;
    float y2 = (v2 - mean) * rstd * gm.z + bt.z;
    float y3 = (v3 - mean) * rstd * gm.w + bt.w;
    float4 yo; yo.x = y0; yo.y = y1; yo.z = y2; yo.w = y3;
    *(float4*)(Xf + base) = yo;
    if (Xb) {
        bf16x4 ob; ob[0] = (bf16_t)y0; ob[1] = (bf16_t)y1; ob[2] = (bf16_t)y2; ob[3] = (bf16_t)y3;
        *(bf16x4*)(Xb + base) = ob;
    }
}

// ---------------------------------------------------------------------------
extern "C" void kernel_launch(void* const* d_in, const int* in_sizes, int n_in,
                              void* d_out, int out_size, void* d_ws, size_t ws_size,
                              hipStream_t stream) {
    const float* value = (const float*)d_in[0];
    const float* key   = (const float*)d_in[1];
    const float* query = (const float*)d_in[2];
    const float* wq = (const float*)d_in[3];
    const float* bq = (const float*)d_in[4];
    const float* wk = (const float*)d_in[5];
    const float* bk = (const float*)d_in[6];
    const float* wv = (const float*)d_in[7];
    const float* bv = (const float*)d_in[8];
    const float* wo = (const float*)d_in[9];
    const float* bo = (const float*)d_in[10];
    const float* g1 = (const float*)d_in[11];
    const float* beta1 = (const float*)d_in[12];
    const float* w1 = (const float*)d_in[13];
    const float* b1 = (const float*)d_in[14];
    const float* w2 = (const float*)d_in[15];
    const float* b2 = (const float*)d_in[16];
    const float* g2 = (const float*)d_in[17];
    const float* beta2 = (const float*)d_in[18];
    (void)in_sizes; (void)n_in; (void)out_size; (void)ws_size;

    const size_t MB = 1ull << 20;
    char* ws = (char*)d_ws;
    bf16_t* wqT = (bf16_t*)(ws + 0 * MB);
    bf16_t* wkT = (bf16_t*)(ws + 2 * MB);
    bf16_t* wvT = (bf16_t*)(ws + 4 * MB);
    bf16_t* woT = (bf16_t*)(ws + 6 * MB);
    bf16_t* w1T = (bf16_t*)(ws + 8 * MB);
    bf16_t* w2T = (bf16_t*)(ws + 16 * MB);
    bf16_t* q_bf = (bf16_t*)(ws + 24 * MB);
    bf16_t* k_bf = (bf16_t*)(ws + 32 * MB);
    bf16_t* v_bf = (bf16_t*)(ws + 40 * MB);
    bf16_t* Qp  = (bf16_t*)(ws + 48 * MB);
    bf16_t* Kp  = (bf16_t*)(ws + 56 * MB);
    bf16_t* Vp  = (bf16_t*)(ws + 64 * MB);
    bf16_t* VT  = (bf16_t*)(ws + 72 * MB);
    bf16_t* attn = (bf16_t*)(ws + 24 * MB);
    float*  woP0 = (float*)(ws + 32 * MB);
    float*  woP1 = (float*)(ws + 48 * MB);
    float*  x_f = (float*)(ws + 64 * MB);
    bf16_t* x_b = (bf16_t*)(ws + 24 * MB);
    bf16_t* h_b = (bf16_t*)(ws + 32 * MB);
    float*  ffP0 = (float*)(ws + 80 * MB);
    float*  ffP1 = (float*)(ws + 96 * MB);

    dim3 blk(256);
    dim3 blk512(512);

    // 1) casts + weight transposes
    cast3_f32_bf16<<<12288, blk, 0, stream>>>(query, key, value, q_bf, k_bf, v_bf);
    transpose_cast_w4<<<dim3(32, 32, 4), blk, 0, stream>>>(wq, wk, wv, wo, wqT, wkT, wvT, woT);
    transpose_cast_w<<<dim3(32, 128), blk, 0, stream>>>(w1, w1T, 1024, 4096);
    transpose_cast_w<<<dim3(128, 32), blk, 0, stream>>>(w2, w2T, 4096, 1024);

    // 2) grouped QKV projection (256-tile, 192 blocks)
    gemm_qkv256<<<dim3(16, 4, 3), blk512, 0, stream>>>(q_bf, k_bf, v_bf, wqT, wkT, wvT,
                                                       bq, bk, bv, Qp, Kp, Vp);

    // 3) V transpose
    transpose_v<<<dim3(64, 2, 32), blk, 0, stream>>>(Vp, VT);

    // 4) flash attention v5
    flash_attn<<<dim3(32, 16, 2), blk, 0, stream>>>(Qp, Kp, VT, attn);

    // 5) WO projection (256x128, split-K=2)
    gemm_bt256<2, false, false, true><<<dim3(16, 8, 2), blk512, 0, stream>>>(attn, 1024, woT, 1024, bo, woP0, woP1, nullptr, D_MODEL, 512);

    // 6) LN1
    ln_fused<<<4096, blk, 0, stream>>>(woP0, woP1, query, g1, beta1, x_f, x_b);

    // 7) FF1 + ReLU (256x256)
    gemm_bt256<4, true, true, false><<<dim3(16, 16, 1), blk512, 0, stream>>>(x_b, 1024, w1T, 1024, b1, nullptr, nullptr, h_b, FF_DIM, 1024);

    // 8) FF2 (256x128, split-K=2)
    gemm_bt256<2, false, false, true><<<dim3(16, 8, 2), blk512, 0, stream>>>(h_b, 4096, w2T, 4096, b2, ffP0, ffP1, nullptr, D_MODEL, 2048);

    // 9) LN2 -> d_out
    ln_fused<<<4096, blk, 0, stream>>>(ffP0, ffP1, x_f, g2, beta2, (float*)d_out, nullptr);
}